// Round 1
// baseline (1199.777 us; speedup 1.0000x reference)
//
#include <hip/hip_runtime.h>
#include <hip/hip_bf16.h>
#include <math.h>

#define NB 8        // batch
#define LNN 64      // nodes
#define LTN 256     // text len
#define DD 1024     // model dim
#define NH 4        // heads (each full width D)
#define HDD 4096    // NH*DD
#define DINN 2048
#define DHN 1024    // DIN/2

// ---------------- generic fp32 GEMM: C[M,N] = A[M,K] @ W[K,N] + bias (+res) ----------------
// 64x64 tile, 256 threads, 4x4 microtile, K-chunk 16. M%64==0, N%64==0, K%16==0.
__global__ __launch_bounds__(256) void gemm64(const float* __restrict__ A,
                                              const float* __restrict__ W,
                                              const float* __restrict__ bias,
                                              const float* __restrict__ res,
                                              float* __restrict__ C,
                                              int M, int N, int K) {
  __shared__ float As[64][17];
  __shared__ float Bs[16][65];
  int tid = threadIdx.x;
  int tx = tid & 15, ty = tid >> 4;
  int m0 = blockIdx.y << 6, n0 = blockIdx.x << 6;
  float acc[4][4] = {};
  int ra = tid >> 2, ca = (tid & 3) << 2;
  int rb = tid >> 4, cb = (tid & 15) << 2;
  const float* pa = A + (size_t)(m0 + ra) * K + ca;
  const float* pb = W + (size_t)rb * N + n0 + cb;
  for (int k0 = 0; k0 < K; k0 += 16) {
    float4 a4 = *(const float4*)(pa + k0);
    float4 b4 = *(const float4*)(pb + (size_t)k0 * N);
    As[ra][ca + 0] = a4.x; As[ra][ca + 1] = a4.y; As[ra][ca + 2] = a4.z; As[ra][ca + 3] = a4.w;
    Bs[rb][cb + 0] = b4.x; Bs[rb][cb + 1] = b4.y; Bs[rb][cb + 2] = b4.z; Bs[rb][cb + 3] = b4.w;
    __syncthreads();
#pragma unroll
    for (int kk = 0; kk < 16; ++kk) {
      float a[4], b[4];
#pragma unroll
      for (int i = 0; i < 4; ++i) a[i] = As[ty * 4 + i][kk];
#pragma unroll
      for (int j = 0; j < 4; ++j) b[j] = Bs[kk][tx * 4 + j];
#pragma unroll
      for (int i = 0; i < 4; ++i)
#pragma unroll
        for (int j = 0; j < 4; ++j) acc[i][j] += a[i] * b[j];
    }
    __syncthreads();
  }
#pragma unroll
  for (int i = 0; i < 4; ++i) {
    int row = m0 + ty * 4 + i;
#pragma unroll
    for (int j = 0; j < 4; ++j) {
      int col = n0 + tx * 4 + j;
      float v = acc[i][j] + bias[col];
      if (res) v += res[(size_t)row * N + col];
      C[(size_t)row * N + col] = v;
    }
  }
}

// ---------------- fused self-attention per (b,h): scores+softmax+PV ----------------
__global__ __launch_bounds__(1024) void attn_kernel(const float* __restrict__ Qb,
                                                    const float* __restrict__ Kb,
                                                    const float* __restrict__ Vb,
                                                    const int* __restrict__ gmask,
                                                    float* __restrict__ AO) {
  int b = blockIdx.x >> 2, h = blockIdx.x & 3;
  __shared__ float Qc[64][65];
  __shared__ float Kc[64][65];
  __shared__ float S[64][65];
  int tid = threadIdx.x;
  int tx = tid & 15, ty = tid >> 4;  // ty 0..63
  float acc0 = 0.f, acc1 = 0.f, acc2 = 0.f, acc3 = 0.f;
  size_t base = ((size_t)b * LNN) * HDD + (size_t)h * DD;
  for (int d0 = 0; d0 < DD; d0 += 64) {
    int c = tx * 4;
    float4 q4 = *(const float4*)(Qb + base + (size_t)ty * HDD + d0 + c);
    float4 k4 = *(const float4*)(Kb + base + (size_t)ty * HDD + d0 + c);
    Qc[ty][c + 0] = q4.x; Qc[ty][c + 1] = q4.y; Qc[ty][c + 2] = q4.z; Qc[ty][c + 3] = q4.w;
    Kc[ty][c + 0] = k4.x; Kc[ty][c + 1] = k4.y; Kc[ty][c + 2] = k4.z; Kc[ty][c + 3] = k4.w;
    __syncthreads();
#pragma unroll 16
    for (int kk = 0; kk < 64; ++kk) {
      float a = Qc[ty][kk];
      acc0 += a * Kc[tx * 4 + 0][kk];
      acc1 += a * Kc[tx * 4 + 1][kk];
      acc2 += a * Kc[tx * 4 + 2][kk];
      acc3 += a * Kc[tx * 4 + 3][kk];
    }
    __syncthreads();
  }
  S[ty][tx * 4 + 0] = acc0;
  S[ty][tx * 4 + 1] = acc1;
  S[ty][tx * 4 + 2] = acc2;
  S[ty][tx * 4 + 3] = acc3;
  __syncthreads();
  // softmax over k (64 values per row), wave w handles rows 4w..4w+3
  int lane = tid & 63, w = tid >> 6;
  bool valid = gmask[b * LNN + lane] != 0;
#pragma unroll
  for (int i = 0; i < 4; ++i) {
    int q = w * 4 + i;
    float v = valid ? S[q][lane] * 0.03125f : -__builtin_inff();
    float m = v;
    for (int o = 32; o; o >>= 1) m = fmaxf(m, __shfl_xor(m, o, 64));
    float e = valid ? __expf(v - m) : 0.f;
    float s = e;
    for (int o = 32; o; o >>= 1) s += __shfl_xor(s, o, 64);
    S[q][lane] = e / s;
  }
  __syncthreads();
  // PV: thread owns one d (0..1023); V column in registers
  float vr[64];
#pragma unroll
  for (int k = 0; k < 64; ++k) vr[k] = Vb[base + (size_t)k * HDD + tid];
#pragma unroll 2
  for (int q = 0; q < 64; ++q) {
    float o = 0.f;
#pragma unroll
    for (int k = 0; k < 64; ++k) o += S[q][k] * vr[k];
    AO[base + (size_t)q * HDD + tid] = o;
  }
}

// ---------------- LayerNorm per row over D=1024 ----------------
__global__ __launch_bounds__(256) void lnorm(const float* __restrict__ X,
                                             const float* __restrict__ g,
                                             const float* __restrict__ be,
                                             float* __restrict__ Y) {
  int row = blockIdx.x, tid = threadIdx.x;
  int c = tid * 4;
  float4 v = *(const float4*)(X + (size_t)row * DD + c);
  float s = v.x + v.y + v.z + v.w;
  float ss = v.x * v.x + v.y * v.y + v.z * v.z + v.w * v.w;
  for (int o = 32; o; o >>= 1) {
    s += __shfl_xor(s, o, 64);
    ss += __shfl_xor(ss, o, 64);
  }
  __shared__ float rb_[8];
  int lane = tid & 63, w = tid >> 6;
  if (lane == 0) { rb_[w] = s; rb_[4 + w] = ss; }
  __syncthreads();
  s = rb_[0] + rb_[1] + rb_[2] + rb_[3];
  ss = rb_[4] + rb_[5] + rb_[6] + rb_[7];
  float mu = s * (1.f / 1024.f);
  float var = ss * (1.f / 1024.f) - mu * mu;
  float rstd = rsqrtf(var + 1e-5f);
  float4 o4;
  o4.x = (v.x - mu) * rstd * g[c + 0] + be[c + 0];
  o4.y = (v.y - mu) * rstd * g[c + 1] + be[c + 1];
  o4.z = (v.z - mu) * rstd * g[c + 2] + be[c + 2];
  o4.w = (v.w - mu) * rstd * g[c + 3] + be[c + 3];
  *(float4*)(Y + (size_t)row * DD + c) = o4;
}

__device__ __forceinline__ float ftanh(float x) {
  float e = __expf(2.f * x);
  return 1.f - __fdividef(2.f, e + 1.f);
}

// ---------------- additive attention per (b,qn): e -> softmax -> H3 ----------------
__global__ __launch_bounds__(256) void addattn(const float* __restrict__ QBu,
                                               const float* __restrict__ KBu,
                                               const float* __restrict__ text,
                                               const int* __restrict__ lmask,
                                               const float* __restrict__ av_,
                                               const float* __restrict__ ab_,
                                               float* __restrict__ H3) {
  int b = blockIdx.x >> 6;
  int qn = blockIdx.x & 63;
  __shared__ float qrow[DD], av[DD], ab[DD];
  __shared__ float wv[LTN];
  __shared__ float rb_[8];
  int tid = threadIdx.x;
  int c = tid * 4;
  *(float4*)(qrow + c) = *(const float4*)(QBu + ((size_t)(b * LNN + qn)) * DD + c);
  *(float4*)(av + c) = *(const float4*)(av_ + c);
  *(float4*)(ab + c) = *(const float4*)(ab_ + c);
  __syncthreads();
  // phase 1: thread t computes e[k=t] = sum_d att_v[d]*tanh(q[d]+K[t][d]+att_b[d])
  bool valid = lmask[b * LTN + tid] != 0;
  float e = -__builtin_inff();
  if (valid) {
    const float* kr = KBu + ((size_t)(b * LTN + tid)) * DD;
    float acc = 0.f;
#pragma unroll 4
    for (int d = 0; d < DD; d += 4) {
      float4 kv = *(const float4*)(kr + d);
      acc += av[d + 0] * ftanh(qrow[d + 0] + kv.x + ab[d + 0]);
      acc += av[d + 1] * ftanh(qrow[d + 1] + kv.y + ab[d + 1]);
      acc += av[d + 2] * ftanh(qrow[d + 2] + kv.z + ab[d + 2]);
      acc += av[d + 3] * ftanh(qrow[d + 3] + kv.w + ab[d + 3]);
    }
    e = acc;
  }
  // block softmax over 256 values
  int lane = tid & 63, w = tid >> 6;
  float m = e;
  for (int o = 32; o; o >>= 1) m = fmaxf(m, __shfl_xor(m, o, 64));
  if (lane == 0) rb_[w] = m;
  __syncthreads();
  m = fmaxf(fmaxf(rb_[0], rb_[1]), fmaxf(rb_[2], rb_[3]));
  float ex = valid ? __expf(e - m) : 0.f;
  float s = ex;
  for (int o = 32; o; o >>= 1) s += __shfl_xor(s, o, 64);
  if (lane == 0) rb_[4 + w] = s;
  __syncthreads();
  s = rb_[4] + rb_[5] + rb_[6] + rb_[7];
  wv[tid] = __fdividef(ex, s);
  __syncthreads();
  // phase 2: H3[b,qn,:] = sum_k wv[k] * text[b,k,:]
  float ax = 0.f, ay = 0.f, az = 0.f, aw = 0.f;
  const float* tb = text + (size_t)b * LTN * DD + c;
  for (int kk = 0; kk < LTN; ++kk) {
    float wgt = wv[kk];
    if (wgt != 0.f) {
      float4 tv = *(const float4*)(tb + (size_t)kk * DD);
      ax += wgt * tv.x; ay += wgt * tv.y; az += wgt * tv.z; aw += wgt * tv.w;
    }
  }
  float4 o4 = {ax, ay, az, aw};
  *(float4*)(H3 + ((size_t)(b * LNN + qn)) * DD + c) = o4;
}

// ---------------- masked mean pool over nodes ----------------
__global__ __launch_bounds__(256) void poolk(const float* __restrict__ H3,
                                             const int* __restrict__ gmask,
                                             float* __restrict__ H4) {
  int b = blockIdx.x, tid = threadIdx.x;
  float cnt = 0.f;
#pragma unroll
  for (int n = 0; n < LNN; ++n) cnt += (gmask[b * LNN + n] != 0) ? 1.f : 0.f;
  cnt = fmaxf(cnt, 9.765625e-04f);  // f16 eps clip
  int c = tid * 4;
  float ax = 0.f, ay = 0.f, az = 0.f, aw = 0.f;
  for (int n = 0; n < LNN; ++n) {
    if (gmask[b * LNN + n] != 0) {
      float4 v = *(const float4*)(H3 + ((size_t)(b * LNN + n)) * DD + c);
      ax += v.x; ay += v.y; az += v.z; aw += v.w;
    }
  }
  float4 o4 = {ax / cnt, ay / cnt, az / cnt, aw / cnt};
  *(float4*)(H4 + (size_t)b * DD + c) = o4;
}

// ---------------- dp1 + exact GELU ----------------
__global__ __launch_bounds__(256) void dp1k(const float* __restrict__ H4,
                                            const float* __restrict__ W,
                                            const float* __restrict__ bias,
                                            float* __restrict__ G) {
  int b = blockIdx.y;
  int j = blockIdx.x * 256 + threadIdx.x;
  __shared__ float h[DD];
  int c = threadIdx.x * 4;
  *(float4*)(h + c) = *(const float4*)(H4 + (size_t)b * DD + c);
  __syncthreads();
  float acc = bias[j];
#pragma unroll 8
  for (int d = 0; d < DD; ++d) acc += h[d] * W[(size_t)d * DHN + j];
  float x = acc;
  G[(size_t)b * DHN + j] = 0.5f * x * (1.f + erff(x * 0.70710678118654752440f));
}

// ---------------- dp2 ----------------
__global__ __launch_bounds__(256) void dp2k(const float* __restrict__ G,
                                            const float* __restrict__ W,
                                            const float* __restrict__ bias,
                                            float* __restrict__ Z) {
  int b = blockIdx.y;
  int j = blockIdx.x * 256 + threadIdx.x;
  __shared__ float h[DHN];
  int c = threadIdx.x * 4;
  *(float4*)(h + c) = *(const float4*)(G + (size_t)b * DHN + c);
  __syncthreads();
  float acc = bias[j];
#pragma unroll 8
  for (int d = 0; d < DHN; ++d) acc += h[d] * W[(size_t)d * DINN + j];
  Z[(size_t)b * DINN + j] = acc;
}

extern "C" void kernel_launch(void* const* d_in, const int* in_sizes, int n_in,
                              void* d_out, int out_size, void* d_ws, size_t ws_size,
                              hipStream_t stream) {
  const float* text = (const float*)d_in[0];
  const float* node = (const float*)d_in[1];
  const float* Wq = (const float*)d_in[2];
  const float* bq = (const float*)d_in[3];
  const float* Wk = (const float*)d_in[4];
  const float* bk = (const float*)d_in[5];
  const float* Wv = (const float*)d_in[6];
  const float* bv = (const float*)d_in[7];
  const float* Wo = (const float*)d_in[8];
  const float* bo = (const float*)d_in[9];
  const float* lng = (const float*)d_in[10];
  const float* lnb = (const float*)d_in[11];
  const float* aqW = (const float*)d_in[12];
  const float* aqb = (const float*)d_in[13];
  const float* akW = (const float*)d_in[14];
  const float* akb = (const float*)d_in[15];
  const float* attv = (const float*)d_in[16];
  const float* attb = (const float*)d_in[17];
  const float* dp1W = (const float*)d_in[18];
  const float* dp1b = (const float*)d_in[19];
  const float* dp2W = (const float*)d_in[20];
  const float* dp2b = (const float*)d_in[21];
  const int* gmask = (const int*)d_in[22];
  const int* lmask = (const int*)d_in[23];
  (void)in_sizes; (void)n_in; (void)out_size; (void)ws_size;

  float* ws = (float*)d_ws;
  float* Qb = ws;                    // 2M floats (B*LN, HD)
  float* Kb = ws + 2097152;          // 2M
  float* Vb = ws + 4194304;          // 2M
  float* AO = ws + 6291456;          // 2M  (B*LN, HD)
  float* PRE = Qb;                   // (B*LN, D) reuses Q
  float* H2 = Kb;                    // reuses K
  float* QBu = Vb;                   // additive q, reuses V
  float* KBu = AO;                   // additive k, reuses AO
  float* H3 = Qb;                    // reuses PRE
  float* H4 = ws + 8388608;          // 8192
  float* G = ws + 8396800;           // 8192
  float* Z = (float*)d_out;

  const int M1 = NB * LNN;  // 512
  dim3 blk(256);

  // QKV projections
  gemm64<<<dim3(HDD / 64, M1 / 64), blk, 0, stream>>>(node, Wq, bq, nullptr, Qb, M1, HDD, DD);
  gemm64<<<dim3(HDD / 64, M1 / 64), blk, 0, stream>>>(node, Wk, bk, nullptr, Kb, M1, HDD, DD);
  gemm64<<<dim3(HDD / 64, M1 / 64), blk, 0, stream>>>(node, Wv, bv, nullptr, Vb, M1, HDD, DD);
  // self-attention
  attn_kernel<<<dim3(NB * NH), dim3(1024), 0, stream>>>(Qb, Kb, Vb, gmask, AO);
  // output proj + residual
  gemm64<<<dim3(DD / 64, M1 / 64), blk, 0, stream>>>(AO, Wo, bo, node, PRE, M1, DD, HDD);
  // layernorm
  lnorm<<<dim3(M1), blk, 0, stream>>>(PRE, lng, lnb, H2);
  // additive attention projections
  gemm64<<<dim3(DD / 64, M1 / 64), blk, 0, stream>>>(H2, aqW, aqb, nullptr, QBu, M1, DD, DD);
  gemm64<<<dim3(DD / 64, (NB * LTN) / 64), blk, 0, stream>>>(text, akW, akb, nullptr, KBu, NB * LTN, DD, DD);
  // additive attention + context
  addattn<<<dim3(NB * LNN), blk, 0, stream>>>(QBu, KBu, text, lmask, attv, attb, H3);
  // pool + MLP
  poolk<<<dim3(NB), blk, 0, stream>>>(H3, gmask, H4);
  dp1k<<<dim3(DHN / 256, NB), blk, 0, stream>>>(H4, dp1W, dp1b, G);
  dp2k<<<dim3(DINN / 256, NB), blk, 0, stream>>>(G, dp2W, dp2b, Z);
}

// Round 2
// 618.251 us; speedup vs baseline: 1.9406x; 1.9406x over previous
//
#include <hip/hip_runtime.h>
#include <hip/hip_bf16.h>
#include <math.h>

#define NB 8        // batch
#define LNN 64      // nodes
#define LTN 256     // text len
#define DD 1024     // model dim
#define NH 4        // heads (each full width D)
#define HDD 4096    // NH*DD
#define DINN 2048
#define DHN 1024    // DIN/2

typedef __bf16 bf16x8 __attribute__((ext_vector_type(8)));
typedef float f32x4 __attribute__((ext_vector_type(4)));

__device__ __forceinline__ float b2f(ushort u) {
  union { float f; unsigned int i; } x; x.i = ((unsigned int)u) << 16; return x.f;
}
__device__ __forceinline__ ushort f2b(float f) {
  unsigned int u = __builtin_bit_cast(unsigned int, f);
  u = (u + 0x7FFFu + ((u >> 16) & 1u)) >> 16;
  return (ushort)u;
}

// ---------------- fp32 -> bf16 elementwise (n % 2048 == 0) ----------------
__global__ __launch_bounds__(256) void cvtk(const float* __restrict__ in,
                                            ushort* __restrict__ out, int n) {
  int i = (blockIdx.x * 256 + threadIdx.x) * 8;
  if (i >= n) return;
  float4 a = *(const float4*)(in + i);
  float4 b = *(const float4*)(in + i + 4);
  ushort4 o0 = {f2b(a.x), f2b(a.y), f2b(a.z), f2b(a.w)};
  ushort4 o1 = {f2b(b.x), f2b(b.y), f2b(b.z), f2b(b.w)};
  *(ushort4*)(out + i) = o0;
  *(ushort4*)(out + i + 4) = o1;
}

// ---------------- transpose + convert: W[K][N] fp32 -> Wt[N][K] bf16 ----------------
__global__ __launch_bounds__(256) void tcvt(const float* __restrict__ W,
                                            ushort* __restrict__ Wt, int K, int N) {
  __shared__ float tf[64][65];
  int k0 = blockIdx.y << 6, n0 = blockIdx.x << 6;
  int t = threadIdx.x;
  int r = t >> 2, c4 = (t & 3) * 16;
  const float* src = W + (size_t)(k0 + r) * N + n0 + c4;
  float4 v0 = *(const float4*)(src);
  float4 v1 = *(const float4*)(src + 4);
  float4 v2 = *(const float4*)(src + 8);
  float4 v3 = *(const float4*)(src + 12);
  *(float4*)&tf[r][c4] = v0;
  *(float4*)&tf[r][c4 + 4] = v1;
  *(float4*)&tf[r][c4 + 8] = v2;
  *(float4*)&tf[r][c4 + 12] = v3;
  __syncthreads();
  int nl = t >> 2, kc = (t & 3) * 16;
  ushort tmp[16];
#pragma unroll
  for (int j = 0; j < 16; ++j) tmp[j] = f2b(tf[kc + j][nl]);
  ushort* dst = Wt + (size_t)(n0 + nl) * K + k0 + kc;
  *(uint4*)(dst) = *(uint4*)&tmp[0];
  *(uint4*)(dst + 8) = *(uint4*)&tmp[8];
}

// ---------------- bf16 MFMA GEMM: C[M,N] = A[M,K] @ Bt[N,K]^T + bias (+res) ----------------
// 64x64 tile, 256 threads (4 waves, 2x2 of 32x32), BK=64, XOR-swizzled LDS.
template <int OUTBF, int RES>
__global__ __launch_bounds__(256) void gemm_mfma(const ushort* __restrict__ A,
                                                 const ushort* __restrict__ Bt,
                                                 const float* __restrict__ bias,
                                                 const float* __restrict__ res,
                                                 void* __restrict__ Cout,
                                                 int M, int N, int K) {
  __shared__ ushort Als[64 * 64];
  __shared__ ushort Bls[64 * 64];
  int tid = threadIdx.x;
  int m0 = blockIdx.y << 6, n0 = blockIdx.x << 6;

  // staging: thread -> row (0..63), two 16B units (16 bf16 = 32B per thread)
  int srow = tid >> 2;
  int su0 = (tid & 3) * 2;
  const ushort* ga = A + (size_t)(m0 + srow) * K + su0 * 8;
  const ushort* gb = Bt + (size_t)(n0 + srow) * K + su0 * 8;
  int wa0 = srow * 64 + ((su0) ^ (srow & 7)) * 8;
  int wa1 = srow * 64 + ((su0 + 1) ^ (srow & 7)) * 8;

  int lane = tid & 63, w = tid >> 6;
  int wm = w >> 1, wn = w & 1;
  int r = lane & 15, kg = lane >> 4;

  f32x4 acc[2][2] = {};

  uint4 pa0 = *(const uint4*)(ga);
  uint4 pa1 = *(const uint4*)(ga + 8);
  uint4 pb0 = *(const uint4*)(gb);
  uint4 pb1 = *(const uint4*)(gb + 8);

  for (int k0 = 0; k0 < K; k0 += 64) {
    __syncthreads();
    *(uint4*)&Als[wa0] = pa0; *(uint4*)&Als[wa1] = pa1;
    *(uint4*)&Bls[wa0] = pb0; *(uint4*)&Bls[wa1] = pb1;
    __syncthreads();
    int kn = k0 + 64;
    if (kn < K) {
      pa0 = *(const uint4*)(ga + kn);
      pa1 = *(const uint4*)(ga + kn + 8);
      pb0 = *(const uint4*)(gb + kn);
      pb1 = *(const uint4*)(gb + kn + 8);
    }
#pragma unroll
    for (int h = 0; h < 2; ++h) {
      int sa = ((h * 4 + kg) ^ (r & 7)) * 8;  // swizzled 16B-unit (rows == r mod 8)
      bf16x8 af[2], bfr[2];
#pragma unroll
      for (int m = 0; m < 2; ++m)
        af[m] = *(const bf16x8*)&Als[(wm * 32 + m * 16 + r) * 64 + sa];
#pragma unroll
      for (int n = 0; n < 2; ++n)
        bfr[n] = *(const bf16x8*)&Bls[(wn * 32 + n * 16 + r) * 64 + sa];
#pragma unroll
      for (int m = 0; m < 2; ++m)
#pragma unroll
        for (int n = 0; n < 2; ++n)
          acc[m][n] = __builtin_amdgcn_mfma_f32_16x16x32_bf16(af[m], bfr[n], acc[m][n], 0, 0, 0);
    }
  }
  // epilogue: C/D layout col=lane&15, row=(lane>>4)*4+v
#pragma unroll
  for (int m = 0; m < 2; ++m)
#pragma unroll
    for (int n = 0; n < 2; ++n) {
      f32x4 a = acc[m][n];
#pragma unroll
      for (int v = 0; v < 4; ++v) {
        int row = m0 + wm * 32 + m * 16 + kg * 4 + v;
        int col = n0 + wn * 32 + n * 16 + r;
        float x = a[v] + bias[col];
        if constexpr (RES) x += res[(size_t)row * N + col];
        if constexpr (OUTBF) ((ushort*)Cout)[(size_t)row * N + col] = f2b(x);
        else ((float*)Cout)[(size_t)row * N + col] = x;
      }
    }
}

// ---------------- fused self-attention per (b,h): scores+softmax+PV (bf16 in/out) ----------------
__global__ __launch_bounds__(1024) void attn_kernel(const ushort* __restrict__ Qb,
                                                    const ushort* __restrict__ Kb,
                                                    const ushort* __restrict__ Vb,
                                                    const int* __restrict__ gmask,
                                                    ushort* __restrict__ AO) {
  int b = blockIdx.x >> 2, h = blockIdx.x & 3;
  __shared__ float Qc[64][65];
  __shared__ float Kc[64][65];
  __shared__ float S[64][65];
  int tid = threadIdx.x;
  int tx = tid & 15, ty = tid >> 4;  // ty 0..63
  float acc0 = 0.f, acc1 = 0.f, acc2 = 0.f, acc3 = 0.f;
  size_t base = ((size_t)b * LNN) * HDD + (size_t)h * DD;
  for (int d0 = 0; d0 < DD; d0 += 64) {
    int c = tx * 4;
    ushort4 q4 = *(const ushort4*)(Qb + base + (size_t)ty * HDD + d0 + c);
    ushort4 k4 = *(const ushort4*)(Kb + base + (size_t)ty * HDD + d0 + c);
    Qc[ty][c + 0] = b2f(q4.x); Qc[ty][c + 1] = b2f(q4.y);
    Qc[ty][c + 2] = b2f(q4.z); Qc[ty][c + 3] = b2f(q4.w);
    Kc[ty][c + 0] = b2f(k4.x); Kc[ty][c + 1] = b2f(k4.y);
    Kc[ty][c + 2] = b2f(k4.z); Kc[ty][c + 3] = b2f(k4.w);
    __syncthreads();
#pragma unroll 16
    for (int kk = 0; kk < 64; ++kk) {
      float a = Qc[ty][kk];
      acc0 += a * Kc[tx * 4 + 0][kk];
      acc1 += a * Kc[tx * 4 + 1][kk];
      acc2 += a * Kc[tx * 4 + 2][kk];
      acc3 += a * Kc[tx * 4 + 3][kk];
    }
    __syncthreads();
  }
  S[ty][tx * 4 + 0] = acc0;
  S[ty][tx * 4 + 1] = acc1;
  S[ty][tx * 4 + 2] = acc2;
  S[ty][tx * 4 + 3] = acc3;
  __syncthreads();
  int lane = tid & 63, w = tid >> 6;
  bool valid = gmask[b * LNN + lane] != 0;
#pragma unroll
  for (int i = 0; i < 4; ++i) {
    int q = w * 4 + i;
    float v = valid ? S[q][lane] * 0.03125f : -__builtin_inff();
    float m = v;
    for (int o = 32; o; o >>= 1) m = fmaxf(m, __shfl_xor(m, o, 64));
    float e = valid ? __expf(v - m) : 0.f;
    float s = e;
    for (int o = 32; o; o >>= 1) s += __shfl_xor(s, o, 64);
    S[q][lane] = e / s;
  }
  __syncthreads();
  float vr[64];
#pragma unroll
  for (int k = 0; k < 64; ++k) vr[k] = b2f(Vb[base + (size_t)k * HDD + tid]);
#pragma unroll 2
  for (int q = 0; q < 64; ++q) {
    float o = 0.f;
#pragma unroll
    for (int k = 0; k < 64; ++k) o += S[q][k] * vr[k];
    AO[base + (size_t)q * HDD + tid] = f2b(o);
  }
}

// ---------------- LayerNorm per row over D=1024, bf16 out ----------------
__global__ __launch_bounds__(256) void lnorm(const float* __restrict__ X,
                                             const float* __restrict__ g,
                                             const float* __restrict__ be,
                                             ushort* __restrict__ Y) {
  int row = blockIdx.x, tid = threadIdx.x;
  int c = tid * 4;
  float4 v = *(const float4*)(X + (size_t)row * DD + c);
  float s = v.x + v.y + v.z + v.w;
  float ss = v.x * v.x + v.y * v.y + v.z * v.z + v.w * v.w;
  for (int o = 32; o; o >>= 1) {
    s += __shfl_xor(s, o, 64);
    ss += __shfl_xor(ss, o, 64);
  }
  __shared__ float rb_[8];
  int lane = tid & 63, w = tid >> 6;
  if (lane == 0) { rb_[w] = s; rb_[4 + w] = ss; }
  __syncthreads();
  s = rb_[0] + rb_[1] + rb_[2] + rb_[3];
  ss = rb_[4] + rb_[5] + rb_[6] + rb_[7];
  float mu = s * (1.f / 1024.f);
  float var = ss * (1.f / 1024.f) - mu * mu;
  float rstd = rsqrtf(var + 1e-5f);
  ushort4 o4;
  o4.x = f2b((v.x - mu) * rstd * g[c + 0] + be[c + 0]);
  o4.y = f2b((v.y - mu) * rstd * g[c + 1] + be[c + 1]);
  o4.z = f2b((v.z - mu) * rstd * g[c + 2] + be[c + 2]);
  o4.w = f2b((v.w - mu) * rstd * g[c + 3] + be[c + 3]);
  *(ushort4*)(Y + (size_t)row * DD + c) = o4;
}

__device__ __forceinline__ float ftanh(float x) {
  float e = __expf(2.f * x);
  return 1.f - __fdividef(2.f, e + 1.f);
}

// ---------------- additive attention per (b,qn) ----------------
__global__ __launch_bounds__(256) void addattn(const float* __restrict__ QBu,
                                               const float* __restrict__ KBu,
                                               const float* __restrict__ text,
                                               const int* __restrict__ lmask,
                                               const float* __restrict__ av_,
                                               const float* __restrict__ ab_,
                                               float* __restrict__ H3) {
  int b = blockIdx.x >> 6;
  int qn = blockIdx.x & 63;
  __shared__ float qrow[DD], av[DD], ab[DD];
  __shared__ float wv[LTN];
  __shared__ float rb_[8];
  int tid = threadIdx.x;
  int c = tid * 4;
  *(float4*)(qrow + c) = *(const float4*)(QBu + ((size_t)(b * LNN + qn)) * DD + c);
  *(float4*)(av + c) = *(const float4*)(av_ + c);
  *(float4*)(ab + c) = *(const float4*)(ab_ + c);
  __syncthreads();
  bool valid = lmask[b * LTN + tid] != 0;
  float e = -__builtin_inff();
  if (valid) {
    const float* kr = KBu + ((size_t)(b * LTN + tid)) * DD;
    float acc = 0.f;
#pragma unroll 4
    for (int d = 0; d < DD; d += 4) {
      float4 kv = *(const float4*)(kr + d);
      acc += av[d + 0] * ftanh(qrow[d + 0] + kv.x + ab[d + 0]);
      acc += av[d + 1] * ftanh(qrow[d + 1] + kv.y + ab[d + 1]);
      acc += av[d + 2] * ftanh(qrow[d + 2] + kv.z + ab[d + 2]);
      acc += av[d + 3] * ftanh(qrow[d + 3] + kv.w + ab[d + 3]);
    }
    e = acc;
  }
  int lane = tid & 63, w = tid >> 6;
  float m = e;
  for (int o = 32; o; o >>= 1) m = fmaxf(m, __shfl_xor(m, o, 64));
  if (lane == 0) rb_[w] = m;
  __syncthreads();
  m = fmaxf(fmaxf(rb_[0], rb_[1]), fmaxf(rb_[2], rb_[3]));
  float ex = valid ? __expf(e - m) : 0.f;
  float s = ex;
  for (int o = 32; o; o >>= 1) s += __shfl_xor(s, o, 64);
  if (lane == 0) rb_[4 + w] = s;
  __syncthreads();
  s = rb_[4] + rb_[5] + rb_[6] + rb_[7];
  wv[tid] = __fdividef(ex, s);
  __syncthreads();
  float ax = 0.f, ay = 0.f, az = 0.f, aw = 0.f;
  const float* tb = text + (size_t)b * LTN * DD + c;
  for (int kk = 0; kk < LTN; ++kk) {
    float wgt = wv[kk];
    if (wgt != 0.f) {
      float4 tv = *(const float4*)(tb + (size_t)kk * DD);
      ax += wgt * tv.x; ay += wgt * tv.y; az += wgt * tv.z; aw += wgt * tv.w;
    }
  }
  float4 o4 = {ax, ay, az, aw};
  *(float4*)(H3 + ((size_t)(b * LNN + qn)) * DD + c) = o4;
}

// ---------------- masked mean pool ----------------
__global__ __launch_bounds__(256) void poolk(const float* __restrict__ H3,
                                             const int* __restrict__ gmask,
                                             float* __restrict__ H4) {
  int b = blockIdx.x, tid = threadIdx.x;
  float cnt = 0.f;
#pragma unroll
  for (int n = 0; n < LNN; ++n) cnt += (gmask[b * LNN + n] != 0) ? 1.f : 0.f;
  cnt = fmaxf(cnt, 9.765625e-04f);
  int c = tid * 4;
  float ax = 0.f, ay = 0.f, az = 0.f, aw = 0.f;
  for (int n = 0; n < LNN; ++n) {
    if (gmask[b * LNN + n] != 0) {
      float4 v = *(const float4*)(H3 + ((size_t)(b * LNN + n)) * DD + c);
      ax += v.x; ay += v.y; az += v.z; aw += v.w;
    }
  }
  float4 o4 = {ax / cnt, ay / cnt, az / cnt, aw / cnt};
  *(float4*)(H4 + (size_t)b * DD + c) = o4;
}

// ---------------- dp1 + exact GELU ----------------
__global__ __launch_bounds__(256) void dp1k(const float* __restrict__ H4,
                                            const float* __restrict__ W,
                                            const float* __restrict__ bias,
                                            float* __restrict__ G) {
  int b = blockIdx.y;
  int j = blockIdx.x * 256 + threadIdx.x;
  __shared__ float h[DD];
  int c = threadIdx.x * 4;
  *(float4*)(h + c) = *(const float4*)(H4 + (size_t)b * DD + c);
  __syncthreads();
  float acc = bias[j];
#pragma unroll 8
  for (int d = 0; d < DD; ++d) acc += h[d] * W[(size_t)d * DHN + j];
  float x = acc;
  G[(size_t)b * DHN + j] = 0.5f * x * (1.f + erff(x * 0.70710678118654752440f));
}

// ---------------- dp2 ----------------
__global__ __launch_bounds__(256) void dp2k(const float* __restrict__ G,
                                            const float* __restrict__ W,
                                            const float* __restrict__ bias,
                                            float* __restrict__ Z) {
  int b = blockIdx.y;
  int j = blockIdx.x * 256 + threadIdx.x;
  __shared__ float h[DHN];
  int c = threadIdx.x * 4;
  *(float4*)(h + c) = *(const float4*)(G + (size_t)b * DHN + c);
  __syncthreads();
  float acc = bias[j];
#pragma unroll 8
  for (int d = 0; d < DHN; ++d) acc += h[d] * W[(size_t)d * DINN + j];
  Z[(size_t)b * DINN + j] = acc;
}

extern "C" void kernel_launch(void* const* d_in, const int* in_sizes, int n_in,
                              void* d_out, int out_size, void* d_ws, size_t ws_size,
                              hipStream_t stream) {
  const float* text = (const float*)d_in[0];
  const float* node = (const float*)d_in[1];
  const float* Wq = (const float*)d_in[2];
  const float* bq = (const float*)d_in[3];
  const float* Wk = (const float*)d_in[4];
  const float* bk = (const float*)d_in[5];
  const float* Wv = (const float*)d_in[6];
  const float* bv = (const float*)d_in[7];
  const float* Wo = (const float*)d_in[8];
  const float* bo = (const float*)d_in[9];
  const float* lng = (const float*)d_in[10];
  const float* lnb = (const float*)d_in[11];
  const float* aqW = (const float*)d_in[12];
  const float* aqb = (const float*)d_in[13];
  const float* akW = (const float*)d_in[14];
  const float* akb = (const float*)d_in[15];
  const float* attv = (const float*)d_in[16];
  const float* attb = (const float*)d_in[17];
  const float* dp1W = (const float*)d_in[18];
  const float* dp1b = (const float*)d_in[19];
  const float* dp2W = (const float*)d_in[20];
  const float* dp2b = (const float*)d_in[21];
  const int* gmask = (const int*)d_in[22];
  const int* lmask = (const int*)d_in[23];
  (void)in_sizes; (void)n_in; (void)out_size; (void)ws_size;

  char* base = (char*)d_ws;
#define MB(x) (((size_t)(x)) << 20)
  ushort* Twt = (ushort*)(base);            // 8MB, reused per weight
  ushort* node_bf = (ushort*)(base + MB(8));   // 1MB
  ushort* text_bf = (ushort*)(base + MB(9));   // 4MB
  ushort* Qb = (ushort*)(base + MB(13));       // 4MB
  ushort* Kb = (ushort*)(base + MB(17));       // 4MB
  ushort* Vb = (ushort*)(base + MB(21));       // 4MB
  ushort* AO = (ushort*)(base + MB(25));       // 4MB
  float* PRE = (float*)(base + MB(13));        // 2MB (aliases Qb, dead then)
  ushort* H2 = (ushort*)(base + MB(17));       // 1MB (aliases Kb)
  float* QBu = (float*)(base + MB(21));        // 2MB (aliases Vb)
  float* KBu = (float*)(base + MB(25));        // 8MB (aliases AO)
  float* H3 = (float*)(base + MB(13));         // 2MB (aliases PRE)
  float* H4 = (float*)(base + MB(33));         // 32KB
  float* G = (float*)(base + MB(33) + 32768);  // 32KB
  float* Z = (float*)d_out;
#undef MB

  const int M1 = NB * LNN;  // 512
  dim3 blk(256);

  cvtk<<<dim3(512 * 1024 / 2048), blk, 0, stream>>>(node, node_bf, 512 * 1024);
  cvtk<<<dim3(NB * LTN * DD / 2048), blk, 0, stream>>>(text, text_bf, NB * LTN * DD);

  // QKV projections (bf16 MFMA)
  tcvt<<<dim3(HDD / 64, DD / 64), blk, 0, stream>>>(Wq, Twt, DD, HDD);
  gemm_mfma<1, 0><<<dim3(HDD / 64, M1 / 64), blk, 0, stream>>>(node_bf, Twt, bq, nullptr, Qb, M1, HDD, DD);
  tcvt<<<dim3(HDD / 64, DD / 64), blk, 0, stream>>>(Wk, Twt, DD, HDD);
  gemm_mfma<1, 0><<<dim3(HDD / 64, M1 / 64), blk, 0, stream>>>(node_bf, Twt, bk, nullptr, Kb, M1, HDD, DD);
  tcvt<<<dim3(HDD / 64, DD / 64), blk, 0, stream>>>(Wv, Twt, DD, HDD);
  gemm_mfma<1, 0><<<dim3(HDD / 64, M1 / 64), blk, 0, stream>>>(node_bf, Twt, bv, nullptr, Vb, M1, HDD, DD);

  // self-attention
  attn_kernel<<<dim3(NB * NH), dim3(1024), 0, stream>>>(Qb, Kb, Vb, gmask, AO);

  // output proj + residual (fp32 out)
  tcvt<<<dim3(DD / 64, HDD / 64), blk, 0, stream>>>(Wo, Twt, HDD, DD);
  gemm_mfma<0, 1><<<dim3(DD / 64, M1 / 64), blk, 0, stream>>>(AO, Twt, bo, node, PRE, M1, DD, HDD);

  // layernorm -> bf16
  lnorm<<<dim3(M1), blk, 0, stream>>>(PRE, lng, lnb, H2);

  // additive attention projections
  tcvt<<<dim3(DD / 64, DD / 64), blk, 0, stream>>>(aqW, Twt, DD, DD);
  gemm_mfma<0, 0><<<dim3(DD / 64, M1 / 64), blk, 0, stream>>>(H2, Twt, aqb, nullptr, QBu, M1, DD, DD);
  tcvt<<<dim3(DD / 64, DD / 64), blk, 0, stream>>>(akW, Twt, DD, DD);
  gemm_mfma<0, 0><<<dim3(DD / 64, (NB * LTN) / 64), blk, 0, stream>>>(text_bf, Twt, akb, nullptr, KBu, NB * LTN, DD, DD);

  // additive attention + context
  addattn<<<dim3(NB * LNN), blk, 0, stream>>>(QBu, KBu, text, lmask, attv, attb, H3);

  // pool + MLP
  poolk<<<dim3(NB), blk, 0, stream>>>(H3, gmask, H4);
  dp1k<<<dim3(DHN / 256, NB), blk, 0, stream>>>(H4, dp1W, dp1b, G);
  dp2k<<<dim3(DINN / 256, NB), blk, 0, stream>>>(G, dp2W, dp2b, Z);
}

// Round 3
// 396.298 us; speedup vs baseline: 3.0275x; 1.5601x over previous
//
#include <hip/hip_runtime.h>
#include <hip/hip_bf16.h>
#include <math.h>

#define NB 8        // batch
#define LNN 64      // nodes
#define LTN 256     // text len
#define DD 1024     // model dim
#define NH 4        // heads (each full width D)
#define HDD 4096    // NH*DD
#define DINN 2048
#define DHN 1024    // DIN/2

typedef __bf16 bf16x8 __attribute__((ext_vector_type(8)));
typedef float f32x4 __attribute__((ext_vector_type(4)));

__device__ __forceinline__ float b2f(ushort u) {
  union { float f; unsigned int i; } x; x.i = ((unsigned int)u) << 16; return x.f;
}
__device__ __forceinline__ ushort f2b(float f) {
  unsigned int u = __builtin_bit_cast(unsigned int, f);
  u = (u + 0x7FFFu + ((u >> 16) & 1u)) >> 16;
  return (ushort)u;
}

// ---------------- fp32 -> bf16 elementwise (n % 2048 == 0) ----------------
__global__ __launch_bounds__(256) void cvtk(const float* __restrict__ in,
                                            ushort* __restrict__ out, int n) {
  int i = (blockIdx.x * 256 + threadIdx.x) * 8;
  if (i >= n) return;
  float4 a = *(const float4*)(in + i);
  float4 b = *(const float4*)(in + i + 4);
  ushort4 o0 = {f2b(a.x), f2b(a.y), f2b(a.z), f2b(a.w)};
  ushort4 o1 = {f2b(b.x), f2b(b.y), f2b(b.z), f2b(b.w)};
  *(ushort4*)(out + i) = o0;
  *(ushort4*)(out + i + 4) = o1;
}

// ---------------- transpose + convert: W[K][N] fp32 -> Wt[N][K] bf16 ----------------
__global__ __launch_bounds__(256) void tcvt(const float* __restrict__ W,
                                            ushort* __restrict__ Wt, int K, int N) {
  __shared__ float tf[64][65];
  int k0 = blockIdx.y << 6, n0 = blockIdx.x << 6;
  int t = threadIdx.x;
  int r = t >> 2, c4 = (t & 3) * 16;
  const float* src = W + (size_t)(k0 + r) * N + n0 + c4;
  float4 v0 = *(const float4*)(src);
  float4 v1 = *(const float4*)(src + 4);
  float4 v2 = *(const float4*)(src + 8);
  float4 v3 = *(const float4*)(src + 12);
  *(float4*)&tf[r][c4] = v0;
  *(float4*)&tf[r][c4 + 4] = v1;
  *(float4*)&tf[r][c4 + 8] = v2;
  *(float4*)&tf[r][c4 + 12] = v3;
  __syncthreads();
  int nl = t >> 2, kc = (t & 3) * 16;
  ushort tmp[16];
#pragma unroll
  for (int j = 0; j < 16; ++j) tmp[j] = f2b(tf[kc + j][nl]);
  ushort* dst = Wt + (size_t)(n0 + nl) * K + k0 + kc;
  *(uint4*)(dst) = *(uint4*)&tmp[0];
  *(uint4*)(dst + 8) = *(uint4*)&tmp[8];
}

// ---------------- bf16 MFMA GEMM: C[M,N] = A[M,K] @ Bt[N,K]^T + bias (+res) ----------------
template <int OUTBF, int RES>
__global__ __launch_bounds__(256) void gemm_mfma(const ushort* __restrict__ A,
                                                 const ushort* __restrict__ Bt,
                                                 const float* __restrict__ bias,
                                                 const float* __restrict__ res,
                                                 void* __restrict__ Cout,
                                                 int M, int N, int K) {
  __shared__ ushort Als[64 * 64];
  __shared__ ushort Bls[64 * 64];
  int tid = threadIdx.x;
  int m0 = blockIdx.y << 6, n0 = blockIdx.x << 6;

  int srow = tid >> 2;
  int su0 = (tid & 3) * 2;
  const ushort* ga = A + (size_t)(m0 + srow) * K + su0 * 8;
  const ushort* gb = Bt + (size_t)(n0 + srow) * K + su0 * 8;
  int wa0 = srow * 64 + ((su0) ^ (srow & 7)) * 8;
  int wa1 = srow * 64 + ((su0 + 1) ^ (srow & 7)) * 8;

  int lane = tid & 63, w = tid >> 6;
  int wm = w >> 1, wn = w & 1;
  int r = lane & 15, kg = lane >> 4;

  f32x4 acc[2][2] = {};

  uint4 pa0 = *(const uint4*)(ga);
  uint4 pa1 = *(const uint4*)(ga + 8);
  uint4 pb0 = *(const uint4*)(gb);
  uint4 pb1 = *(const uint4*)(gb + 8);

  for (int k0 = 0; k0 < K; k0 += 64) {
    __syncthreads();
    *(uint4*)&Als[wa0] = pa0; *(uint4*)&Als[wa1] = pa1;
    *(uint4*)&Bls[wa0] = pb0; *(uint4*)&Bls[wa1] = pb1;
    __syncthreads();
    int kn = k0 + 64;
    if (kn < K) {
      pa0 = *(const uint4*)(ga + kn);
      pa1 = *(const uint4*)(ga + kn + 8);
      pb0 = *(const uint4*)(gb + kn);
      pb1 = *(const uint4*)(gb + kn + 8);
    }
#pragma unroll
    for (int h = 0; h < 2; ++h) {
      int sa = ((h * 4 + kg) ^ (r & 7)) * 8;
      bf16x8 af[2], bfr[2];
#pragma unroll
      for (int m = 0; m < 2; ++m)
        af[m] = *(const bf16x8*)&Als[(wm * 32 + m * 16 + r) * 64 + sa];
#pragma unroll
      for (int n = 0; n < 2; ++n)
        bfr[n] = *(const bf16x8*)&Bls[(wn * 32 + n * 16 + r) * 64 + sa];
#pragma unroll
      for (int m = 0; m < 2; ++m)
#pragma unroll
        for (int n = 0; n < 2; ++n)
          acc[m][n] = __builtin_amdgcn_mfma_f32_16x16x32_bf16(af[m], bfr[n], acc[m][n], 0, 0, 0);
    }
  }
#pragma unroll
  for (int m = 0; m < 2; ++m)
#pragma unroll
    for (int n = 0; n < 2; ++n) {
      f32x4 a = acc[m][n];
#pragma unroll
      for (int v = 0; v < 4; ++v) {
        int row = m0 + wm * 32 + m * 16 + kg * 4 + v;
        int col = n0 + wn * 32 + n * 16 + r;
        float x = a[v] + bias[col];
        if constexpr (RES) x += res[(size_t)row * N + col];
        if constexpr (OUTBF) ((ushort*)Cout)[(size_t)row * N + col] = f2b(x);
        else ((float*)Cout)[(size_t)row * N + col] = x;
      }
    }
}

// ---------------- attn part 1: S = softmax(Q K^T / 32) per (b,h) -> P bf16 ----------------
__global__ __launch_bounds__(256) void attn_scores(const ushort* __restrict__ Qb,
                                                   const ushort* __restrict__ Kb,
                                                   const int* __restrict__ gmask,
                                                   ushort* __restrict__ P) {
  int bh = blockIdx.x;
  int b = bh >> 2;
  size_t base = ((size_t)b * LNN) * HDD + (size_t)(bh & 3) * DD;
  __shared__ ushort Als[64 * 64];
  __shared__ ushort Bls[64 * 64];
  __shared__ float S[64][68];
  int tid = threadIdx.x;
  int srow = tid >> 2, su0 = (tid & 3) * 2;
  const ushort* ga = Qb + base + (size_t)srow * HDD + su0 * 8;
  const ushort* gb = Kb + base + (size_t)srow * HDD + su0 * 8;
  int wa0 = srow * 64 + ((su0) ^ (srow & 7)) * 8;
  int wa1 = srow * 64 + ((su0 + 1) ^ (srow & 7)) * 8;
  int lane = tid & 63, w = tid >> 6;
  int wm = w >> 1, wn = w & 1;
  int r = lane & 15, kg = lane >> 4;
  f32x4 acc[2][2] = {};
  uint4 pa0 = *(const uint4*)(ga);
  uint4 pa1 = *(const uint4*)(ga + 8);
  uint4 pb0 = *(const uint4*)(gb);
  uint4 pb1 = *(const uint4*)(gb + 8);
  for (int k0 = 0; k0 < DD; k0 += 64) {
    __syncthreads();
    *(uint4*)&Als[wa0] = pa0; *(uint4*)&Als[wa1] = pa1;
    *(uint4*)&Bls[wa0] = pb0; *(uint4*)&Bls[wa1] = pb1;
    __syncthreads();
    int kn = k0 + 64;
    if (kn < DD) {
      pa0 = *(const uint4*)(ga + kn);
      pa1 = *(const uint4*)(ga + kn + 8);
      pb0 = *(const uint4*)(gb + kn);
      pb1 = *(const uint4*)(gb + kn + 8);
    }
#pragma unroll
    for (int h = 0; h < 2; ++h) {
      int sa = ((h * 4 + kg) ^ (r & 7)) * 8;
      bf16x8 af[2], bfr[2];
#pragma unroll
      for (int m = 0; m < 2; ++m)
        af[m] = *(const bf16x8*)&Als[(wm * 32 + m * 16 + r) * 64 + sa];
#pragma unroll
      for (int n = 0; n < 2; ++n)
        bfr[n] = *(const bf16x8*)&Bls[(wn * 32 + n * 16 + r) * 64 + sa];
#pragma unroll
      for (int m = 0; m < 2; ++m)
#pragma unroll
        for (int n = 0; n < 2; ++n)
          acc[m][n] = __builtin_amdgcn_mfma_f32_16x16x32_bf16(af[m], bfr[n], acc[m][n], 0, 0, 0);
    }
  }
#pragma unroll
  for (int m = 0; m < 2; ++m)
#pragma unroll
    for (int n = 0; n < 2; ++n)
#pragma unroll
      for (int v = 0; v < 4; ++v)
        S[wm * 32 + m * 16 + kg * 4 + v][wn * 32 + n * 16 + r] = acc[m][n][v];
  __syncthreads();
  // softmax: wave w handles rows w*16 .. w*16+15; lane = k index
  bool valid = gmask[b * LNN + lane] != 0;
  for (int i = 0; i < 16; ++i) {
    int q = w * 16 + i;
    float v = valid ? S[q][lane] * 0.03125f : -__builtin_inff();
    float mx = v;
    for (int o = 32; o; o >>= 1) mx = fmaxf(mx, __shfl_xor(mx, o, 64));
    float e = valid ? __expf(v - mx) : 0.f;
    float s = e;
    for (int o = 32; o; o >>= 1) s += __shfl_xor(s, o, 64);
    P[(size_t)bh * 4096 + q * 64 + lane] = f2b(__fdividef(e, s));
  }
}

// ---------------- attn part 2: O[q,d-tile] = P @ V per (b,h,dtile) ----------------
__global__ __launch_bounds__(256) void attn_pv(const ushort* __restrict__ P,
                                               const ushort* __restrict__ Vb,
                                               ushort* __restrict__ AO) {
  int bid = blockIdx.x;
  int bh = bid >> 4, dt = bid & 15;
  int d0 = dt * 64;
  size_t vbase = ((size_t)(bh >> 2) * LNN) * HDD + (size_t)(bh & 3) * DD;
  __shared__ ushort Pls[64 * 72];  // q rows (stride 144B), k cols
  __shared__ ushort Vt[64 * 72];   // d rows (stride 144B), k cols (transposed V)
  int tid = threadIdx.x;
  {
    int row = tid >> 2, c = (tid & 3) * 16;
    const ushort* src = P + (size_t)bh * 4096 + row * 64 + c;
    uint4 v0 = *(const uint4*)src;
    uint4 v1 = *(const uint4*)(src + 8);
    *(uint4*)&Pls[row * 72 + c] = v0;
    *(uint4*)&Pls[row * 72 + c + 8] = v1;
  }
  {
    int kq = tid >> 2, dq = (tid & 3) * 16;
    const ushort* src = Vb + vbase + (size_t)kq * HDD + d0 + dq;
    uint4 v0 = *(const uint4*)src;
    uint4 v1 = *(const uint4*)(src + 8);
    ushort tmp[16];
    *(uint4*)&tmp[0] = v0;
    *(uint4*)&tmp[8] = v1;
#pragma unroll
    for (int j = 0; j < 16; ++j) Vt[(dq + j) * 72 + kq] = tmp[j];
  }
  __syncthreads();
  int lane = tid & 63, w = tid >> 6;
  int wm = w >> 1, wn = w & 1;
  int r = lane & 15, kg = lane >> 4;
  f32x4 acc[2][2] = {};
#pragma unroll
  for (int h = 0; h < 2; ++h) {
    int ko = h * 32 + kg * 8;
    bf16x8 af[2], bfr[2];
#pragma unroll
    for (int m = 0; m < 2; ++m)
      af[m] = *(const bf16x8*)&Pls[(wm * 32 + m * 16 + r) * 72 + ko];
#pragma unroll
    for (int n = 0; n < 2; ++n)
      bfr[n] = *(const bf16x8*)&Vt[(wn * 32 + n * 16 + r) * 72 + ko];
#pragma unroll
    for (int m = 0; m < 2; ++m)
#pragma unroll
      for (int n = 0; n < 2; ++n)
        acc[m][n] = __builtin_amdgcn_mfma_f32_16x16x32_bf16(af[m], bfr[n], acc[m][n], 0, 0, 0);
  }
#pragma unroll
  for (int m = 0; m < 2; ++m)
#pragma unroll
    for (int n = 0; n < 2; ++n) {
      f32x4 a = acc[m][n];
#pragma unroll
      for (int v = 0; v < 4; ++v) {
        int q = wm * 32 + m * 16 + kg * 4 + v;
        int col = wn * 32 + n * 16 + r;
        AO[vbase + (size_t)q * HDD + d0 + col] = f2b(a[v]);
      }
    }
}

// ---------------- LayerNorm per row over D=1024, bf16 out ----------------
__global__ __launch_bounds__(256) void lnorm(const float* __restrict__ X,
                                             const float* __restrict__ g,
                                             const float* __restrict__ be,
                                             ushort* __restrict__ Y) {
  int row = blockIdx.x, tid = threadIdx.x;
  int c = tid * 4;
  float4 v = *(const float4*)(X + (size_t)row * DD + c);
  float s = v.x + v.y + v.z + v.w;
  float ss = v.x * v.x + v.y * v.y + v.z * v.z + v.w * v.w;
  for (int o = 32; o; o >>= 1) {
    s += __shfl_xor(s, o, 64);
    ss += __shfl_xor(ss, o, 64);
  }
  __shared__ float rb_[8];
  int lane = tid & 63, w = tid >> 6;
  if (lane == 0) { rb_[w] = s; rb_[4 + w] = ss; }
  __syncthreads();
  s = rb_[0] + rb_[1] + rb_[2] + rb_[3];
  ss = rb_[4] + rb_[5] + rb_[6] + rb_[7];
  float mu = s * (1.f / 1024.f);
  float var = ss * (1.f / 1024.f) - mu * mu;
  float rstd = rsqrtf(var + 1e-5f);
  ushort4 o4;
  o4.x = f2b((v.x - mu) * rstd * g[c + 0] + be[c + 0]);
  o4.y = f2b((v.y - mu) * rstd * g[c + 1] + be[c + 1]);
  o4.z = f2b((v.z - mu) * rstd * g[c + 2] + be[c + 2]);
  o4.w = f2b((v.w - mu) * rstd * g[c + 3] + be[c + 3]);
  *(ushort4*)(Y + (size_t)row * DD + c) = o4;
}

__device__ __forceinline__ float ftanh(float x) {
  float e = __expf(2.f * x);
  return 1.f - __fdividef(2.f, e + 1.f);
}

// ---------------- additive attention per (b,qn) ----------------
__global__ __launch_bounds__(256) void addattn(const float* __restrict__ QBu,
                                               const float* __restrict__ KBu,
                                               const float* __restrict__ text,
                                               const int* __restrict__ lmask,
                                               const float* __restrict__ av_,
                                               const float* __restrict__ ab_,
                                               float* __restrict__ H3) {
  int b = blockIdx.x >> 6;
  int qn = blockIdx.x & 63;
  __shared__ float qrow[DD], av[DD], ab[DD];
  __shared__ float wv[LTN];
  __shared__ float rb_[8];
  int tid = threadIdx.x;
  int c = tid * 4;
  *(float4*)(qrow + c) = *(const float4*)(QBu + ((size_t)(b * LNN + qn)) * DD + c);
  *(float4*)(av + c) = *(const float4*)(av_ + c);
  *(float4*)(ab + c) = *(const float4*)(ab_ + c);
  __syncthreads();
  bool valid = lmask[b * LTN + tid] != 0;
  float e = -__builtin_inff();
  if (valid) {
    const float* kr = KBu + ((size_t)(b * LTN + tid)) * DD;
    float acc = 0.f;
#pragma unroll 4
    for (int d = 0; d < DD; d += 4) {
      float4 kv = *(const float4*)(kr + d);
      acc += av[d + 0] * ftanh(qrow[d + 0] + kv.x + ab[d + 0]);
      acc += av[d + 1] * ftanh(qrow[d + 1] + kv.y + ab[d + 1]);
      acc += av[d + 2] * ftanh(qrow[d + 2] + kv.z + ab[d + 2]);
      acc += av[d + 3] * ftanh(qrow[d + 3] + kv.w + ab[d + 3]);
    }
    e = acc;
  }
  int lane = tid & 63, w = tid >> 6;
  float m = e;
  for (int o = 32; o; o >>= 1) m = fmaxf(m, __shfl_xor(m, o, 64));
  if (lane == 0) rb_[w] = m;
  __syncthreads();
  m = fmaxf(fmaxf(rb_[0], rb_[1]), fmaxf(rb_[2], rb_[3]));
  float ex = valid ? __expf(e - m) : 0.f;
  float s = ex;
  for (int o = 32; o; o >>= 1) s += __shfl_xor(s, o, 64);
  if (lane == 0) rb_[4 + w] = s;
  __syncthreads();
  s = rb_[4] + rb_[5] + rb_[6] + rb_[7];
  wv[tid] = __fdividef(ex, s);
  __syncthreads();
  float ax = 0.f, ay = 0.f, az = 0.f, aw = 0.f;
  const float* tb = text + (size_t)b * LTN * DD + c;
  for (int kk = 0; kk < LTN; ++kk) {
    float wgt = wv[kk];
    if (wgt != 0.f) {
      float4 tv = *(const float4*)(tb + (size_t)kk * DD);
      ax += wgt * tv.x; ay += wgt * tv.y; az += wgt * tv.z; aw += wgt * tv.w;
    }
  }
  float4 o4 = {ax, ay, az, aw};
  *(float4*)(H3 + ((size_t)(b * LNN + qn)) * DD + c) = o4;
}

// ---------------- masked mean pool ----------------
__global__ __launch_bounds__(256) void poolk(const float* __restrict__ H3,
                                             const int* __restrict__ gmask,
                                             float* __restrict__ H4) {
  int b = blockIdx.x, tid = threadIdx.x;
  float cnt = 0.f;
#pragma unroll
  for (int n = 0; n < LNN; ++n) cnt += (gmask[b * LNN + n] != 0) ? 1.f : 0.f;
  cnt = fmaxf(cnt, 9.765625e-04f);
  int c = tid * 4;
  float ax = 0.f, ay = 0.f, az = 0.f, aw = 0.f;
  for (int n = 0; n < LNN; ++n) {
    if (gmask[b * LNN + n] != 0) {
      float4 v = *(const float4*)(H3 + ((size_t)(b * LNN + n)) * DD + c);
      ax += v.x; ay += v.y; az += v.z; aw += v.w;
    }
  }
  float4 o4 = {ax / cnt, ay / cnt, az / cnt, aw / cnt};
  *(float4*)(H4 + (size_t)b * DD + c) = o4;
}

// ---------------- dp1 + exact GELU ----------------
__global__ __launch_bounds__(256) void dp1k(const float* __restrict__ H4,
                                            const float* __restrict__ W,
                                            const float* __restrict__ bias,
                                            float* __restrict__ G) {
  int b = blockIdx.y;
  int j = blockIdx.x * 256 + threadIdx.x;
  __shared__ float h[DD];
  int c = threadIdx.x * 4;
  *(float4*)(h + c) = *(const float4*)(H4 + (size_t)b * DD + c);
  __syncthreads();
  float acc = bias[j];
#pragma unroll 8
  for (int d = 0; d < DD; ++d) acc += h[d] * W[(size_t)d * DHN + j];
  float x = acc;
  G[(size_t)b * DHN + j] = 0.5f * x * (1.f + erff(x * 0.70710678118654752440f));
}

// ---------------- dp2 ----------------
__global__ __launch_bounds__(256) void dp2k(const float* __restrict__ G,
                                            const float* __restrict__ W,
                                            const float* __restrict__ bias,
                                            float* __restrict__ Z) {
  int b = blockIdx.y;
  int j = blockIdx.x * 256 + threadIdx.x;
  __shared__ float h[DHN];
  int c = threadIdx.x * 4;
  *(float4*)(h + c) = *(const float4*)(G + (size_t)b * DHN + c);
  __syncthreads();
  float acc = bias[j];
#pragma unroll 8
  for (int d = 0; d < DHN; ++d) acc += h[d] * W[(size_t)d * DINN + j];
  Z[(size_t)b * DINN + j] = acc;
}

extern "C" void kernel_launch(void* const* d_in, const int* in_sizes, int n_in,
                              void* d_out, int out_size, void* d_ws, size_t ws_size,
                              hipStream_t stream) {
  const float* text = (const float*)d_in[0];
  const float* node = (const float*)d_in[1];
  const float* Wq = (const float*)d_in[2];
  const float* bq = (const float*)d_in[3];
  const float* Wk = (const float*)d_in[4];
  const float* bk = (const float*)d_in[5];
  const float* Wv = (const float*)d_in[6];
  const float* bv = (const float*)d_in[7];
  const float* Wo = (const float*)d_in[8];
  const float* bo = (const float*)d_in[9];
  const float* lng = (const float*)d_in[10];
  const float* lnb = (const float*)d_in[11];
  const float* aqW = (const float*)d_in[12];
  const float* aqb = (const float*)d_in[13];
  const float* akW = (const float*)d_in[14];
  const float* akb = (const float*)d_in[15];
  const float* attv = (const float*)d_in[16];
  const float* attb = (const float*)d_in[17];
  const float* dp1W = (const float*)d_in[18];
  const float* dp1b = (const float*)d_in[19];
  const float* dp2W = (const float*)d_in[20];
  const float* dp2b = (const float*)d_in[21];
  const int* gmask = (const int*)d_in[22];
  const int* lmask = (const int*)d_in[23];
  (void)in_sizes; (void)n_in; (void)out_size; (void)ws_size;

  char* base = (char*)d_ws;
#define MB(x) (((size_t)(x)) << 20)
  ushort* Twt = (ushort*)(base);               // 8MB, reused per weight
  ushort* node_bf = (ushort*)(base + MB(8));   // 1MB
  ushort* text_bf = (ushort*)(base + MB(9));   // 4MB
  ushort* Qb = (ushort*)(base + MB(13));       // 4MB
  ushort* Kb = (ushort*)(base + MB(17));       // 4MB
  ushort* Vb = (ushort*)(base + MB(21));       // 4MB
  ushort* AO = (ushort*)(base + MB(25));       // 4MB
  float* PRE = (float*)(base + MB(13));        // 2MB (aliases Qb, dead then)
  ushort* H2 = (ushort*)(base + MB(17));       // 1MB (aliases Kb)
  float* QBu = (float*)(base + MB(21));        // 2MB (aliases Vb)
  float* KBu = (float*)(base + MB(25));        // 8MB (aliases AO)
  float* H4 = (float*)(base + MB(33));         // 32KB
  float* G = (float*)(base + MB(33) + 32768);  // 32KB
  ushort* Pws = (ushort*)(base + MB(33) + 65536);  // 256KB attn probs
  float* H3 = (float*)(base + MB(13));         // 2MB (aliases PRE)
  float* Z = (float*)d_out;
#undef MB

  const int M1 = NB * LNN;  // 512
  dim3 blk(256);

  cvtk<<<dim3(512 * 1024 / 2048), blk, 0, stream>>>(node, node_bf, 512 * 1024);
  cvtk<<<dim3(NB * LTN * DD / 2048), blk, 0, stream>>>(text, text_bf, NB * LTN * DD);

  // QKV projections (bf16 MFMA)
  tcvt<<<dim3(HDD / 64, DD / 64), blk, 0, stream>>>(Wq, Twt, DD, HDD);
  gemm_mfma<1, 0><<<dim3(HDD / 64, M1 / 64), blk, 0, stream>>>(node_bf, Twt, bq, nullptr, Qb, M1, HDD, DD);
  tcvt<<<dim3(HDD / 64, DD / 64), blk, 0, stream>>>(Wk, Twt, DD, HDD);
  gemm_mfma<1, 0><<<dim3(HDD / 64, M1 / 64), blk, 0, stream>>>(node_bf, Twt, bk, nullptr, Kb, M1, HDD, DD);
  tcvt<<<dim3(HDD / 64, DD / 64), blk, 0, stream>>>(Wv, Twt, DD, HDD);
  gemm_mfma<1, 0><<<dim3(HDD / 64, M1 / 64), blk, 0, stream>>>(node_bf, Twt, bv, nullptr, Vb, M1, HDD, DD);

  // self-attention (MFMA scores + MFMA PV)
  attn_scores<<<dim3(NB * NH), blk, 0, stream>>>(Qb, Kb, gmask, Pws);
  attn_pv<<<dim3(NB * NH * 16), blk, 0, stream>>>(Pws, Vb, AO);

  // output proj + residual (fp32 out)
  tcvt<<<dim3(DD / 64, HDD / 64), blk, 0, stream>>>(Wo, Twt, HDD, DD);
  gemm_mfma<0, 1><<<dim3(DD / 64, M1 / 64), blk, 0, stream>>>(AO, Twt, bo, node, PRE, M1, DD, HDD);

  // layernorm -> bf16
  lnorm<<<dim3(M1), blk, 0, stream>>>(PRE, lng, lnb, H2);

  // additive attention projections
  tcvt<<<dim3(DD / 64, DD / 64), blk, 0, stream>>>(aqW, Twt, DD, DD);
  gemm_mfma<0, 0><<<dim3(DD / 64, M1 / 64), blk, 0, stream>>>(H2, Twt, aqb, nullptr, QBu, M1, DD, DD);
  tcvt<<<dim3(DD / 64, DD / 64), blk, 0, stream>>>(akW, Twt, DD, DD);
  gemm_mfma<0, 0><<<dim3(DD / 64, (NB * LTN) / 64), blk, 0, stream>>>(text_bf, Twt, akb, nullptr, KBu, NB * LTN, DD, DD);

  // additive attention + context
  addattn<<<dim3(NB * LNN), blk, 0, stream>>>(QBu, KBu, text, lmask, attv, attb, H3);

  // pool + MLP
  poolk<<<dim3(NB), blk, 0, stream>>>(H3, gmask, H4);
  dp1k<<<dim3(DHN / 256, NB), blk, 0, stream>>>(H4, dp1W, dp1b, G);
  dp2k<<<dim3(DINN / 256, NB), blk, 0, stream>>>(G, dp2W, dp2b, Z);
}

// Round 4
// 337.095 us; speedup vs baseline: 3.5592x; 1.1756x over previous
//
#include <hip/hip_runtime.h>
#include <hip/hip_bf16.h>
#include <math.h>

#define NB 8        // batch
#define LNN 64      // nodes
#define LTN 256     // text len
#define DD 1024     // model dim
#define NH 4        // heads (each full width D)
#define HDD 4096    // NH*DD
#define DINN 2048
#define DHN 1024    // DIN/2

// 2*log2(e): tanh(x) = 1 - 2/(exp2(x*C)+1)
#define C_TANH 2.8853900817779268f

typedef __bf16 bf16x8 __attribute__((ext_vector_type(8)));
typedef float f32x4 __attribute__((ext_vector_type(4)));

__device__ __forceinline__ float b2f(ushort u) {
  union { float f; unsigned int i; } x; x.i = ((unsigned int)u) << 16; return x.f;
}
__device__ __forceinline__ ushort f2b(float f) {
  unsigned int u = __builtin_bit_cast(unsigned int, f);
  u = (u + 0x7FFFu + ((u >> 16) & 1u)) >> 16;
  return (ushort)u;
}

// ---------------- fp32 -> bf16 elementwise (n % 2048 == 0) ----------------
__global__ __launch_bounds__(256) void cvtk(const float* __restrict__ in,
                                            ushort* __restrict__ out, int n) {
  int i = (blockIdx.x * 256 + threadIdx.x) * 8;
  if (i >= n) return;
  float4 a = *(const float4*)(in + i);
  float4 b = *(const float4*)(in + i + 4);
  ushort4 o0 = {f2b(a.x), f2b(a.y), f2b(a.z), f2b(a.w)};
  ushort4 o1 = {f2b(b.x), f2b(b.y), f2b(b.z), f2b(b.w)};
  *(ushort4*)(out + i) = o0;
  *(ushort4*)(out + i + 4) = o1;
}

// ---------------- transpose + convert: W[K][N] fp32 -> Wt[N][K] bf16 ----------------
__global__ __launch_bounds__(256) void tcvt(const float* __restrict__ W,
                                            ushort* __restrict__ Wt, int K, int N) {
  __shared__ float tf[64][65];
  int k0 = blockIdx.y << 6, n0 = blockIdx.x << 6;
  int t = threadIdx.x;
  int r = t >> 2, c4 = (t & 3) * 16;
  const float* src = W + (size_t)(k0 + r) * N + n0 + c4;
  float4 v0 = *(const float4*)(src);
  float4 v1 = *(const float4*)(src + 4);
  float4 v2 = *(const float4*)(src + 8);
  float4 v3 = *(const float4*)(src + 12);
  *(float4*)&tf[r][c4] = v0;
  *(float4*)&tf[r][c4 + 4] = v1;
  *(float4*)&tf[r][c4 + 8] = v2;
  *(float4*)&tf[r][c4 + 12] = v3;
  __syncthreads();
  int nl = t >> 2, kc = (t & 3) * 16;
  ushort tmp[16];
#pragma unroll
  for (int j = 0; j < 16; ++j) tmp[j] = f2b(tf[kc + j][nl]);
  ushort* dst = Wt + (size_t)(n0 + nl) * K + k0 + kc;
  *(uint4*)(dst) = *(uint4*)&tmp[0];
  *(uint4*)(dst + 8) = *(uint4*)&tmp[8];
}

// ---------------- bf16 MFMA GEMM: C[M,N] = (A[M,K] @ Bt[N,K]^T + b1 (+b2) (+res)) * scale ----------------
template <int OUTBF, int RES>
__global__ __launch_bounds__(256) void gemm_mfma(const ushort* __restrict__ A,
                                                 const ushort* __restrict__ Bt,
                                                 const float* __restrict__ bias,
                                                 const float* __restrict__ bias2,
                                                 const float* __restrict__ res,
                                                 void* __restrict__ Cout,
                                                 int M, int N, int K, float scale) {
  __shared__ ushort Als[64 * 64];
  __shared__ ushort Bls[64 * 64];
  int tid = threadIdx.x;
  int m0 = blockIdx.y << 6, n0 = blockIdx.x << 6;

  int srow = tid >> 2;
  int su0 = (tid & 3) * 2;
  const ushort* ga = A + (size_t)(m0 + srow) * K + su0 * 8;
  const ushort* gb = Bt + (size_t)(n0 + srow) * K + su0 * 8;
  int wa0 = srow * 64 + ((su0) ^ (srow & 7)) * 8;
  int wa1 = srow * 64 + ((su0 + 1) ^ (srow & 7)) * 8;

  int lane = tid & 63, w = tid >> 6;
  int wm = w >> 1, wn = w & 1;
  int r = lane & 15, kg = lane >> 4;

  f32x4 acc[2][2] = {};

  uint4 pa0 = *(const uint4*)(ga);
  uint4 pa1 = *(const uint4*)(ga + 8);
  uint4 pb0 = *(const uint4*)(gb);
  uint4 pb1 = *(const uint4*)(gb + 8);

  for (int k0 = 0; k0 < K; k0 += 64) {
    __syncthreads();
    *(uint4*)&Als[wa0] = pa0; *(uint4*)&Als[wa1] = pa1;
    *(uint4*)&Bls[wa0] = pb0; *(uint4*)&Bls[wa1] = pb1;
    __syncthreads();
    int kn = k0 + 64;
    if (kn < K) {
      pa0 = *(const uint4*)(ga + kn);
      pa1 = *(const uint4*)(ga + kn + 8);
      pb0 = *(const uint4*)(gb + kn);
      pb1 = *(const uint4*)(gb + kn + 8);
    }
#pragma unroll
    for (int h = 0; h < 2; ++h) {
      int sa = ((h * 4 + kg) ^ (r & 7)) * 8;
      bf16x8 af[2], bfr[2];
#pragma unroll
      for (int m = 0; m < 2; ++m)
        af[m] = *(const bf16x8*)&Als[(wm * 32 + m * 16 + r) * 64 + sa];
#pragma unroll
      for (int n = 0; n < 2; ++n)
        bfr[n] = *(const bf16x8*)&Bls[(wn * 32 + n * 16 + r) * 64 + sa];
#pragma unroll
      for (int m = 0; m < 2; ++m)
#pragma unroll
        for (int n = 0; n < 2; ++n)
          acc[m][n] = __builtin_amdgcn_mfma_f32_16x16x32_bf16(af[m], bfr[n], acc[m][n], 0, 0, 0);
    }
  }
#pragma unroll
  for (int m = 0; m < 2; ++m)
#pragma unroll
    for (int n = 0; n < 2; ++n) {
      f32x4 a = acc[m][n];
#pragma unroll
      for (int v = 0; v < 4; ++v) {
        int row = m0 + wm * 32 + m * 16 + kg * 4 + v;
        int col = n0 + wn * 32 + n * 16 + r;
        float x = a[v] + bias[col];
        if (bias2) x += bias2[col];
        if constexpr (RES) x += res[(size_t)row * N + col];
        x *= scale;
        if constexpr (OUTBF) ((ushort*)Cout)[(size_t)row * N + col] = f2b(x);
        else ((float*)Cout)[(size_t)row * N + col] = x;
      }
    }
}

// ---------------- attn part 1: S = softmax(Q K^T / 32) per (b,h) -> P bf16 ----------------
__global__ __launch_bounds__(256) void attn_scores(const ushort* __restrict__ Qb,
                                                   const ushort* __restrict__ Kb,
                                                   const int* __restrict__ gmask,
                                                   ushort* __restrict__ P) {
  int bh = blockIdx.x;
  int b = bh >> 2;
  size_t base = ((size_t)b * LNN) * HDD + (size_t)(bh & 3) * DD;
  __shared__ ushort Als[64 * 64];
  __shared__ ushort Bls[64 * 64];
  __shared__ float S[64][68];
  int tid = threadIdx.x;
  int srow = tid >> 2, su0 = (tid & 3) * 2;
  const ushort* ga = Qb + base + (size_t)srow * HDD + su0 * 8;
  const ushort* gb = Kb + base + (size_t)srow * HDD + su0 * 8;
  int wa0 = srow * 64 + ((su0) ^ (srow & 7)) * 8;
  int wa1 = srow * 64 + ((su0 + 1) ^ (srow & 7)) * 8;
  int lane = tid & 63, w = tid >> 6;
  int wm = w >> 1, wn = w & 1;
  int r = lane & 15, kg = lane >> 4;
  f32x4 acc[2][2] = {};
  uint4 pa0 = *(const uint4*)(ga);
  uint4 pa1 = *(const uint4*)(ga + 8);
  uint4 pb0 = *(const uint4*)(gb);
  uint4 pb1 = *(const uint4*)(gb + 8);
  for (int k0 = 0; k0 < DD; k0 += 64) {
    __syncthreads();
    *(uint4*)&Als[wa0] = pa0; *(uint4*)&Als[wa1] = pa1;
    *(uint4*)&Bls[wa0] = pb0; *(uint4*)&Bls[wa1] = pb1;
    __syncthreads();
    int kn = k0 + 64;
    if (kn < DD) {
      pa0 = *(const uint4*)(ga + kn);
      pa1 = *(const uint4*)(ga + kn + 8);
      pb0 = *(const uint4*)(gb + kn);
      pb1 = *(const uint4*)(gb + kn + 8);
    }
#pragma unroll
    for (int h = 0; h < 2; ++h) {
      int sa = ((h * 4 + kg) ^ (r & 7)) * 8;
      bf16x8 af[2], bfr[2];
#pragma unroll
      for (int m = 0; m < 2; ++m)
        af[m] = *(const bf16x8*)&Als[(wm * 32 + m * 16 + r) * 64 + sa];
#pragma unroll
      for (int n = 0; n < 2; ++n)
        bfr[n] = *(const bf16x8*)&Bls[(wn * 32 + n * 16 + r) * 64 + sa];
#pragma unroll
      for (int m = 0; m < 2; ++m)
#pragma unroll
        for (int n = 0; n < 2; ++n)
          acc[m][n] = __builtin_amdgcn_mfma_f32_16x16x32_bf16(af[m], bfr[n], acc[m][n], 0, 0, 0);
    }
  }
#pragma unroll
  for (int m = 0; m < 2; ++m)
#pragma unroll
    for (int n = 0; n < 2; ++n)
#pragma unroll
      for (int v = 0; v < 4; ++v)
        S[wm * 32 + m * 16 + kg * 4 + v][wn * 32 + n * 16 + r] = acc[m][n][v];
  __syncthreads();
  bool valid = gmask[b * LNN + lane] != 0;
  for (int i = 0; i < 16; ++i) {
    int q = w * 16 + i;
    float v = valid ? S[q][lane] * 0.03125f : -__builtin_inff();
    float mx = v;
    for (int o = 32; o; o >>= 1) mx = fmaxf(mx, __shfl_xor(mx, o, 64));
    float e = valid ? __expf(v - mx) : 0.f;
    float s = e;
    for (int o = 32; o; o >>= 1) s += __shfl_xor(s, o, 64);
    P[(size_t)bh * 4096 + q * 64 + lane] = f2b(__fdividef(e, s));
  }
}

// ---------------- attn part 2: O[q,d-tile] = P @ V per (b,h,dtile) ----------------
__global__ __launch_bounds__(256) void attn_pv(const ushort* __restrict__ P,
                                               const ushort* __restrict__ Vb,
                                               ushort* __restrict__ AO) {
  int bid = blockIdx.x;
  int bh = bid >> 4, dt = bid & 15;
  int d0 = dt * 64;
  size_t vbase = ((size_t)(bh >> 2) * LNN) * HDD + (size_t)(bh & 3) * DD;
  __shared__ ushort Pls[64 * 72];
  __shared__ ushort Vt[64 * 72];
  int tid = threadIdx.x;
  {
    int row = tid >> 2, c = (tid & 3) * 16;
    const ushort* src = P + (size_t)bh * 4096 + row * 64 + c;
    uint4 v0 = *(const uint4*)src;
    uint4 v1 = *(const uint4*)(src + 8);
    *(uint4*)&Pls[row * 72 + c] = v0;
    *(uint4*)&Pls[row * 72 + c + 8] = v1;
  }
  {
    int kq = tid >> 2, dq = (tid & 3) * 16;
    const ushort* src = Vb + vbase + (size_t)kq * HDD + d0 + dq;
    uint4 v0 = *(const uint4*)src;
    uint4 v1 = *(const uint4*)(src + 8);
    ushort tmp[16];
    *(uint4*)&tmp[0] = v0;
    *(uint4*)&tmp[8] = v1;
#pragma unroll
    for (int j = 0; j < 16; ++j) Vt[(dq + j) * 72 + kq] = tmp[j];
  }
  __syncthreads();
  int lane = tid & 63, w = tid >> 6;
  int wm = w >> 1, wn = w & 1;
  int r = lane & 15, kg = lane >> 4;
  f32x4 acc[2][2] = {};
#pragma unroll
  for (int h = 0; h < 2; ++h) {
    int ko = h * 32 + kg * 8;
    bf16x8 af[2], bfr[2];
#pragma unroll
    for (int m = 0; m < 2; ++m)
      af[m] = *(const bf16x8*)&Pls[(wm * 32 + m * 16 + r) * 72 + ko];
#pragma unroll
    for (int n = 0; n < 2; ++n)
      bfr[n] = *(const bf16x8*)&Vt[(wn * 32 + n * 16 + r) * 72 + ko];
#pragma unroll
    for (int m = 0; m < 2; ++m)
#pragma unroll
      for (int n = 0; n < 2; ++n)
        acc[m][n] = __builtin_amdgcn_mfma_f32_16x16x32_bf16(af[m], bfr[n], acc[m][n], 0, 0, 0);
  }
#pragma unroll
  for (int m = 0; m < 2; ++m)
#pragma unroll
    for (int n = 0; n < 2; ++n) {
      f32x4 a = acc[m][n];
#pragma unroll
      for (int v = 0; v < 4; ++v) {
        int q = wm * 32 + m * 16 + kg * 4 + v;
        int col = wn * 32 + n * 16 + r;
        AO[vbase + (size_t)q * HDD + d0 + col] = f2b(a[v]);
      }
    }
}

// ---------------- LayerNorm per row over D=1024, bf16 out ----------------
__global__ __launch_bounds__(256) void lnorm(const float* __restrict__ X,
                                             const float* __restrict__ g,
                                             const float* __restrict__ be,
                                             ushort* __restrict__ Y) {
  int row = blockIdx.x, tid = threadIdx.x;
  int c = tid * 4;
  float4 v = *(const float4*)(X + (size_t)row * DD + c);
  float s = v.x + v.y + v.z + v.w;
  float ss = v.x * v.x + v.y * v.y + v.z * v.z + v.w * v.w;
  for (int o = 32; o; o >>= 1) {
    s += __shfl_xor(s, o, 64);
    ss += __shfl_xor(ss, o, 64);
  }
  __shared__ float rb_[8];
  int lane = tid & 63, w = tid >> 6;
  if (lane == 0) { rb_[w] = s; rb_[4 + w] = ss; }
  __syncthreads();
  s = rb_[0] + rb_[1] + rb_[2] + rb_[3];
  ss = rb_[4] + rb_[5] + rb_[6] + rb_[7];
  float mu = s * (1.f / 1024.f);
  float var = ss * (1.f / 1024.f) - mu * mu;
  float rstd = rsqrtf(var + 1e-5f);
  ushort4 o4;
  o4.x = f2b((v.x - mu) * rstd * g[c + 0] + be[c + 0]);
  o4.y = f2b((v.y - mu) * rstd * g[c + 1] + be[c + 1]);
  o4.z = f2b((v.z - mu) * rstd * g[c + 2] + be[c + 2]);
  o4.w = f2b((v.w - mu) * rstd * g[c + 3] + be[c + 3]);
  *(ushort4*)(Y + (size_t)row * DD + c) = o4;
}

// ---------------- additive attention phase 1: partial e over d-quarter ----------------
// QBu/KAB are pre-scaled by C_TANH and have all biases folded in.
// e_part[b,q,k] = sum_{d in slice} av[d] * tanh-part, via av - 2*av*rcp(exp2(t)+1)
__global__ __launch_bounds__(256) void addatt_e(const float* __restrict__ QBu,
                                                const float* __restrict__ KAB,
                                                const float* __restrict__ av_,
                                                float* __restrict__ E4) {
  int dq = blockIdx.x, q = blockIdx.y, b = blockIdx.z;
  int tid = threadIdx.x;
  __shared__ float qs[256], avs[256];
  __shared__ float red[4];
  int bq = b * LNN + q;
  qs[tid] = QBu[(size_t)bq * DD + dq * 256 + tid];
  float av = av_[dq * 256 + tid];
  avs[tid] = av;
  float s = av;
  for (int o = 32; o; o >>= 1) s += __shfl_xor(s, o, 64);
  int lane = tid & 63, w = tid >> 6;
  if (lane == 0) red[w] = s;
  __syncthreads();
  float sumav = red[0] + red[1] + red[2] + red[3];
  const float* kr = KAB + (size_t)(b * LTN + tid) * DD + dq * 256;
  float acc = 0.f;
#pragma unroll 8
  for (int d = 0; d < 256; d += 4) {
    float4 kv = *(const float4*)(kr + d);
    float r0 = __builtin_amdgcn_rcpf(__builtin_amdgcn_exp2f(qs[d + 0] + kv.x) + 1.f);
    float r1 = __builtin_amdgcn_rcpf(__builtin_amdgcn_exp2f(qs[d + 1] + kv.y) + 1.f);
    float r2 = __builtin_amdgcn_rcpf(__builtin_amdgcn_exp2f(qs[d + 2] + kv.z) + 1.f);
    float r3 = __builtin_amdgcn_rcpf(__builtin_amdgcn_exp2f(qs[d + 3] + kv.w) + 1.f);
    acc = fmaf(avs[d + 0], r0, acc);
    acc = fmaf(avs[d + 1], r1, acc);
    acc = fmaf(avs[d + 2], r2, acc);
    acc = fmaf(avs[d + 3], r3, acc);
  }
  E4[((size_t)dq * 512 + bq) * LTN + tid] = sumav - 2.f * acc;
}

// ---------------- additive attention phase 2: sum partials + masked softmax -> w ----------------
__global__ __launch_bounds__(256) void addatt_sm(const float* __restrict__ E4,
                                                 const int* __restrict__ lmask,
                                                 float* __restrict__ Wv) {
  int bq = blockIdx.x;
  int b = bq >> 6;
  int tid = threadIdx.x;
  __shared__ float rb_[8];
  float e = E4[(size_t)bq * LTN + tid] + E4[((size_t)512 + bq) * LTN + tid] +
            E4[((size_t)1024 + bq) * LTN + tid] + E4[((size_t)1536 + bq) * LTN + tid];
  bool valid = lmask[b * LTN + tid] != 0;
  float v = valid ? e : -__builtin_inff();
  int lane = tid & 63, w = tid >> 6;
  float m = v;
  for (int o = 32; o; o >>= 1) m = fmaxf(m, __shfl_xor(m, o, 64));
  if (lane == 0) rb_[w] = m;
  __syncthreads();
  m = fmaxf(fmaxf(rb_[0], rb_[1]), fmaxf(rb_[2], rb_[3]));
  float ex = valid ? __expf(v - m) : 0.f;
  float sm = ex;
  for (int o = 32; o; o >>= 1) sm += __shfl_xor(sm, o, 64);
  if (lane == 0) rb_[4 + w] = sm;
  __syncthreads();
  sm = rb_[4] + rb_[5] + rb_[6] + rb_[7];
  Wv[(size_t)bq * LTN + tid] = __fdividef(ex, sm);
}

// ---------------- additive attention phase 3: pooled context ----------------
// H4[b,d] = (sum_k (sum_q m_q w[b,q,k]) * text[b,k,d]) / cnt
__global__ __launch_bounds__(256) void addatt_pool(const float* __restrict__ Wv,
                                                   const float* __restrict__ text,
                                                   const int* __restrict__ gmask,
                                                   float* __restrict__ H4) {
  int dt = blockIdx.x, b = blockIdx.y;
  int tid = threadIdx.x;
  __shared__ float cf[LTN];
  float c = 0.f, cnt = 0.f;
#pragma unroll 8
  for (int q = 0; q < LNN; ++q) {
    float m = (gmask[b * LNN + q] != 0) ? 1.f : 0.f;
    cnt += m;
    c = fmaf(m, Wv[(size_t)(b * LNN + q) * LTN + tid], c);
  }
  cf[tid] = c;
  cnt = fmaxf(cnt, 9.765625e-04f);
  __syncthreads();
  int d = dt * 256 + tid;
  const float* tb = text + (size_t)b * LTN * DD + d;
  float acc = 0.f;
#pragma unroll 8
  for (int k = 0; k < LTN; ++k) acc = fmaf(cf[k], tb[(size_t)k * DD], acc);
  H4[b * DD + d] = acc / cnt;
}

// ---------------- dp1 + exact GELU ----------------
__global__ __launch_bounds__(256) void dp1k(const float* __restrict__ H4,
                                            const float* __restrict__ W,
                                            const float* __restrict__ bias,
                                            float* __restrict__ G) {
  int b = blockIdx.y;
  int j = blockIdx.x * 256 + threadIdx.x;
  __shared__ float h[DD];
  int c = threadIdx.x * 4;
  *(float4*)(h + c) = *(const float4*)(H4 + (size_t)b * DD + c);
  __syncthreads();
  float acc = bias[j];
#pragma unroll 8
  for (int d = 0; d < DD; ++d) acc += h[d] * W[(size_t)d * DHN + j];
  float x = acc;
  G[(size_t)b * DHN + j] = 0.5f * x * (1.f + erff(x * 0.70710678118654752440f));
}

// ---------------- dp2 ----------------
__global__ __launch_bounds__(256) void dp2k(const float* __restrict__ G,
                                            const float* __restrict__ W,
                                            const float* __restrict__ bias,
                                            float* __restrict__ Z) {
  int b = blockIdx.y;
  int j = blockIdx.x * 256 + threadIdx.x;
  __shared__ float h[DHN];
  int c = threadIdx.x * 4;
  *(float4*)(h + c) = *(const float4*)(G + (size_t)b * DHN + c);
  __syncthreads();
  float acc = bias[j];
#pragma unroll 8
  for (int d = 0; d < DHN; ++d) acc += h[d] * W[(size_t)d * DINN + j];
  Z[(size_t)b * DINN + j] = acc;
}

extern "C" void kernel_launch(void* const* d_in, const int* in_sizes, int n_in,
                              void* d_out, int out_size, void* d_ws, size_t ws_size,
                              hipStream_t stream) {
  const float* text = (const float*)d_in[0];
  const float* node = (const float*)d_in[1];
  const float* Wq = (const float*)d_in[2];
  const float* bq = (const float*)d_in[3];
  const float* Wk = (const float*)d_in[4];
  const float* bk = (const float*)d_in[5];
  const float* Wv = (const float*)d_in[6];
  const float* bv = (const float*)d_in[7];
  const float* Wo = (const float*)d_in[8];
  const float* bo = (const float*)d_in[9];
  const float* lng = (const float*)d_in[10];
  const float* lnb = (const float*)d_in[11];
  const float* aqW = (const float*)d_in[12];
  const float* aqb = (const float*)d_in[13];
  const float* akW = (const float*)d_in[14];
  const float* akb = (const float*)d_in[15];
  const float* attv = (const float*)d_in[16];
  const float* attb = (const float*)d_in[17];
  const float* dp1W = (const float*)d_in[18];
  const float* dp1b = (const float*)d_in[19];
  const float* dp2W = (const float*)d_in[20];
  const float* dp2b = (const float*)d_in[21];
  const int* gmask = (const int*)d_in[22];
  const int* lmask = (const int*)d_in[23];
  (void)in_sizes; (void)n_in; (void)out_size; (void)ws_size;

  char* base = (char*)d_ws;
#define MB(x) (((size_t)(x)) << 20)
  ushort* Twt = (ushort*)(base);               // 8MB, reused per weight
  ushort* node_bf = (ushort*)(base + MB(8));   // 1MB
  ushort* text_bf = (ushort*)(base + MB(9));   // 4MB
  ushort* Qb = (ushort*)(base + MB(13));       // 4MB
  ushort* Kb = (ushort*)(base + MB(17));       // 4MB
  ushort* Vb = (ushort*)(base + MB(21));       // 4MB
  ushort* AO = (ushort*)(base + MB(25));       // 4MB
  float* PRE = (float*)(base + MB(13));        // 2MB (aliases Qb, dead then)
  ushort* H2 = (ushort*)(base + MB(17));       // 1MB (aliases Kb)
  float* QBu = (float*)(base + MB(21));        // 2MB (aliases Vb, dead after attn_pv)
  float* KAB = (float*)(base + MB(25));        // 8MB (aliases AO, dead after Wo gemm)
  float* E4 = (float*)(base + MB(13));         // 2MB (aliases PRE, dead after lnorm)
  float* Wvb = (float*)(base + MB(15));        // 512KB
  float* H4 = (float*)(base + MB(33));         // 32KB
  float* G = (float*)(base + MB(33) + 32768);  // 32KB
  ushort* Pws = (ushort*)(base + MB(33) + 65536);  // 256KB attn probs
  float* Z = (float*)d_out;
#undef MB

  const int M1 = NB * LNN;  // 512
  dim3 blk(256);

  cvtk<<<dim3(512 * 1024 / 2048), blk, 0, stream>>>(node, node_bf, 512 * 1024);
  cvtk<<<dim3(NB * LTN * DD / 2048), blk, 0, stream>>>(text, text_bf, NB * LTN * DD);

  // QKV projections (bf16 MFMA)
  tcvt<<<dim3(HDD / 64, DD / 64), blk, 0, stream>>>(Wq, Twt, DD, HDD);
  gemm_mfma<1, 0><<<dim3(HDD / 64, M1 / 64), blk, 0, stream>>>(node_bf, Twt, bq, nullptr, nullptr, Qb, M1, HDD, DD, 1.f);
  tcvt<<<dim3(HDD / 64, DD / 64), blk, 0, stream>>>(Wk, Twt, DD, HDD);
  gemm_mfma<1, 0><<<dim3(HDD / 64, M1 / 64), blk, 0, stream>>>(node_bf, Twt, bk, nullptr, nullptr, Kb, M1, HDD, DD, 1.f);
  tcvt<<<dim3(HDD / 64, DD / 64), blk, 0, stream>>>(Wv, Twt, DD, HDD);
  gemm_mfma<1, 0><<<dim3(HDD / 64, M1 / 64), blk, 0, stream>>>(node_bf, Twt, bv, nullptr, nullptr, Vb, M1, HDD, DD, 1.f);

  // self-attention (MFMA scores + MFMA PV)
  attn_scores<<<dim3(NB * NH), blk, 0, stream>>>(Qb, Kb, gmask, Pws);
  attn_pv<<<dim3(NB * NH * 16), blk, 0, stream>>>(Pws, Vb, AO);

  // output proj + residual (fp32 out)
  tcvt<<<dim3(DD / 64, HDD / 64), blk, 0, stream>>>(Wo, Twt, HDD, DD);
  gemm_mfma<0, 1><<<dim3(DD / 64, M1 / 64), blk, 0, stream>>>(AO, Twt, bo, nullptr, node, PRE, M1, DD, HDD, 1.f);

  // layernorm -> bf16
  lnorm<<<dim3(M1), blk, 0, stream>>>(PRE, lng, lnb, H2);

  // additive attention projections: pre-scaled by C_TANH, att_b folded into KAB
  tcvt<<<dim3(DD / 64, DD / 64), blk, 0, stream>>>(aqW, Twt, DD, DD);
  gemm_mfma<0, 0><<<dim3(DD / 64, M1 / 64), blk, 0, stream>>>(H2, Twt, aqb, nullptr, nullptr, QBu, M1, DD, DD, C_TANH);
  tcvt<<<dim3(DD / 64, DD / 64), blk, 0, stream>>>(akW, Twt, DD, DD);
  gemm_mfma<0, 0><<<dim3(DD / 64, (NB * LTN) / 64), blk, 0, stream>>>(text_bf, Twt, akb, attb, nullptr, KAB, NB * LTN, DD, DD, C_TANH);

  // additive attention: partial-e -> softmax -> pooled context (H3 eliminated algebraically)
  addatt_e<<<dim3(4, LNN, NB), blk, 0, stream>>>(QBu, KAB, attv, E4);
  addatt_sm<<<dim3(M1), blk, 0, stream>>>(E4, lmask, Wvb);
  addatt_pool<<<dim3(4, NB), blk, 0, stream>>>(Wvb, text, gmask, H4);

  // MLP
  dp1k<<<dim3(DHN / 256, NB), blk, 0, stream>>>(H4, dp1W, dp1b, G);
  dp2k<<<dim3(DINN / 256, NB), blk, 0, stream>>>(G, dp2W, dp2b, Z);
}

// Round 5
// 248.481 us; speedup vs baseline: 4.8284x; 1.3566x over previous
//
#include <hip/hip_runtime.h>
#include <hip/hip_bf16.h>
#include <math.h>

#define NB 8        // batch
#define LNN 64      // nodes
#define LTN 256     // text len
#define DD 1024     // model dim
#define NH 4        // heads (each full width D)
#define HDD 4096    // NH*DD
#define DINN 2048
#define DHN 1024    // DIN/2

// 2*log2(e): tanh(x) = 1 - 2/(exp2(x*C)+1)
#define C_TANH 2.8853900817779268f

typedef __bf16 bf16x8 __attribute__((ext_vector_type(8)));
typedef float f32x4 __attribute__((ext_vector_type(4)));

__device__ __forceinline__ float b2f(ushort u) {
  union { float f; unsigned int i; } x; x.i = ((unsigned int)u) << 16; return x.f;
}
__device__ __forceinline__ ushort f2b(float f) {
  unsigned int u = __builtin_bit_cast(unsigned int, f);
  u = (u + 0x7FFFu + ((u >> 16) & 1u)) >> 16;
  return (ushort)u;
}

// ---------------- fp32 -> bf16 elementwise (n % 2048 == 0) ----------------
__global__ __launch_bounds__(256) void cvtk(const float* __restrict__ in,
                                            ushort* __restrict__ out, int n) {
  int i = (blockIdx.x * 256 + threadIdx.x) * 8;
  if (i >= n) return;
  float4 a = *(const float4*)(in + i);
  float4 b = *(const float4*)(in + i + 4);
  ushort4 o0 = {f2b(a.x), f2b(a.y), f2b(a.z), f2b(a.w)};
  ushort4 o1 = {f2b(b.x), f2b(b.y), f2b(b.z), f2b(b.w)};
  *(ushort4*)(out + i) = o0;
  *(ushort4*)(out + i + 4) = o1;
}

// ---------------- transpose + convert: W[K][N] fp32 -> Wt[N][K] bf16 ----------------
__global__ __launch_bounds__(256) void tcvt(const float* __restrict__ W,
                                            ushort* __restrict__ Wt, int K, int N) {
  __shared__ float tf[64][65];
  int k0 = blockIdx.y << 6, n0 = blockIdx.x << 6;
  int t = threadIdx.x;
  int r = t >> 2, c4 = (t & 3) * 16;
  const float* src = W + (size_t)(k0 + r) * N + n0 + c4;
  float4 v0 = *(const float4*)(src);
  float4 v1 = *(const float4*)(src + 4);
  float4 v2 = *(const float4*)(src + 8);
  float4 v3 = *(const float4*)(src + 12);
  *(float4*)&tf[r][c4] = v0;
  *(float4*)&tf[r][c4 + 4] = v1;
  *(float4*)&tf[r][c4 + 8] = v2;
  *(float4*)&tf[r][c4 + 12] = v3;
  __syncthreads();
  int nl = t >> 2, kc = (t & 3) * 16;
  ushort tmp[16];
#pragma unroll
  for (int j = 0; j < 16; ++j) tmp[j] = f2b(tf[kc + j][nl]);
  ushort* dst = Wt + (size_t)(n0 + nl) * K + k0 + kc;
  *(uint4*)(dst) = *(uint4*)&tmp[0];
  *(uint4*)(dst + 8) = *(uint4*)&tmp[8];
}

// ---------------- bf16 MFMA GEMM: C[M,N] = (A[M,K] @ Bt[N,K]^T + b1 (+b2) (+res)) * scale ----------------
template <int OUTBF, int RES>
__global__ __launch_bounds__(256) void gemm_mfma(const ushort* __restrict__ A,
                                                 const ushort* __restrict__ Bt,
                                                 const float* __restrict__ bias,
                                                 const float* __restrict__ bias2,
                                                 const float* __restrict__ res,
                                                 void* __restrict__ Cout,
                                                 int M, int N, int K, float scale) {
  __shared__ ushort Als[64 * 64];
  __shared__ ushort Bls[64 * 64];
  int tid = threadIdx.x;
  int m0 = blockIdx.y << 6, n0 = blockIdx.x << 6;

  int srow = tid >> 2;
  int su0 = (tid & 3) * 2;
  const ushort* ga = A + (size_t)(m0 + srow) * K + su0 * 8;
  const ushort* gb = Bt + (size_t)(n0 + srow) * K + su0 * 8;
  int wa0 = srow * 64 + ((su0) ^ (srow & 7)) * 8;
  int wa1 = srow * 64 + ((su0 + 1) ^ (srow & 7)) * 8;

  int lane = tid & 63, w = tid >> 6;
  int wm = w >> 1, wn = w & 1;
  int r = lane & 15, kg = lane >> 4;

  f32x4 acc[2][2] = {};

  uint4 pa0 = *(const uint4*)(ga);
  uint4 pa1 = *(const uint4*)(ga + 8);
  uint4 pb0 = *(const uint4*)(gb);
  uint4 pb1 = *(const uint4*)(gb + 8);

  for (int k0 = 0; k0 < K; k0 += 64) {
    __syncthreads();
    *(uint4*)&Als[wa0] = pa0; *(uint4*)&Als[wa1] = pa1;
    *(uint4*)&Bls[wa0] = pb0; *(uint4*)&Bls[wa1] = pb1;
    __syncthreads();
    int kn = k0 + 64;
    if (kn < K) {
      pa0 = *(const uint4*)(ga + kn);
      pa1 = *(const uint4*)(ga + kn + 8);
      pb0 = *(const uint4*)(gb + kn);
      pb1 = *(const uint4*)(gb + kn + 8);
    }
#pragma unroll
    for (int h = 0; h < 2; ++h) {
      int sa = ((h * 4 + kg) ^ (r & 7)) * 8;
      bf16x8 af[2], bfr[2];
#pragma unroll
      for (int m = 0; m < 2; ++m)
        af[m] = *(const bf16x8*)&Als[(wm * 32 + m * 16 + r) * 64 + sa];
#pragma unroll
      for (int n = 0; n < 2; ++n)
        bfr[n] = *(const bf16x8*)&Bls[(wn * 32 + n * 16 + r) * 64 + sa];
#pragma unroll
      for (int m = 0; m < 2; ++m)
#pragma unroll
        for (int n = 0; n < 2; ++n)
          acc[m][n] = __builtin_amdgcn_mfma_f32_16x16x32_bf16(af[m], bfr[n], acc[m][n], 0, 0, 0);
    }
  }
#pragma unroll
  for (int m = 0; m < 2; ++m)
#pragma unroll
    for (int n = 0; n < 2; ++n) {
      f32x4 a = acc[m][n];
#pragma unroll
      for (int v = 0; v < 4; ++v) {
        int row = m0 + wm * 32 + m * 16 + kg * 4 + v;
        int col = n0 + wn * 32 + n * 16 + r;
        float x = a[v] + bias[col];
        if (bias2) x += bias2[col];
        if constexpr (RES) x += res[(size_t)row * N + col];
        x *= scale;
        if constexpr (OUTBF) ((ushort*)Cout)[(size_t)row * N + col] = f2b(x);
        else ((float*)Cout)[(size_t)row * N + col] = x;
      }
    }
}

// ---------------- attn part 1: S = softmax(Q K^T / 32) per (b,h) -> P bf16 ----------------
__global__ __launch_bounds__(256) void attn_scores(const ushort* __restrict__ Qb,
                                                   const ushort* __restrict__ Kb,
                                                   const int* __restrict__ gmask,
                                                   ushort* __restrict__ P) {
  int bh = blockIdx.x;
  int b = bh >> 2;
  size_t base = ((size_t)b * LNN) * HDD + (size_t)(bh & 3) * DD;
  __shared__ ushort Als[64 * 64];
  __shared__ ushort Bls[64 * 64];
  __shared__ float S[64][68];
  int tid = threadIdx.x;
  int srow = tid >> 2, su0 = (tid & 3) * 2;
  const ushort* ga = Qb + base + (size_t)srow * HDD + su0 * 8;
  const ushort* gb = Kb + base + (size_t)srow * HDD + su0 * 8;
  int wa0 = srow * 64 + ((su0) ^ (srow & 7)) * 8;
  int wa1 = srow * 64 + ((su0 + 1) ^ (srow & 7)) * 8;
  int lane = tid & 63, w = tid >> 6;
  int wm = w >> 1, wn = w & 1;
  int r = lane & 15, kg = lane >> 4;
  f32x4 acc[2][2] = {};
  uint4 pa0 = *(const uint4*)(ga);
  uint4 pa1 = *(const uint4*)(ga + 8);
  uint4 pb0 = *(const uint4*)(gb);
  uint4 pb1 = *(const uint4*)(gb + 8);
  for (int k0 = 0; k0 < DD; k0 += 64) {
    __syncthreads();
    *(uint4*)&Als[wa0] = pa0; *(uint4*)&Als[wa1] = pa1;
    *(uint4*)&Bls[wa0] = pb0; *(uint4*)&Bls[wa1] = pb1;
    __syncthreads();
    int kn = k0 + 64;
    if (kn < DD) {
      pa0 = *(const uint4*)(ga + kn);
      pa1 = *(const uint4*)(ga + kn + 8);
      pb0 = *(const uint4*)(gb + kn);
      pb1 = *(const uint4*)(gb + kn + 8);
    }
#pragma unroll
    for (int h = 0; h < 2; ++h) {
      int sa = ((h * 4 + kg) ^ (r & 7)) * 8;
      bf16x8 af[2], bfr[2];
#pragma unroll
      for (int m = 0; m < 2; ++m)
        af[m] = *(const bf16x8*)&Als[(wm * 32 + m * 16 + r) * 64 + sa];
#pragma unroll
      for (int n = 0; n < 2; ++n)
        bfr[n] = *(const bf16x8*)&Bls[(wn * 32 + n * 16 + r) * 64 + sa];
#pragma unroll
      for (int m = 0; m < 2; ++m)
#pragma unroll
        for (int n = 0; n < 2; ++n)
          acc[m][n] = __builtin_amdgcn_mfma_f32_16x16x32_bf16(af[m], bfr[n], acc[m][n], 0, 0, 0);
    }
  }
#pragma unroll
  for (int m = 0; m < 2; ++m)
#pragma unroll
    for (int n = 0; n < 2; ++n)
#pragma unroll
      for (int v = 0; v < 4; ++v)
        S[wm * 32 + m * 16 + kg * 4 + v][wn * 32 + n * 16 + r] = acc[m][n][v];
  __syncthreads();
  bool valid = gmask[b * LNN + lane] != 0;
  for (int i = 0; i < 16; ++i) {
    int q = w * 16 + i;
    float v = valid ? S[q][lane] * 0.03125f : -__builtin_inff();
    float mx = v;
    for (int o = 32; o; o >>= 1) mx = fmaxf(mx, __shfl_xor(mx, o, 64));
    float e = valid ? __expf(v - mx) : 0.f;
    float s = e;
    for (int o = 32; o; o >>= 1) s += __shfl_xor(s, o, 64);
    P[(size_t)bh * 4096 + q * 64 + lane] = f2b(__fdividef(e, s));
  }
}

// ---------------- attn part 2: O[q,d-tile] = P @ V per (b,h,dtile) ----------------
__global__ __launch_bounds__(256) void attn_pv(const ushort* __restrict__ P,
                                               const ushort* __restrict__ Vb,
                                               ushort* __restrict__ AO) {
  int bid = blockIdx.x;
  int bh = bid >> 4, dt = bid & 15;
  int d0 = dt * 64;
  size_t vbase = ((size_t)(bh >> 2) * LNN) * HDD + (size_t)(bh & 3) * DD;
  __shared__ ushort Pls[64 * 72];
  __shared__ ushort Vt[64 * 72];
  int tid = threadIdx.x;
  {
    int row = tid >> 2, c = (tid & 3) * 16;
    const ushort* src = P + (size_t)bh * 4096 + row * 64 + c;
    uint4 v0 = *(const uint4*)src;
    uint4 v1 = *(const uint4*)(src + 8);
    *(uint4*)&Pls[row * 72 + c] = v0;
    *(uint4*)&Pls[row * 72 + c + 8] = v1;
  }
  {
    int kq = tid >> 2, dq = (tid & 3) * 16;
    const ushort* src = Vb + vbase + (size_t)kq * HDD + d0 + dq;
    uint4 v0 = *(const uint4*)src;
    uint4 v1 = *(const uint4*)(src + 8);
    ushort tmp[16];
    *(uint4*)&tmp[0] = v0;
    *(uint4*)&tmp[8] = v1;
#pragma unroll
    for (int j = 0; j < 16; ++j) Vt[(dq + j) * 72 + kq] = tmp[j];
  }
  __syncthreads();
  int lane = tid & 63, w = tid >> 6;
  int wm = w >> 1, wn = w & 1;
  int r = lane & 15, kg = lane >> 4;
  f32x4 acc[2][2] = {};
#pragma unroll
  for (int h = 0; h < 2; ++h) {
    int ko = h * 32 + kg * 8;
    bf16x8 af[2], bfr[2];
#pragma unroll
    for (int m = 0; m < 2; ++m)
      af[m] = *(const bf16x8*)&Pls[(wm * 32 + m * 16 + r) * 72 + ko];
#pragma unroll
    for (int n = 0; n < 2; ++n)
      bfr[n] = *(const bf16x8*)&Vt[(wn * 32 + n * 16 + r) * 72 + ko];
#pragma unroll
    for (int m = 0; m < 2; ++m)
#pragma unroll
      for (int n = 0; n < 2; ++n)
        acc[m][n] = __builtin_amdgcn_mfma_f32_16x16x32_bf16(af[m], bfr[n], acc[m][n], 0, 0, 0);
  }
#pragma unroll
  for (int m = 0; m < 2; ++m)
#pragma unroll
    for (int n = 0; n < 2; ++n) {
      f32x4 a = acc[m][n];
#pragma unroll
      for (int v = 0; v < 4; ++v) {
        int q = wm * 32 + m * 16 + kg * 4 + v;
        int col = wn * 32 + n * 16 + r;
        AO[vbase + (size_t)q * HDD + d0 + col] = f2b(a[v]);
      }
    }
}

// ---------------- LayerNorm per row over D=1024, bf16 out ----------------
__global__ __launch_bounds__(256) void lnorm(const float* __restrict__ X,
                                             const float* __restrict__ g,
                                             const float* __restrict__ be,
                                             ushort* __restrict__ Y) {
  int row = blockIdx.x, tid = threadIdx.x;
  int c = tid * 4;
  float4 v = *(const float4*)(X + (size_t)row * DD + c);
  float s = v.x + v.y + v.z + v.w;
  float ss = v.x * v.x + v.y * v.y + v.z * v.z + v.w * v.w;
  for (int o = 32; o; o >>= 1) {
    s += __shfl_xor(s, o, 64);
    ss += __shfl_xor(ss, o, 64);
  }
  __shared__ float rb_[8];
  int lane = tid & 63, w = tid >> 6;
  if (lane == 0) { rb_[w] = s; rb_[4 + w] = ss; }
  __syncthreads();
  s = rb_[0] + rb_[1] + rb_[2] + rb_[3];
  ss = rb_[4] + rb_[5] + rb_[6] + rb_[7];
  float mu = s * (1.f / 1024.f);
  float var = ss * (1.f / 1024.f) - mu * mu;
  float rstd = rsqrtf(var + 1e-5f);
  ushort4 o4;
  o4.x = f2b((v.x - mu) * rstd * g[c + 0] + be[c + 0]);
  o4.y = f2b((v.y - mu) * rstd * g[c + 1] + be[c + 1]);
  o4.z = f2b((v.z - mu) * rstd * g[c + 2] + be[c + 2]);
  o4.w = f2b((v.w - mu) * rstd * g[c + 3] + be[c + 3]);
  *(ushort4*)(Y + (size_t)row * DD + c) = o4;
}

// ---------------- additive attention phase 1: partial e over d-quarter ----------------
__global__ __launch_bounds__(256) void addatt_e(const float* __restrict__ QBu,
                                                const float* __restrict__ KAB,
                                                const float* __restrict__ av_,
                                                float* __restrict__ E4) {
  int dq = blockIdx.x, q = blockIdx.y, b = blockIdx.z;
  int tid = threadIdx.x;
  __shared__ float qs[256], avs[256];
  __shared__ float red[4];
  int bq = b * LNN + q;
  qs[tid] = QBu[(size_t)bq * DD + dq * 256 + tid];
  float av = av_[dq * 256 + tid];
  avs[tid] = av;
  float s = av;
  for (int o = 32; o; o >>= 1) s += __shfl_xor(s, o, 64);
  int lane = tid & 63, w = tid >> 6;
  if (lane == 0) red[w] = s;
  __syncthreads();
  float sumav = red[0] + red[1] + red[2] + red[3];
  const float* kr = KAB + (size_t)(b * LTN + tid) * DD + dq * 256;
  float acc = 0.f;
#pragma unroll 8
  for (int d = 0; d < 256; d += 4) {
    float4 kv = *(const float4*)(kr + d);
    float r0 = __builtin_amdgcn_rcpf(__builtin_amdgcn_exp2f(qs[d + 0] + kv.x) + 1.f);
    float r1 = __builtin_amdgcn_rcpf(__builtin_amdgcn_exp2f(qs[d + 1] + kv.y) + 1.f);
    float r2 = __builtin_amdgcn_rcpf(__builtin_amdgcn_exp2f(qs[d + 2] + kv.z) + 1.f);
    float r3 = __builtin_amdgcn_rcpf(__builtin_amdgcn_exp2f(qs[d + 3] + kv.w) + 1.f);
    acc = fmaf(avs[d + 0], r0, acc);
    acc = fmaf(avs[d + 1], r1, acc);
    acc = fmaf(avs[d + 2], r2, acc);
    acc = fmaf(avs[d + 3], r3, acc);
  }
  E4[((size_t)dq * 512 + bq) * LTN + tid] = sumav - 2.f * acc;
}

// ---------------- additive attention phase 2: sum partials + masked softmax -> w ----------------
__global__ __launch_bounds__(256) void addatt_sm(const float* __restrict__ E4,
                                                 const int* __restrict__ lmask,
                                                 float* __restrict__ Wv) {
  int bq = blockIdx.x;
  int b = bq >> 6;
  int tid = threadIdx.x;
  __shared__ float rb_[8];
  float e = E4[(size_t)bq * LTN + tid] + E4[((size_t)512 + bq) * LTN + tid] +
            E4[((size_t)1024 + bq) * LTN + tid] + E4[((size_t)1536 + bq) * LTN + tid];
  bool valid = lmask[b * LTN + tid] != 0;
  float v = valid ? e : -__builtin_inff();
  int lane = tid & 63, w = tid >> 6;
  float m = v;
  for (int o = 32; o; o >>= 1) m = fmaxf(m, __shfl_xor(m, o, 64));
  if (lane == 0) rb_[w] = m;
  __syncthreads();
  m = fmaxf(fmaxf(rb_[0], rb_[1]), fmaxf(rb_[2], rb_[3]));
  float ex = valid ? __expf(v - m) : 0.f;
  float sm = ex;
  for (int o = 32; o; o >>= 1) sm += __shfl_xor(sm, o, 64);
  if (lane == 0) rb_[4 + w] = sm;
  __syncthreads();
  sm = rb_[4] + rb_[5] + rb_[6] + rb_[7];
  Wv[(size_t)bq * LTN + tid] = __fdividef(ex, sm);
}

// ---------------- additive attention phase 3: pooled context ----------------
__global__ __launch_bounds__(256) void addatt_pool(const float* __restrict__ Wv,
                                                   const float* __restrict__ text,
                                                   const int* __restrict__ gmask,
                                                   float* __restrict__ H4) {
  int dt = blockIdx.x, b = blockIdx.y;
  int tid = threadIdx.x;
  __shared__ float cf[LTN];
  float c = 0.f, cnt = 0.f;
#pragma unroll 8
  for (int q = 0; q < LNN; ++q) {
    float m = (gmask[b * LNN + q] != 0) ? 1.f : 0.f;
    cnt += m;
    c = fmaf(m, Wv[(size_t)(b * LNN + q) * LTN + tid], c);
  }
  cf[tid] = c;
  cnt = fmaxf(cnt, 9.765625e-04f);
  __syncthreads();
  int d = dt * 256 + tid;
  const float* tb = text + (size_t)b * LTN * DD + d;
  float acc = 0.f;
#pragma unroll 8
  for (int k = 0; k < LTN; ++k) acc = fmaf(cf[k], tb[(size_t)k * DD], acc);
  H4[b * DD + d] = acc / cnt;
}

// ---------------- split-K GEMV: P[kt][8][N] partials of X[8,K] @ W[K,N] ----------------
// K chunk = 32, j tile = 64. grid (N/64, K/32).
__global__ __launch_bounds__(256) void dp_split(const float* __restrict__ X,
                                                const float* __restrict__ W,
                                                float* __restrict__ P,
                                                int K, int N) {
  int jt = blockIdx.x, kt = blockIdx.y;
  int t = threadIdx.x;
  __shared__ float xs[8][32];
  if (t < 64) {
    int b = t >> 3, kk = (t & 7) * 4;
    *(float4*)&xs[b][kk] = *(const float4*)(X + (size_t)b * K + kt * 32 + kk);
  }
  __syncthreads();
  int j = jt * 64 + (t & 63);
  int bg = (t >> 6) * 2;  // 0,2,4,6
  const float* wp = W + (size_t)(kt * 32) * N + j;
  float a0 = 0.f, a1 = 0.f;
#pragma unroll
  for (int k = 0; k < 32; ++k) {
    float w = wp[(size_t)k * N];
    a0 = fmaf(xs[bg + 0][k], w, a0);
    a1 = fmaf(xs[bg + 1][k], w, a1);
  }
  P[((size_t)kt * 8 + bg + 0) * N + j] = a0;
  P[((size_t)kt * 8 + bg + 1) * N + j] = a1;
}

// ---------------- reduce partials (+bias, optional exact GELU) ----------------
template <int GELU>
__global__ __launch_bounds__(256) void dp_reduce(const float* __restrict__ P,
                                                 const float* __restrict__ bias,
                                                 float* __restrict__ O, int N) {
  int b = blockIdx.y;
  int j = blockIdx.x * 256 + threadIdx.x;
  float s = bias[j];
#pragma unroll 8
  for (int kt = 0; kt < 32; ++kt) s += P[((size_t)kt * 8 + b) * N + j];
  if constexpr (GELU) s = 0.5f * s * (1.f + erff(s * 0.70710678118654752440f));
  O[(size_t)b * N + j] = s;
}

extern "C" void kernel_launch(void* const* d_in, const int* in_sizes, int n_in,
                              void* d_out, int out_size, void* d_ws, size_t ws_size,
                              hipStream_t stream) {
  const float* text = (const float*)d_in[0];
  const float* node = (const float*)d_in[1];
  const float* Wq = (const float*)d_in[2];
  const float* bq = (const float*)d_in[3];
  const float* Wk = (const float*)d_in[4];
  const float* bk = (const float*)d_in[5];
  const float* Wv = (const float*)d_in[6];
  const float* bv = (const float*)d_in[7];
  const float* Wo = (const float*)d_in[8];
  const float* bo = (const float*)d_in[9];
  const float* lng = (const float*)d_in[10];
  const float* lnb = (const float*)d_in[11];
  const float* aqW = (const float*)d_in[12];
  const float* aqb = (const float*)d_in[13];
  const float* akW = (const float*)d_in[14];
  const float* akb = (const float*)d_in[15];
  const float* attv = (const float*)d_in[16];
  const float* attb = (const float*)d_in[17];
  const float* dp1W = (const float*)d_in[18];
  const float* dp1b = (const float*)d_in[19];
  const float* dp2W = (const float*)d_in[20];
  const float* dp2b = (const float*)d_in[21];
  const int* gmask = (const int*)d_in[22];
  const int* lmask = (const int*)d_in[23];
  (void)in_sizes; (void)n_in; (void)out_size; (void)ws_size;

  char* base = (char*)d_ws;
#define MB(x) (((size_t)(x)) << 20)
  ushort* Twt = (ushort*)(base);               // 8MB, reused per weight
  ushort* node_bf = (ushort*)(base + MB(8));   // 1MB
  ushort* text_bf = (ushort*)(base + MB(9));   // 4MB
  ushort* Qb = (ushort*)(base + MB(13));       // 4MB
  ushort* Kb = (ushort*)(base + MB(17));       // 4MB
  ushort* Vb = (ushort*)(base + MB(21));       // 4MB
  ushort* AO = (ushort*)(base + MB(25));       // 4MB
  float* PRE = (float*)(base + MB(13));        // 2MB (aliases Qb, dead then)
  ushort* H2 = (ushort*)(base + MB(17));       // 1MB (aliases Kb head; Kb dead after attn_scores)
  float* P1 = (float*)(base + MB(18));         // 1MB partials dp1 (in dead Kb tail)
  float* P2 = (float*)(base + MB(19));         // 2MB partials dp2 (in dead Kb tail)
  float* QBu = (float*)(base + MB(21));        // 2MB (aliases Vb, dead after attn_pv)
  float* KAB = (float*)(base + MB(25));        // 8MB (aliases AO, dead after Wo gemm)
  float* E4 = (float*)(base + MB(13));         // 2MB (aliases PRE, dead after lnorm)
  float* Wvb = (float*)(base + MB(15));        // 512KB
  float* H4 = (float*)(base + MB(33));         // 32KB
  float* G = (float*)(base + MB(33) + 32768);  // 32KB
  ushort* Pws = (ushort*)(base + MB(33) + 65536);  // 256KB attn probs
  float* Z = (float*)d_out;
#undef MB

  const int M1 = NB * LNN;  // 512
  dim3 blk(256);

  cvtk<<<dim3(512 * 1024 / 2048), blk, 0, stream>>>(node, node_bf, 512 * 1024);
  cvtk<<<dim3(NB * LTN * DD / 2048), blk, 0, stream>>>(text, text_bf, NB * LTN * DD);

  // QKV projections (bf16 MFMA)
  tcvt<<<dim3(HDD / 64, DD / 64), blk, 0, stream>>>(Wq, Twt, DD, HDD);
  gemm_mfma<1, 0><<<dim3(HDD / 64, M1 / 64), blk, 0, stream>>>(node_bf, Twt, bq, nullptr, nullptr, Qb, M1, HDD, DD, 1.f);
  tcvt<<<dim3(HDD / 64, DD / 64), blk, 0, stream>>>(Wk, Twt, DD, HDD);
  gemm_mfma<1, 0><<<dim3(HDD / 64, M1 / 64), blk, 0, stream>>>(node_bf, Twt, bk, nullptr, nullptr, Kb, M1, HDD, DD, 1.f);
  tcvt<<<dim3(HDD / 64, DD / 64), blk, 0, stream>>>(Wv, Twt, DD, HDD);
  gemm_mfma<1, 0><<<dim3(HDD / 64, M1 / 64), blk, 0, stream>>>(node_bf, Twt, bv, nullptr, nullptr, Vb, M1, HDD, DD, 1.f);

  // self-attention (MFMA scores + MFMA PV)
  attn_scores<<<dim3(NB * NH), blk, 0, stream>>>(Qb, Kb, gmask, Pws);
  attn_pv<<<dim3(NB * NH * 16), blk, 0, stream>>>(Pws, Vb, AO);

  // output proj + residual (fp32 out)
  tcvt<<<dim3(DD / 64, HDD / 64), blk, 0, stream>>>(Wo, Twt, HDD, DD);
  gemm_mfma<0, 1><<<dim3(DD / 64, M1 / 64), blk, 0, stream>>>(AO, Twt, bo, nullptr, node, PRE, M1, DD, HDD, 1.f);

  // layernorm -> bf16
  lnorm<<<dim3(M1), blk, 0, stream>>>(PRE, lng, lnb, H2);

  // additive attention projections: pre-scaled by C_TANH, att_b folded into KAB
  tcvt<<<dim3(DD / 64, DD / 64), blk, 0, stream>>>(aqW, Twt, DD, DD);
  gemm_mfma<0, 0><<<dim3(DD / 64, M1 / 64), blk, 0, stream>>>(H2, Twt, aqb, nullptr, nullptr, QBu, M1, DD, DD, C_TANH);
  tcvt<<<dim3(DD / 64, DD / 64), blk, 0, stream>>>(akW, Twt, DD, DD);
  gemm_mfma<0, 0><<<dim3(DD / 64, (NB * LTN) / 64), blk, 0, stream>>>(text_bf, Twt, akb, attb, nullptr, KAB, NB * LTN, DD, DD, C_TANH);

  // additive attention: partial-e -> softmax -> pooled context
  addatt_e<<<dim3(4, LNN, NB), blk, 0, stream>>>(QBu, KAB, attv, E4);
  addatt_sm<<<dim3(M1), blk, 0, stream>>>(E4, lmask, Wvb);
  addatt_pool<<<dim3(4, NB), blk, 0, stream>>>(Wvb, text, gmask, H4);

  // MLP via split-K GEMV (weight-read-bound)
  dp_split<<<dim3(DHN / 64, 32), blk, 0, stream>>>(H4, dp1W, P1, DD, DHN);
  dp_reduce<1><<<dim3(DHN / 256, NB), blk, 0, stream>>>(P1, dp1b, G, DHN);
  dp_split<<<dim3(DINN / 64, 32), blk, 0, stream>>>(G, dp2W, P2, DHN, DINN);
  dp_reduce<0><<<dim3(DINN / 256, NB), blk, 0, stream>>>(P2, dp2b, Z, DINN);
}

// Round 6
// 242.124 us; speedup vs baseline: 4.9552x; 1.0263x over previous
//
#include <hip/hip_runtime.h>
#include <hip/hip_bf16.h>
#include <math.h>

#define NB 8        // batch
#define LNN 64      // nodes
#define LTN 256     // text len
#define DD 1024     // model dim
#define NH 4        // heads (each full width D)
#define HDD 4096    // NH*DD
#define DINN 2048
#define DHN 1024    // DIN/2

// 2*log2(e): tanh(x) = 1 - 2/(exp2(x*C)+1)
#define C_TANH 2.8853900817779268f

typedef __bf16 bf16x8 __attribute__((ext_vector_type(8)));
typedef float f32x4 __attribute__((ext_vector_type(4)));

__device__ __forceinline__ float b2f(ushort u) {
  union { float f; unsigned int i; } x; x.i = ((unsigned int)u) << 16; return x.f;
}
__device__ __forceinline__ ushort f2b(float f) {
  unsigned int u = __builtin_bit_cast(unsigned int, f);
  u = (u + 0x7FFFu + ((u >> 16) & 1u)) >> 16;
  return (ushort)u;
}

// ---------------- fp32 -> bf16 elementwise (n % 2048 == 0) ----------------
__global__ __launch_bounds__(256) void cvtk(const float* __restrict__ in,
                                            ushort* __restrict__ out, int n) {
  int i = (blockIdx.x * 256 + threadIdx.x) * 8;
  if (i >= n) return;
  float4 a = *(const float4*)(in + i);
  float4 b = *(const float4*)(in + i + 4);
  ushort4 o0 = {f2b(a.x), f2b(a.y), f2b(a.z), f2b(a.w)};
  ushort4 o1 = {f2b(b.x), f2b(b.y), f2b(b.z), f2b(b.w)};
  *(ushort4*)(out + i) = o0;
  *(ushort4*)(out + i + 4) = o1;
}

// ---------------- transpose + convert: W[K][N] fp32 -> Wt[N][K] bf16 ----------------
__global__ __launch_bounds__(256) void tcvt(const float* __restrict__ W,
                                            ushort* __restrict__ Wt, int K, int N) {
  __shared__ float tf[64][65];
  int k0 = blockIdx.y << 6, n0 = blockIdx.x << 6;
  int t = threadIdx.x;
  int r = t >> 2, c4 = (t & 3) * 16;
  const float* src = W + (size_t)(k0 + r) * N + n0 + c4;
  float4 v0 = *(const float4*)(src);
  float4 v1 = *(const float4*)(src + 4);
  float4 v2 = *(const float4*)(src + 8);
  float4 v3 = *(const float4*)(src + 12);
  *(float4*)&tf[r][c4] = v0;
  *(float4*)&tf[r][c4 + 4] = v1;
  *(float4*)&tf[r][c4 + 8] = v2;
  *(float4*)&tf[r][c4 + 12] = v3;
  __syncthreads();
  int nl = t >> 2, kc = (t & 3) * 16;
  ushort tmp[16];
#pragma unroll
  for (int j = 0; j < 16; ++j) tmp[j] = f2b(tf[kc + j][nl]);
  ushort* dst = Wt + (size_t)(n0 + nl) * K + k0 + kc;
  *(uint4*)(dst) = *(uint4*)&tmp[0];
  *(uint4*)(dst + 8) = *(uint4*)&tmp[8];
}

// ---------------- bf16 MFMA GEMM, BN=128: C[M,N] = A @ Bt^T (+biases) * scale ----------------
// 256 threads, 4 waves as 2Mx2N, wave tile 32x64. BK=64. Optional split-K via grid.z.
template <int OUTBF, int SPLIT>
__global__ __launch_bounds__(256) void gemmN128(const ushort* __restrict__ A,
                                                const ushort* __restrict__ Bt,
                                                const float* __restrict__ bias,
                                                const float* __restrict__ bias2,
                                                void* __restrict__ Cout,
                                                int M, int N, int K, float scale) {
  __shared__ ushort Als[64 * 64];
  __shared__ ushort Bls[128 * 64];
  int tid = threadIdx.x;
  int m0 = blockIdx.y << 6, n0 = blockIdx.x << 7;
  int Ks = K, kbase = 0;
  if constexpr (SPLIT) { Ks = K / gridDim.z; kbase = blockIdx.z * Ks; }

  // staging: thread t -> unit u=t&7 (16B), rows (t>>3)+i*32
  int srow = tid >> 3, su = tid & 7;
  int sx = (su ^ (srow & 7)) * 8;
  const ushort* ga = A + (size_t)(m0 + srow) * K + kbase + su * 8;
  const ushort* gb = Bt + (size_t)(n0 + srow) * K + kbase + su * 8;
  int wa0 = srow * 64 + sx, wa1 = (srow + 32) * 64 + sx;
  int wb0 = wa0, wb1 = wa1, wb2 = (srow + 64) * 64 + sx, wb3 = (srow + 96) * 64 + sx;
  const size_t rs32 = (size_t)32 * K;

  int lane = tid & 63, w = tid >> 6;
  int wm = w >> 1, wn = w & 1;
  int r = lane & 15, kg = lane >> 4;

  f32x4 acc[2][4] = {};

  uint4 pa0 = *(const uint4*)(ga);
  uint4 pa1 = *(const uint4*)(ga + rs32);
  uint4 pb0 = *(const uint4*)(gb);
  uint4 pb1 = *(const uint4*)(gb + rs32);
  uint4 pb2 = *(const uint4*)(gb + 2 * rs32);
  uint4 pb3 = *(const uint4*)(gb + 3 * rs32);

  for (int k0 = 0; k0 < Ks; k0 += 64) {
    __syncthreads();
    *(uint4*)&Als[wa0] = pa0; *(uint4*)&Als[wa1] = pa1;
    *(uint4*)&Bls[wb0] = pb0; *(uint4*)&Bls[wb1] = pb1;
    *(uint4*)&Bls[wb2] = pb2; *(uint4*)&Bls[wb3] = pb3;
    __syncthreads();
    int kn = k0 + 64;
    if (kn < Ks) {
      pa0 = *(const uint4*)(ga + kn);
      pa1 = *(const uint4*)(ga + rs32 + kn);
      pb0 = *(const uint4*)(gb + kn);
      pb1 = *(const uint4*)(gb + rs32 + kn);
      pb2 = *(const uint4*)(gb + 2 * rs32 + kn);
      pb3 = *(const uint4*)(gb + 3 * rs32 + kn);
    }
#pragma unroll
    for (int h = 0; h < 2; ++h) {
      int sa = ((h * 4 + kg) ^ (r & 7)) * 8;
      bf16x8 af[2], bfr[4];
#pragma unroll
      for (int m = 0; m < 2; ++m)
        af[m] = *(const bf16x8*)&Als[(wm * 32 + m * 16 + r) * 64 + sa];
#pragma unroll
      for (int n = 0; n < 4; ++n)
        bfr[n] = *(const bf16x8*)&Bls[(wn * 64 + n * 16 + r) * 64 + sa];
#pragma unroll
      for (int m = 0; m < 2; ++m)
#pragma unroll
        for (int n = 0; n < 4; ++n)
          acc[m][n] = __builtin_amdgcn_mfma_f32_16x16x32_bf16(af[m], bfr[n], acc[m][n], 0, 0, 0);
    }
  }
#pragma unroll
  for (int m = 0; m < 2; ++m)
#pragma unroll
    for (int n = 0; n < 4; ++n) {
      f32x4 a = acc[m][n];
#pragma unroll
      for (int v = 0; v < 4; ++v) {
        int row = m0 + wm * 32 + m * 16 + kg * 4 + v;
        int col = n0 + wn * 64 + n * 16 + r;
        if constexpr (SPLIT) {
          ((float*)Cout)[((size_t)blockIdx.z * M + row) * N + col] = a[v];
        } else {
          float x = a[v] + bias[col];
          if (bias2) x += bias2[col];
          x *= scale;
          if constexpr (OUTBF) ((ushort*)Cout)[(size_t)row * N + col] = f2b(x);
          else ((float*)Cout)[(size_t)row * N + col] = x;
        }
      }
    }
}

// ---------------- bf16 MFMA GEMM 64x64 (for small-N aq) ----------------
template <int OUTBF>
__global__ __launch_bounds__(256) void gemm_mfma(const ushort* __restrict__ A,
                                                 const ushort* __restrict__ Bt,
                                                 const float* __restrict__ bias,
                                                 void* __restrict__ Cout,
                                                 int M, int N, int K, float scale) {
  __shared__ ushort Als[64 * 64];
  __shared__ ushort Bls[64 * 64];
  int tid = threadIdx.x;
  int m0 = blockIdx.y << 6, n0 = blockIdx.x << 6;
  int srow = tid >> 3, su = tid & 7;
  int sx = (su ^ (srow & 7)) * 8;
  const ushort* ga = A + (size_t)(m0 + srow) * K + su * 8;
  const ushort* gb = Bt + (size_t)(n0 + srow) * K + su * 8;
  int wa0 = srow * 64 + sx, wa1 = (srow + 32) * 64 + sx;
  const size_t rs32 = (size_t)32 * K;
  int lane = tid & 63, w = tid >> 6;
  int wm = w >> 1, wn = w & 1;
  int r = lane & 15, kg = lane >> 4;
  f32x4 acc[2][2] = {};
  uint4 pa0 = *(const uint4*)(ga);
  uint4 pa1 = *(const uint4*)(ga + rs32);
  uint4 pb0 = *(const uint4*)(gb);
  uint4 pb1 = *(const uint4*)(gb + rs32);
  for (int k0 = 0; k0 < K; k0 += 64) {
    __syncthreads();
    *(uint4*)&Als[wa0] = pa0; *(uint4*)&Als[wa1] = pa1;
    *(uint4*)&Bls[wa0] = pb0; *(uint4*)&Bls[wa1] = pb1;
    __syncthreads();
    int kn = k0 + 64;
    if (kn < K) {
      pa0 = *(const uint4*)(ga + kn);
      pa1 = *(const uint4*)(ga + rs32 + kn);
      pb0 = *(const uint4*)(gb + kn);
      pb1 = *(const uint4*)(gb + rs32 + kn);
    }
#pragma unroll
    for (int h = 0; h < 2; ++h) {
      int sa = ((h * 4 + kg) ^ (r & 7)) * 8;
      bf16x8 af[2], bfr[2];
#pragma unroll
      for (int m = 0; m < 2; ++m)
        af[m] = *(const bf16x8*)&Als[(wm * 32 + m * 16 + r) * 64 + sa];
#pragma unroll
      for (int n = 0; n < 2; ++n)
        bfr[n] = *(const bf16x8*)&Bls[(wn * 32 + n * 16 + r) * 64 + sa];
#pragma unroll
      for (int m = 0; m < 2; ++m)
#pragma unroll
        for (int n = 0; n < 2; ++n)
          acc[m][n] = __builtin_amdgcn_mfma_f32_16x16x32_bf16(af[m], bfr[n], acc[m][n], 0, 0, 0);
    }
  }
#pragma unroll
  for (int m = 0; m < 2; ++m)
#pragma unroll
    for (int n = 0; n < 2; ++n) {
      f32x4 a = acc[m][n];
#pragma unroll
      for (int v = 0; v < 4; ++v) {
        int row = m0 + wm * 32 + m * 16 + kg * 4 + v;
        int col = n0 + wn * 32 + n * 16 + r;
        float x = (a[v] + bias[col]) * scale;
        if constexpr (OUTBF) ((ushort*)Cout)[(size_t)row * N + col] = f2b(x);
        else ((float*)Cout)[(size_t)row * N + col] = x;
      }
    }
}

// ---------------- Wo split-K reduce + bias + residual + LayerNorm -> bf16 ----------------
__global__ __launch_bounds__(256) void wo_ln(const float* __restrict__ P,
                                             const float* __restrict__ bo,
                                             const float* __restrict__ node,
                                             const float* __restrict__ g,
                                             const float* __restrict__ be,
                                             ushort* __restrict__ Y) {
  int row = blockIdx.x, tid = threadIdx.x;
  int c = tid * 4;
  const size_t MN = (size_t)512 * 1024;
  size_t o = (size_t)row * DD + c;
  float4 v0 = *(const float4*)(P + o);
  float4 v1 = *(const float4*)(P + MN + o);
  float4 v2 = *(const float4*)(P + 2 * MN + o);
  float4 v3 = *(const float4*)(P + 3 * MN + o);
  float4 rv = *(const float4*)(node + o);
  float4 bv = *(const float4*)(bo + c);
  float4 v;
  v.x = v0.x + v1.x + v2.x + v3.x + rv.x + bv.x;
  v.y = v0.y + v1.y + v2.y + v3.y + rv.y + bv.y;
  v.z = v0.z + v1.z + v2.z + v3.z + rv.z + bv.z;
  v.w = v0.w + v1.w + v2.w + v3.w + rv.w + bv.w;
  float s = v.x + v.y + v.z + v.w;
  float ss = v.x * v.x + v.y * v.y + v.z * v.z + v.w * v.w;
  for (int o2 = 32; o2; o2 >>= 1) {
    s += __shfl_xor(s, o2, 64);
    ss += __shfl_xor(ss, o2, 64);
  }
  __shared__ float rb_[8];
  int lane = tid & 63, w = tid >> 6;
  if (lane == 0) { rb_[w] = s; rb_[4 + w] = ss; }
  __syncthreads();
  s = rb_[0] + rb_[1] + rb_[2] + rb_[3];
  ss = rb_[4] + rb_[5] + rb_[6] + rb_[7];
  float mu = s * (1.f / 1024.f);
  float var = ss * (1.f / 1024.f) - mu * mu;
  float rstd = rsqrtf(var + 1e-5f);
  ushort4 o4;
  o4.x = f2b((v.x - mu) * rstd * g[c + 0] + be[c + 0]);
  o4.y = f2b((v.y - mu) * rstd * g[c + 1] + be[c + 1]);
  o4.z = f2b((v.z - mu) * rstd * g[c + 2] + be[c + 2]);
  o4.w = f2b((v.w - mu) * rstd * g[c + 3] + be[c + 3]);
  *(ushort4*)(Y + (size_t)row * DD + c) = o4;
}

// ---------------- attn part 1: S = softmax(Q K^T / 32) per (b,h) -> P bf16 ----------------
__global__ __launch_bounds__(256) void attn_scores(const ushort* __restrict__ Qb,
                                                   const ushort* __restrict__ Kb,
                                                   const int* __restrict__ gmask,
                                                   ushort* __restrict__ P) {
  int bh = blockIdx.x;
  int b = bh >> 2;
  size_t base = ((size_t)b * LNN) * HDD + (size_t)(bh & 3) * DD;
  __shared__ ushort Als[64 * 64];
  __shared__ ushort Bls[64 * 64];
  __shared__ float S[64][68];
  int tid = threadIdx.x;
  int srow = tid >> 2, su0 = (tid & 3) * 2;
  const ushort* ga = Qb + base + (size_t)srow * HDD + su0 * 8;
  const ushort* gb = Kb + base + (size_t)srow * HDD + su0 * 8;
  int wa0 = srow * 64 + ((su0) ^ (srow & 7)) * 8;
  int wa1 = srow * 64 + ((su0 + 1) ^ (srow & 7)) * 8;
  int lane = tid & 63, w = tid >> 6;
  int wm = w >> 1, wn = w & 1;
  int r = lane & 15, kg = lane >> 4;
  f32x4 acc[2][2] = {};
  uint4 pa0 = *(const uint4*)(ga);
  uint4 pa1 = *(const uint4*)(ga + 8);
  uint4 pb0 = *(const uint4*)(gb);
  uint4 pb1 = *(const uint4*)(gb + 8);
  for (int k0 = 0; k0 < DD; k0 += 64) {
    __syncthreads();
    *(uint4*)&Als[wa0] = pa0; *(uint4*)&Als[wa1] = pa1;
    *(uint4*)&Bls[wa0] = pb0; *(uint4*)&Bls[wa1] = pb1;
    __syncthreads();
    int kn = k0 + 64;
    if (kn < DD) {
      pa0 = *(const uint4*)(ga + kn);
      pa1 = *(const uint4*)(ga + kn + 8);
      pb0 = *(const uint4*)(gb + kn);
      pb1 = *(const uint4*)(gb + kn + 8);
    }
#pragma unroll
    for (int h = 0; h < 2; ++h) {
      int sa = ((h * 4 + kg) ^ (r & 7)) * 8;
      bf16x8 af[2], bfr[2];
#pragma unroll
      for (int m = 0; m < 2; ++m)
        af[m] = *(const bf16x8*)&Als[(wm * 32 + m * 16 + r) * 64 + sa];
#pragma unroll
      for (int n = 0; n < 2; ++n)
        bfr[n] = *(const bf16x8*)&Bls[(wn * 32 + n * 16 + r) * 64 + sa];
#pragma unroll
      for (int m = 0; m < 2; ++m)
#pragma unroll
        for (int n = 0; n < 2; ++n)
          acc[m][n] = __builtin_amdgcn_mfma_f32_16x16x32_bf16(af[m], bfr[n], acc[m][n], 0, 0, 0);
    }
  }
#pragma unroll
  for (int m = 0; m < 2; ++m)
#pragma unroll
    for (int n = 0; n < 2; ++n)
#pragma unroll
      for (int v = 0; v < 4; ++v)
        S[wm * 32 + m * 16 + kg * 4 + v][wn * 32 + n * 16 + r] = acc[m][n][v];
  __syncthreads();
  bool valid = gmask[b * LNN + lane] != 0;
  for (int i = 0; i < 16; ++i) {
    int q = w * 16 + i;
    float v = valid ? S[q][lane] * 0.03125f : -__builtin_inff();
    float mx = v;
    for (int o = 32; o; o >>= 1) mx = fmaxf(mx, __shfl_xor(mx, o, 64));
    float e = valid ? __expf(v - mx) : 0.f;
    float s = e;
    for (int o = 32; o; o >>= 1) s += __shfl_xor(s, o, 64);
    P[(size_t)bh * 4096 + q * 64 + lane] = f2b(__fdividef(e, s));
  }
}

// ---------------- attn part 2: O[q,d-tile] = P @ V per (b,h,dtile) ----------------
__global__ __launch_bounds__(256) void attn_pv(const ushort* __restrict__ P,
                                               const ushort* __restrict__ Vb,
                                               ushort* __restrict__ AO) {
  int bid = blockIdx.x;
  int bh = bid >> 4, dt = bid & 15;
  int d0 = dt * 64;
  size_t vbase = ((size_t)(bh >> 2) * LNN) * HDD + (size_t)(bh & 3) * DD;
  __shared__ ushort Pls[64 * 72];
  __shared__ ushort Vt[64 * 72];
  int tid = threadIdx.x;
  {
    int row = tid >> 2, c = (tid & 3) * 16;
    const ushort* src = P + (size_t)bh * 4096 + row * 64 + c;
    uint4 v0 = *(const uint4*)src;
    uint4 v1 = *(const uint4*)(src + 8);
    *(uint4*)&Pls[row * 72 + c] = v0;
    *(uint4*)&Pls[row * 72 + c + 8] = v1;
  }
  {
    int kq = tid >> 2, dq = (tid & 3) * 16;
    const ushort* src = Vb + vbase + (size_t)kq * HDD + d0 + dq;
    uint4 v0 = *(const uint4*)src;
    uint4 v1 = *(const uint4*)(src + 8);
    ushort tmp[16];
    *(uint4*)&tmp[0] = v0;
    *(uint4*)&tmp[8] = v1;
#pragma unroll
    for (int j = 0; j < 16; ++j) Vt[(dq + j) * 72 + kq] = tmp[j];
  }
  __syncthreads();
  int lane = tid & 63, w = tid >> 6;
  int wm = w >> 1, wn = w & 1;
  int r = lane & 15, kg = lane >> 4;
  f32x4 acc[2][2] = {};
#pragma unroll
  for (int h = 0; h < 2; ++h) {
    int ko = h * 32 + kg * 8;
    bf16x8 af[2], bfr[2];
#pragma unroll
    for (int m = 0; m < 2; ++m)
      af[m] = *(const bf16x8*)&Pls[(wm * 32 + m * 16 + r) * 72 + ko];
#pragma unroll
    for (int n = 0; n < 2; ++n)
      bfr[n] = *(const bf16x8*)&Vt[(wn * 32 + n * 16 + r) * 72 + ko];
#pragma unroll
    for (int m = 0; m < 2; ++m)
#pragma unroll
      for (int n = 0; n < 2; ++n)
        acc[m][n] = __builtin_amdgcn_mfma_f32_16x16x32_bf16(af[m], bfr[n], acc[m][n], 0, 0, 0);
  }
#pragma unroll
  for (int m = 0; m < 2; ++m)
#pragma unroll
    for (int n = 0; n < 2; ++n) {
      f32x4 a = acc[m][n];
#pragma unroll
      for (int v = 0; v < 4; ++v) {
        int q = wm * 32 + m * 16 + kg * 4 + v;
        int col = wn * 32 + n * 16 + r;
        AO[vbase + (size_t)q * HDD + d0 + col] = f2b(a[v]);
      }
    }
}

// ---------------- additive attention phase 1: partial e over d-quarter ----------------
__global__ __launch_bounds__(256) void addatt_e(const float* __restrict__ QBu,
                                                const float* __restrict__ KAB,
                                                const float* __restrict__ av_,
                                                float* __restrict__ E4) {
  int dq = blockIdx.x, q = blockIdx.y, b = blockIdx.z;
  int tid = threadIdx.x;
  __shared__ float qs[256], avs[256];
  __shared__ float red[4];
  int bq = b * LNN + q;
  qs[tid] = QBu[(size_t)bq * DD + dq * 256 + tid];
  float av = av_[dq * 256 + tid];
  avs[tid] = av;
  float s = av;
  for (int o = 32; o; o >>= 1) s += __shfl_xor(s, o, 64);
  int lane = tid & 63, w = tid >> 6;
  if (lane == 0) red[w] = s;
  __syncthreads();
  float sumav = red[0] + red[1] + red[2] + red[3];
  const float* kr = KAB + (size_t)(b * LTN + tid) * DD + dq * 256;
  float a0 = 0.f, a1 = 0.f, a2 = 0.f, a3 = 0.f;
#pragma unroll 4
  for (int d = 0; d < 256; d += 8) {
    float4 kv0 = *(const float4*)(kr + d);
    float4 kv1 = *(const float4*)(kr + d + 4);
    float4 q0 = *(const float4*)&qs[d];
    float4 q1 = *(const float4*)&qs[d + 4];
    float4 w0 = *(const float4*)&avs[d];
    float4 w1 = *(const float4*)&avs[d + 4];
    a0 = fmaf(w0.x, __builtin_amdgcn_rcpf(__builtin_amdgcn_exp2f(q0.x + kv0.x) + 1.f), a0);
    a1 = fmaf(w0.y, __builtin_amdgcn_rcpf(__builtin_amdgcn_exp2f(q0.y + kv0.y) + 1.f), a1);
    a2 = fmaf(w0.z, __builtin_amdgcn_rcpf(__builtin_amdgcn_exp2f(q0.z + kv0.z) + 1.f), a2);
    a3 = fmaf(w0.w, __builtin_amdgcn_rcpf(__builtin_amdgcn_exp2f(q0.w + kv0.w) + 1.f), a3);
    a0 = fmaf(w1.x, __builtin_amdgcn_rcpf(__builtin_amdgcn_exp2f(q1.x + kv1.x) + 1.f), a0);
    a1 = fmaf(w1.y, __builtin_amdgcn_rcpf(__builtin_amdgcn_exp2f(q1.y + kv1.y) + 1.f), a1);
    a2 = fmaf(w1.z, __builtin_amdgcn_rcpf(__builtin_amdgcn_exp2f(q1.z + kv1.z) + 1.f), a2);
    a3 = fmaf(w1.w, __builtin_amdgcn_rcpf(__builtin_amdgcn_exp2f(q1.w + kv1.w) + 1.f), a3);
  }
  E4[((size_t)dq * 512 + bq) * LTN + tid] = sumav - 2.f * ((a0 + a1) + (a2 + a3));
}

// ---------------- additive attention phase 2: sum partials + masked softmax -> w ----------------
__global__ __launch_bounds__(256) void addatt_sm(const float* __restrict__ E4,
                                                 const int* __restrict__ lmask,
                                                 float* __restrict__ Wv) {
  int bq = blockIdx.x;
  int b = bq >> 6;
  int tid = threadIdx.x;
  __shared__ float rb_[8];
  float e = E4[(size_t)bq * LTN + tid] + E4[((size_t)512 + bq) * LTN + tid] +
            E4[((size_t)1024 + bq) * LTN + tid] + E4[((size_t)1536 + bq) * LTN + tid];
  bool valid = lmask[b * LTN + tid] != 0;
  float v = valid ? e : -__builtin_inff();
  int lane = tid & 63, w = tid >> 6;
  float m = v;
  for (int o = 32; o; o >>= 1) m = fmaxf(m, __shfl_xor(m, o, 64));
  if (lane == 0) rb_[w] = m;
  __syncthreads();
  m = fmaxf(fmaxf(rb_[0], rb_[1]), fmaxf(rb_[2], rb_[3]));
  float ex = valid ? __expf(v - m) : 0.f;
  float sm = ex;
  for (int o = 32; o; o >>= 1) sm += __shfl_xor(sm, o, 64);
  if (lane == 0) rb_[4 + w] = sm;
  __syncthreads();
  sm = rb_[4] + rb_[5] + rb_[6] + rb_[7];
  Wv[(size_t)bq * LTN + tid] = __fdividef(ex, sm);
}

// ---------------- additive attention phase 3: pooled context ----------------
__global__ __launch_bounds__(256) void addatt_pool(const float* __restrict__ Wv,
                                                   const float* __restrict__ text,
                                                   const int* __restrict__ gmask,
                                                   float* __restrict__ H4) {
  int dt = blockIdx.x, b = blockIdx.y;
  int tid = threadIdx.x;
  __shared__ float cf[LTN];
  float c = 0.f, cnt = 0.f;
#pragma unroll 8
  for (int q = 0; q < LNN; ++q) {
    float m = (gmask[b * LNN + q] != 0) ? 1.f : 0.f;
    cnt += m;
    c = fmaf(m, Wv[(size_t)(b * LNN + q) * LTN + tid], c);
  }
  cf[tid] = c;
  cnt = fmaxf(cnt, 9.765625e-04f);
  __syncthreads();
  int d = dt * 256 + tid;
  const float* tb = text + (size_t)b * LTN * DD + d;
  float acc = 0.f;
#pragma unroll 8
  for (int k = 0; k < LTN; ++k) acc = fmaf(cf[k], tb[(size_t)k * DD], acc);
  H4[b * DD + d] = acc / cnt;
}

// ---------------- split-K GEMV ----------------
__global__ __launch_bounds__(256) void dp_split(const float* __restrict__ X,
                                                const float* __restrict__ W,
                                                float* __restrict__ P,
                                                int K, int N) {
  int jt = blockIdx.x, kt = blockIdx.y;
  int t = threadIdx.x;
  __shared__ float xs[8][32];
  if (t < 64) {
    int b = t >> 3, kk = (t & 7) * 4;
    *(float4*)&xs[b][kk] = *(const float4*)(X + (size_t)b * K + kt * 32 + kk);
  }
  __syncthreads();
  int j = jt * 64 + (t & 63);
  int bg = (t >> 6) * 2;
  const float* wp = W + (size_t)(kt * 32) * N + j;
  float a0 = 0.f, a1 = 0.f;
#pragma unroll
  for (int k = 0; k < 32; ++k) {
    float w = wp[(size_t)k * N];
    a0 = fmaf(xs[bg + 0][k], w, a0);
    a1 = fmaf(xs[bg + 1][k], w, a1);
  }
  P[((size_t)kt * 8 + bg + 0) * N + j] = a0;
  P[((size_t)kt * 8 + bg + 1) * N + j] = a1;
}

template <int GELU>
__global__ __launch_bounds__(256) void dp_reduce(const float* __restrict__ P,
                                                 const float* __restrict__ bias,
                                                 float* __restrict__ O, int N) {
  int b = blockIdx.y;
  int j = blockIdx.x * 256 + threadIdx.x;
  float s = bias[j];
#pragma unroll 8
  for (int kt = 0; kt < 32; ++kt) s += P[((size_t)kt * 8 + b) * N + j];
  if constexpr (GELU) s = 0.5f * s * (1.f + erff(s * 0.70710678118654752440f));
  O[(size_t)b * N + j] = s;
}

extern "C" void kernel_launch(void* const* d_in, const int* in_sizes, int n_in,
                              void* d_out, int out_size, void* d_ws, size_t ws_size,
                              hipStream_t stream) {
  const float* text = (const float*)d_in[0];
  const float* node = (const float*)d_in[1];
  const float* Wq = (const float*)d_in[2];
  const float* bq = (const float*)d_in[3];
  const float* Wk = (const float*)d_in[4];
  const float* bk = (const float*)d_in[5];
  const float* Wv = (const float*)d_in[6];
  const float* bv = (const float*)d_in[7];
  const float* Wo = (const float*)d_in[8];
  const float* bo = (const float*)d_in[9];
  const float* lng = (const float*)d_in[10];
  const float* lnb = (const float*)d_in[11];
  const float* aqW = (const float*)d_in[12];
  const float* aqb = (const float*)d_in[13];
  const float* akW = (const float*)d_in[14];
  const float* akb = (const float*)d_in[15];
  const float* attv = (const float*)d_in[16];
  const float* attb = (const float*)d_in[17];
  const float* dp1W = (const float*)d_in[18];
  const float* dp1b = (const float*)d_in[19];
  const float* dp2W = (const float*)d_in[20];
  const float* dp2b = (const float*)d_in[21];
  const int* gmask = (const int*)d_in[22];
  const int* lmask = (const int*)d_in[23];
  (void)in_sizes; (void)n_in; (void)out_size; (void)ws_size;

  char* base = (char*)d_ws;
#define MB(x) (((size_t)(x)) << 20)
  ushort* Twt = (ushort*)(base);               // 8MB, reused per weight
  ushort* node_bf = (ushort*)(base + MB(8));   // 1MB
  ushort* text_bf = (ushort*)(base + MB(9));   // 4MB
  ushort* Qb = (ushort*)(base + MB(13));       // 4MB
  ushort* Kb = (ushort*)(base + MB(17));       // 4MB
  ushort* Vb = (ushort*)(base + MB(21));       // 4MB
  ushort* AO = (ushort*)(base + MB(25));       // 4MB
  float* E4 = (float*)(base + MB(13));         // 2MB (Qb dead after attn_scores)
  float* Wvb = (float*)(base + MB(15));        // 512KB
  ushort* H2 = (ushort*)(base + MB(15) + (512 << 10));  // 1MB
  float* P_Wo = (float*)(base + MB(17));       // 8MB partials (Kb/Vb dead)
  float* P1 = (float*)(base + MB(18));         // 1MB dp1 partials (dead P_Wo region, used after)
  float* P2 = (float*)(base + MB(19));         // 2MB dp2 partials
  float* QBu = (float*)(base + MB(21));        // 2MB (Vb dead after attn_pv)... careful: P_Wo spans MB17-25!
  float* KAB = (float*)(base + MB(25));        // 8MB (AO dead after Wo gemm)
  float* H4 = (float*)(base + MB(33));         // 32KB
  float* G = (float*)(base + MB(33) + 32768);  // 32KB
  ushort* Pws = (ushort*)(base + MB(33) + 65536);  // 256KB attn probs
  float* Z = (float*)d_out;
#undef MB
  // NOTE on aliasing order: P_Wo (MB17-25) is written by the Wo split gemm and consumed
  // by wo_ln immediately after; QBu (MB21-23) is written AFTER wo_ln (by the aq gemm),
  // and P1/P2 (MB18-21) are written after that (dp phase). H2 sits outside all of them.

  const int M1 = NB * LNN;  // 512
  dim3 blk(256);

  cvtk<<<dim3(512 * 1024 / 2048), blk, 0, stream>>>(node, node_bf, 512 * 1024);
  cvtk<<<dim3(NB * LTN * DD / 2048), blk, 0, stream>>>(text, text_bf, NB * LTN * DD);

  // QKV projections (bf16 MFMA, BN=128)
  tcvt<<<dim3(HDD / 64, DD / 64), blk, 0, stream>>>(Wq, Twt, DD, HDD);
  gemmN128<1, 0><<<dim3(HDD / 128, M1 / 64), blk, 0, stream>>>(node_bf, Twt, bq, nullptr, Qb, M1, HDD, DD, 1.f);
  tcvt<<<dim3(HDD / 64, DD / 64), blk, 0, stream>>>(Wk, Twt, DD, HDD);
  gemmN128<1, 0><<<dim3(HDD / 128, M1 / 64), blk, 0, stream>>>(node_bf, Twt, bk, nullptr, Kb, M1, HDD, DD, 1.f);
  tcvt<<<dim3(HDD / 64, DD / 64), blk, 0, stream>>>(Wv, Twt, DD, HDD);
  gemmN128<1, 0><<<dim3(HDD / 128, M1 / 64), blk, 0, stream>>>(node_bf, Twt, bv, nullptr, Vb, M1, HDD, DD, 1.f);

  // self-attention (MFMA scores + MFMA PV)
  attn_scores<<<dim3(NB * NH), blk, 0, stream>>>(Qb, Kb, gmask, Pws);
  attn_pv<<<dim3(NB * NH * 16), blk, 0, stream>>>(Pws, Vb, AO);

  // output proj: split-K 4-way partials, then fused reduce+residual+LayerNorm
  tcvt<<<dim3(DD / 64, HDD / 64), blk, 0, stream>>>(Wo, Twt, HDD, DD);
  gemmN128<0, 1><<<dim3(DD / 128, M1 / 64, 4), blk, 0, stream>>>(AO, Twt, nullptr, nullptr, P_Wo, M1, DD, HDD, 1.f);
  wo_ln<<<dim3(M1), blk, 0, stream>>>(P_Wo, bo, node, lng, lnb, H2);

  // additive attention projections: pre-scaled by C_TANH, att_b folded into KAB
  tcvt<<<dim3(DD / 64, DD / 64), blk, 0, stream>>>(aqW, Twt, DD, DD);
  gemm_mfma<0><<<dim3(DD / 64, M1 / 64), blk, 0, stream>>>(H2, Twt, aqb, QBu, M1, DD, DD, C_TANH);
  tcvt<<<dim3(DD / 64, DD / 64), blk, 0, stream>>>(akW, Twt, DD, DD);
  gemmN128<0, 0><<<dim3(DD / 128, (NB * LTN) / 64), blk, 0, stream>>>(text_bf, Twt, akb, attb, KAB, NB * LTN, DD, DD, C_TANH);

  // additive attention: partial-e -> softmax -> pooled context
  addatt_e<<<dim3(4, LNN, NB), blk, 0, stream>>>(QBu, KAB, attv, E4);
  addatt_sm<<<dim3(M1), blk, 0, stream>>>(E4, lmask, Wvb);
  addatt_pool<<<dim3(4, NB), blk, 0, stream>>>(Wvb, text, gmask, H4);

  // MLP via split-K GEMV (weight-read-bound)
  dp_split<<<dim3(DHN / 64, 32), blk, 0, stream>>>(H4, dp1W, P1, DD, DHN);
  dp_reduce<1><<<dim3(DHN / 256, NB), blk, 0, stream>>>(P1, dp1b, G, DHN);
  dp_split<<<dim3(DINN / 64, 32), blk, 0, stream>>>(G, dp2W, P2, DHN, DINN);
  dp_reduce<0><<<dim3(DINN / 256, NB), blk, 0, stream>>>(P2, dp2b, Z, DINN);
}

// Round 7
// 184.299 us; speedup vs baseline: 6.5099x; 1.3138x over previous
//
#include <hip/hip_runtime.h>
#include <hip/hip_bf16.h>
#include <math.h>

#define NB 8        // batch
#define LNN 64      // nodes
#define LTN 256     // text len
#define DD 1024     // model dim
#define NH 4        // heads (each full width D)
#define HDD 4096    // NH*DD
#define DINN 2048
#define DHN 1024    // DIN/2

// 2*log2(e): tanh(x) = 1 - 2/(exp2(x*C)+1)
#define C_TANH 2.8853900817779268f

typedef __bf16 bf16x8 __attribute__((ext_vector_type(8)));
typedef float f32x4 __attribute__((ext_vector_type(4)));

__device__ __forceinline__ float b2f(ushort u) {
  union { float f; unsigned int i; } x; x.i = ((unsigned int)u) << 16; return x.f;
}
__device__ __forceinline__ ushort f2b(float f) {
  unsigned int u = __builtin_bit_cast(unsigned int, f);
  u = (u + 0x7FFFu + ((u >> 16) & 1u)) >> 16;
  return (ushort)u;
}

// ---------------- fused fp32->bf16 for node + text in one launch ----------------
__global__ __launch_bounds__(256) void cvt_all(const float* __restrict__ node,
                                               ushort* __restrict__ node_bf,
                                               const float* __restrict__ text,
                                               ushort* __restrict__ text_bf) {
  int bid = blockIdx.x;
  const float* in;
  ushort* out;
  int i;
  if (bid < 256) { in = node; out = node_bf; i = (bid * 256 + threadIdx.x) * 8; }
  else { in = text; out = text_bf; i = ((bid - 256) * 256 + threadIdx.x) * 8; }
  float4 a = *(const float4*)(in + i);
  float4 b = *(const float4*)(in + i + 4);
  ushort4 o0 = {f2b(a.x), f2b(a.y), f2b(a.z), f2b(a.w)};
  ushort4 o1 = {f2b(b.x), f2b(b.y), f2b(b.z), f2b(b.w)};
  *(ushort4*)(out + i) = o0;
  *(ushort4*)(out + i + 4) = o1;
}

// ---------------- transpose+convert up to 3 weights: W[K][N] fp32 -> Wt[z][N][K] bf16 ----------------
__global__ __launch_bounds__(256) void tcvt3(const float* __restrict__ W0,
                                             const float* __restrict__ W1,
                                             const float* __restrict__ W2,
                                             ushort* __restrict__ Wt, int K, int N) {
  int z = blockIdx.z;
  const float* W = (z == 0) ? W0 : ((z == 1) ? W1 : W2);
  ushort* dst0 = Wt + (size_t)z * K * N;
  __shared__ float tf[64][65];
  int k0 = blockIdx.y << 6, n0 = blockIdx.x << 6;
  int t = threadIdx.x;
  int r = t >> 2, c4 = (t & 3) * 16;
  const float* src = W + (size_t)(k0 + r) * N + n0 + c4;
  float4 v0 = *(const float4*)(src);
  float4 v1 = *(const float4*)(src + 4);
  float4 v2 = *(const float4*)(src + 8);
  float4 v3 = *(const float4*)(src + 12);
  *(float4*)&tf[r][c4] = v0;
  *(float4*)&tf[r][c4 + 4] = v1;
  *(float4*)&tf[r][c4 + 8] = v2;
  *(float4*)&tf[r][c4 + 12] = v3;
  __syncthreads();
  int nl = t >> 2, kc = (t & 3) * 16;
  ushort tmp[16];
#pragma unroll
  for (int j = 0; j < 16; ++j) tmp[j] = f2b(tf[kc + j][nl]);
  ushort* dst = dst0 + (size_t)(n0 + nl) * K + k0 + kc;
  *(uint4*)(dst) = *(uint4*)&tmp[0];
  *(uint4*)(dst + 8) = *(uint4*)&tmp[8];
}

// ---------------- QKV gemm (up to 3 via grid.z): bf16 out, +bias ----------------
__global__ __launch_bounds__(256) void gemm_qkv3(const ushort* __restrict__ A,
                                                 const ushort* __restrict__ BtB,
                                                 const float* __restrict__ b0,
                                                 const float* __restrict__ b1,
                                                 const float* __restrict__ b2,
                                                 ushort* __restrict__ o0,
                                                 ushort* __restrict__ o1,
                                                 ushort* __restrict__ o2,
                                                 int M, int N, int K) {
  int z = blockIdx.z;
  const ushort* Bt = BtB + (size_t)z * N * K;
  const float* bias = (z == 0) ? b0 : ((z == 1) ? b1 : b2);
  ushort* Cout = (z == 0) ? o0 : ((z == 1) ? o1 : o2);
  __shared__ ushort Als[64 * 64];
  __shared__ ushort Bls[128 * 64];
  int tid = threadIdx.x;
  int m0 = blockIdx.y << 6, n0 = blockIdx.x << 7;
  int srow = tid >> 3, su = tid & 7;
  int sx = (su ^ (srow & 7)) * 8;
  const ushort* ga = A + (size_t)(m0 + srow) * K + su * 8;
  const ushort* gb = Bt + (size_t)(n0 + srow) * K + su * 8;
  int wa0 = srow * 64 + sx, wa1 = (srow + 32) * 64 + sx;
  int wb2 = (srow + 64) * 64 + sx, wb3 = (srow + 96) * 64 + sx;
  const size_t rs32 = (size_t)32 * K;
  int lane = tid & 63, w = tid >> 6;
  int wm = w >> 1, wn = w & 1;
  int r = lane & 15, kg = lane >> 4;
  f32x4 acc[2][4] = {};
  uint4 pa0 = *(const uint4*)(ga);
  uint4 pa1 = *(const uint4*)(ga + rs32);
  uint4 pb0 = *(const uint4*)(gb);
  uint4 pb1 = *(const uint4*)(gb + rs32);
  uint4 pb2 = *(const uint4*)(gb + 2 * rs32);
  uint4 pb3 = *(const uint4*)(gb + 3 * rs32);
  for (int k0 = 0; k0 < K; k0 += 64) {
    __syncthreads();
    *(uint4*)&Als[wa0] = pa0; *(uint4*)&Als[wa1] = pa1;
    *(uint4*)&Bls[wa0] = pb0; *(uint4*)&Bls[wa1] = pb1;
    *(uint4*)&Bls[wb2] = pb2; *(uint4*)&Bls[wb3] = pb3;
    __syncthreads();
    int kn = k0 + 64;
    if (kn < K) {
      pa0 = *(const uint4*)(ga + kn);
      pa1 = *(const uint4*)(ga + rs32 + kn);
      pb0 = *(const uint4*)(gb + kn);
      pb1 = *(const uint4*)(gb + rs32 + kn);
      pb2 = *(const uint4*)(gb + 2 * rs32 + kn);
      pb3 = *(const uint4*)(gb + 3 * rs32 + kn);
    }
#pragma unroll
    for (int h = 0; h < 2; ++h) {
      int sa = ((h * 4 + kg) ^ (r & 7)) * 8;
      bf16x8 af[2], bfr[4];
#pragma unroll
      for (int m = 0; m < 2; ++m)
        af[m] = *(const bf16x8*)&Als[(wm * 32 + m * 16 + r) * 64 + sa];
#pragma unroll
      for (int n = 0; n < 4; ++n)
        bfr[n] = *(const bf16x8*)&Bls[(wn * 64 + n * 16 + r) * 64 + sa];
#pragma unroll
      for (int m = 0; m < 2; ++m)
#pragma unroll
        for (int n = 0; n < 4; ++n)
          acc[m][n] = __builtin_amdgcn_mfma_f32_16x16x32_bf16(af[m], bfr[n], acc[m][n], 0, 0, 0);
    }
  }
#pragma unroll
  for (int m = 0; m < 2; ++m)
#pragma unroll
    for (int n = 0; n < 4; ++n) {
      f32x4 a = acc[m][n];
#pragma unroll
      for (int v = 0; v < 4; ++v) {
        int row = m0 + wm * 32 + m * 16 + kg * 4 + v;
        int col = n0 + wn * 64 + n * 16 + r;
        Cout[(size_t)row * N + col] = f2b(a[v] + bias[col]);
      }
    }
}

// ---------------- Wo gemm with split-K (grid.z): fp32 partials, no bias ----------------
__global__ __launch_bounds__(256) void gemm_wo_split(const ushort* __restrict__ A,
                                                     const ushort* __restrict__ Bt,
                                                     float* __restrict__ P,
                                                     int M, int N, int K) {
  __shared__ ushort Als[64 * 64];
  __shared__ ushort Bls[128 * 64];
  int tid = threadIdx.x;
  int m0 = blockIdx.y << 6, n0 = blockIdx.x << 7;
  int Ks = K >> 2, kbase = blockIdx.z * Ks;
  int srow = tid >> 3, su = tid & 7;
  int sx = (su ^ (srow & 7)) * 8;
  const ushort* ga = A + (size_t)(m0 + srow) * K + kbase + su * 8;
  const ushort* gb = Bt + (size_t)(n0 + srow) * K + kbase + su * 8;
  int wa0 = srow * 64 + sx, wa1 = (srow + 32) * 64 + sx;
  int wb2 = (srow + 64) * 64 + sx, wb3 = (srow + 96) * 64 + sx;
  const size_t rs32 = (size_t)32 * K;
  int lane = tid & 63, w = tid >> 6;
  int wm = w >> 1, wn = w & 1;
  int r = lane & 15, kg = lane >> 4;
  f32x4 acc[2][4] = {};
  uint4 pa0 = *(const uint4*)(ga);
  uint4 pa1 = *(const uint4*)(ga + rs32);
  uint4 pb0 = *(const uint4*)(gb);
  uint4 pb1 = *(const uint4*)(gb + rs32);
  uint4 pb2 = *(const uint4*)(gb + 2 * rs32);
  uint4 pb3 = *(const uint4*)(gb + 3 * rs32);
  for (int k0 = 0; k0 < Ks; k0 += 64) {
    __syncthreads();
    *(uint4*)&Als[wa0] = pa0; *(uint4*)&Als[wa1] = pa1;
    *(uint4*)&Bls[wa0] = pb0; *(uint4*)&Bls[wa1] = pb1;
    *(uint4*)&Bls[wb2] = pb2; *(uint4*)&Bls[wb3] = pb3;
    __syncthreads();
    int kn = k0 + 64;
    if (kn < Ks) {
      pa0 = *(const uint4*)(ga + kn);
      pa1 = *(const uint4*)(ga + rs32 + kn);
      pb0 = *(const uint4*)(gb + kn);
      pb1 = *(const uint4*)(gb + rs32 + kn);
      pb2 = *(const uint4*)(gb + 2 * rs32 + kn);
      pb3 = *(const uint4*)(gb + 3 * rs32 + kn);
    }
#pragma unroll
    for (int h = 0; h < 2; ++h) {
      int sa = ((h * 4 + kg) ^ (r & 7)) * 8;
      bf16x8 af[2], bfr[4];
#pragma unroll
      for (int m = 0; m < 2; ++m)
        af[m] = *(const bf16x8*)&Als[(wm * 32 + m * 16 + r) * 64 + sa];
#pragma unroll
      for (int n = 0; n < 4; ++n)
        bfr[n] = *(const bf16x8*)&Bls[(wn * 64 + n * 16 + r) * 64 + sa];
#pragma unroll
      for (int m = 0; m < 2; ++m)
#pragma unroll
        for (int n = 0; n < 4; ++n)
          acc[m][n] = __builtin_amdgcn_mfma_f32_16x16x32_bf16(af[m], bfr[n], acc[m][n], 0, 0, 0);
    }
  }
#pragma unroll
  for (int m = 0; m < 2; ++m)
#pragma unroll
    for (int n = 0; n < 4; ++n) {
      f32x4 a = acc[m][n];
#pragma unroll
      for (int v = 0; v < 4; ++v) {
        int row = m0 + wm * 32 + m * 16 + kg * 4 + v;
        int col = n0 + wn * 64 + n * 16 + r;
        P[((size_t)blockIdx.z * M + row) * N + col] = a[v];
      }
    }
}

// ---------------- aq+ak gemm (M-concat row select): fp32 out, *C_TANH ----------------
__global__ __launch_bounds__(256) void gemm_aqak(const ushort* __restrict__ H2,
                                                 const ushort* __restrict__ Tbf,
                                                 const ushort* __restrict__ TwtAQ,
                                                 const float* __restrict__ aqb,
                                                 const float* __restrict__ akb,
                                                 const float* __restrict__ attb,
                                                 float* __restrict__ QBu,
                                                 float* __restrict__ KAB,
                                                 int N, int K) {
  __shared__ ushort Als[64 * 64];
  __shared__ ushort Bls[128 * 64];
  int tid = threadIdx.x;
  int gm0 = blockIdx.y << 6, n0 = blockIdx.x << 7;
  const ushort* Abase;
  const ushort* Bt;
  const float* bias;
  const float* bias2;
  float* Obase;
  if (gm0 < 512) {
    Abase = H2 + (size_t)gm0 * K;
    Bt = TwtAQ;
    bias = aqb; bias2 = nullptr;
    Obase = QBu + (size_t)gm0 * N;
  } else {
    Abase = Tbf + (size_t)(gm0 - 512) * K;
    Bt = TwtAQ + (size_t)N * K;  // ak is second converted weight
    bias = akb; bias2 = attb;
    Obase = KAB + (size_t)(gm0 - 512) * N;
  }
  int srow = tid >> 3, su = tid & 7;
  int sx = (su ^ (srow & 7)) * 8;
  const ushort* ga = Abase + (size_t)srow * K + su * 8;
  const ushort* gb = Bt + (size_t)(n0 + srow) * K + su * 8;
  int wa0 = srow * 64 + sx, wa1 = (srow + 32) * 64 + sx;
  int wb2 = (srow + 64) * 64 + sx, wb3 = (srow + 96) * 64 + sx;
  const size_t rs32 = (size_t)32 * K;
  int lane = tid & 63, w = tid >> 6;
  int wm = w >> 1, wn = w & 1;
  int r = lane & 15, kg = lane >> 4;
  f32x4 acc[2][4] = {};
  uint4 pa0 = *(const uint4*)(ga);
  uint4 pa1 = *(const uint4*)(ga + rs32);
  uint4 pb0 = *(const uint4*)(gb);
  uint4 pb1 = *(const uint4*)(gb + rs32);
  uint4 pb2 = *(const uint4*)(gb + 2 * rs32);
  uint4 pb3 = *(const uint4*)(gb + 3 * rs32);
  for (int k0 = 0; k0 < K; k0 += 64) {
    __syncthreads();
    *(uint4*)&Als[wa0] = pa0; *(uint4*)&Als[wa1] = pa1;
    *(uint4*)&Bls[wa0] = pb0; *(uint4*)&Bls[wa1] = pb1;
    *(uint4*)&Bls[wb2] = pb2; *(uint4*)&Bls[wb3] = pb3;
    __syncthreads();
    int kn = k0 + 64;
    if (kn < K) {
      pa0 = *(const uint4*)(ga + kn);
      pa1 = *(const uint4*)(ga + rs32 + kn);
      pb0 = *(const uint4*)(gb + kn);
      pb1 = *(const uint4*)(gb + rs32 + kn);
      pb2 = *(const uint4*)(gb + 2 * rs32 + kn);
      pb3 = *(const uint4*)(gb + 3 * rs32 + kn);
    }
#pragma unroll
    for (int h = 0; h < 2; ++h) {
      int sa = ((h * 4 + kg) ^ (r & 7)) * 8;
      bf16x8 af[2], bfr[4];
#pragma unroll
      for (int m = 0; m < 2; ++m)
        af[m] = *(const bf16x8*)&Als[(wm * 32 + m * 16 + r) * 64 + sa];
#pragma unroll
      for (int n = 0; n < 4; ++n)
        bfr[n] = *(const bf16x8*)&Bls[(wn * 64 + n * 16 + r) * 64 + sa];
#pragma unroll
      for (int m = 0; m < 2; ++m)
#pragma unroll
        for (int n = 0; n < 4; ++n)
          acc[m][n] = __builtin_amdgcn_mfma_f32_16x16x32_bf16(af[m], bfr[n], acc[m][n], 0, 0, 0);
    }
  }
#pragma unroll
  for (int m = 0; m < 2; ++m)
#pragma unroll
    for (int n = 0; n < 4; ++n) {
      f32x4 a = acc[m][n];
#pragma unroll
      for (int v = 0; v < 4; ++v) {
        int lrow = wm * 32 + m * 16 + kg * 4 + v;
        int col = n0 + wn * 64 + n * 16 + r;
        float x = a[v] + bias[col];
        if (bias2) x += bias2[col];
        Obase[(size_t)lrow * N + col] = x * C_TANH;
      }
    }
}

// ---------------- Wo split-K reduce + bias + residual + LayerNorm -> bf16 ----------------
__global__ __launch_bounds__(256) void wo_ln(const float* __restrict__ P,
                                             const float* __restrict__ bo,
                                             const float* __restrict__ node,
                                             const float* __restrict__ g,
                                             const float* __restrict__ be,
                                             ushort* __restrict__ Y) {
  int row = blockIdx.x, tid = threadIdx.x;
  int c = tid * 4;
  const size_t MN = (size_t)512 * 1024;
  size_t o = (size_t)row * DD + c;
  float4 v0 = *(const float4*)(P + o);
  float4 v1 = *(const float4*)(P + MN + o);
  float4 v2 = *(const float4*)(P + 2 * MN + o);
  float4 v3 = *(const float4*)(P + 3 * MN + o);
  float4 rv = *(const float4*)(node + o);
  float4 bv = *(const float4*)(bo + c);
  float4 v;
  v.x = v0.x + v1.x + v2.x + v3.x + rv.x + bv.x;
  v.y = v0.y + v1.y + v2.y + v3.y + rv.y + bv.y;
  v.z = v0.z + v1.z + v2.z + v3.z + rv.z + bv.z;
  v.w = v0.w + v1.w + v2.w + v3.w + rv.w + bv.w;
  float s = v.x + v.y + v.z + v.w;
  float ss = v.x * v.x + v.y * v.y + v.z * v.z + v.w * v.w;
  for (int o2 = 32; o2; o2 >>= 1) {
    s += __shfl_xor(s, o2, 64);
    ss += __shfl_xor(ss, o2, 64);
  }
  __shared__ float rb_[8];
  int lane = tid & 63, w = tid >> 6;
  if (lane == 0) { rb_[w] = s; rb_[4 + w] = ss; }
  __syncthreads();
  s = rb_[0] + rb_[1] + rb_[2] + rb_[3];
  ss = rb_[4] + rb_[5] + rb_[6] + rb_[7];
  float mu = s * (1.f / 1024.f);
  float var = ss * (1.f / 1024.f) - mu * mu;
  float rstd = rsqrtf(var + 1e-5f);
  ushort4 o4;
  o4.x = f2b((v.x - mu) * rstd * g[c + 0] + be[c + 0]);
  o4.y = f2b((v.y - mu) * rstd * g[c + 1] + be[c + 1]);
  o4.z = f2b((v.z - mu) * rstd * g[c + 2] + be[c + 2]);
  o4.w = f2b((v.w - mu) * rstd * g[c + 3] + be[c + 3]);
  *(ushort4*)(Y + (size_t)row * DD + c) = o4;
}

// ---------------- fused self-attention per (b,h): QK^T + softmax + PV ----------------
__global__ __launch_bounds__(256) void attn_fused(const ushort* __restrict__ Qb,
                                                  const ushort* __restrict__ Kb,
                                                  const ushort* __restrict__ Vb,
                                                  const int* __restrict__ gmask,
                                                  ushort* __restrict__ AO) {
  int bh = blockIdx.x;
  int b = bh >> 2;
  size_t base = ((size_t)b * LNN) * HDD + (size_t)(bh & 3) * DD;
  __shared__ ushort Als[64 * 64];
  __shared__ ushort Bls[64 * 64];
  __shared__ float S[64][68];
  __shared__ ushort Pls[64 * 72];
  __shared__ ushort Vt[64 * 72];
  int tid = threadIdx.x;
  int srow = tid >> 2, su0 = (tid & 3) * 2;
  const ushort* ga = Qb + base + (size_t)srow * HDD + su0 * 8;
  const ushort* gb = Kb + base + (size_t)srow * HDD + su0 * 8;
  int wa0 = srow * 64 + ((su0) ^ (srow & 7)) * 8;
  int wa1 = srow * 64 + ((su0 + 1) ^ (srow & 7)) * 8;
  int lane = tid & 63, w = tid >> 6;
  int wm = w >> 1, wn = w & 1;
  int r = lane & 15, kg = lane >> 4;
  {
    f32x4 acc[2][2] = {};
    uint4 pa0 = *(const uint4*)(ga);
    uint4 pa1 = *(const uint4*)(ga + 8);
    uint4 pb0 = *(const uint4*)(gb);
    uint4 pb1 = *(const uint4*)(gb + 8);
    for (int k0 = 0; k0 < DD; k0 += 64) {
      __syncthreads();
      *(uint4*)&Als[wa0] = pa0; *(uint4*)&Als[wa1] = pa1;
      *(uint4*)&Bls[wa0] = pb0; *(uint4*)&Bls[wa1] = pb1;
      __syncthreads();
      int kn = k0 + 64;
      if (kn < DD) {
        pa0 = *(const uint4*)(ga + kn);
        pa1 = *(const uint4*)(ga + kn + 8);
        pb0 = *(const uint4*)(gb + kn);
        pb1 = *(const uint4*)(gb + kn + 8);
      }
#pragma unroll
      for (int h = 0; h < 2; ++h) {
        int sa = ((h * 4 + kg) ^ (r & 7)) * 8;
        bf16x8 af[2], bfr[2];
#pragma unroll
        for (int m = 0; m < 2; ++m)
          af[m] = *(const bf16x8*)&Als[(wm * 32 + m * 16 + r) * 64 + sa];
#pragma unroll
        for (int n = 0; n < 2; ++n)
          bfr[n] = *(const bf16x8*)&Bls[(wn * 32 + n * 16 + r) * 64 + sa];
#pragma unroll
        for (int m = 0; m < 2; ++m)
#pragma unroll
          for (int n = 0; n < 2; ++n)
            acc[m][n] = __builtin_amdgcn_mfma_f32_16x16x32_bf16(af[m], bfr[n], acc[m][n], 0, 0, 0);
      }
    }
#pragma unroll
    for (int m = 0; m < 2; ++m)
#pragma unroll
      for (int n = 0; n < 2; ++n)
#pragma unroll
        for (int v = 0; v < 4; ++v)
          S[wm * 32 + m * 16 + kg * 4 + v][wn * 32 + n * 16 + r] = acc[m][n][v];
  }
  __syncthreads();
  // softmax rows w*16..w*16+15, lane = k
  bool valid = gmask[b * LNN + lane] != 0;
  for (int i = 0; i < 16; ++i) {
    int q = w * 16 + i;
    float v = valid ? S[q][lane] * 0.03125f : -__builtin_inff();
    float mx = v;
    for (int o = 32; o; o >>= 1) mx = fmaxf(mx, __shfl_xor(mx, o, 64));
    float e = valid ? __expf(v - mx) : 0.f;
    float s = e;
    for (int o = 32; o; o >>= 1) s += __shfl_xor(s, o, 64);
    Pls[q * 72 + lane] = f2b(__fdividef(e, s));
  }
  // PV over 16 d-tiles
  for (int dt = 0; dt < 16; ++dt) {
    int d0 = dt * 64;
    {
      int kq = tid >> 2, dq = (tid & 3) * 16;
      const ushort* src = Vb + base + (size_t)kq * HDD + d0 + dq;
      uint4 v0 = *(const uint4*)src;
      uint4 v1 = *(const uint4*)(src + 8);
      ushort tmp[16];
      *(uint4*)&tmp[0] = v0;
      *(uint4*)&tmp[8] = v1;
#pragma unroll
      for (int j = 0; j < 16; ++j) Vt[(dq + j) * 72 + kq] = tmp[j];
    }
    __syncthreads();
    f32x4 acc[2][2] = {};
#pragma unroll
    for (int h = 0; h < 2; ++h) {
      int ko = h * 32 + kg * 8;
      bf16x8 af[2], bfr[2];
#pragma unroll
      for (int m = 0; m < 2; ++m)
        af[m] = *(const bf16x8*)&Pls[(wm * 32 + m * 16 + r) * 72 + ko];
#pragma unroll
      for (int n = 0; n < 2; ++n)
        bfr[n] = *(const bf16x8*)&Vt[(wn * 32 + n * 16 + r) * 72 + ko];
#pragma unroll
      for (int m = 0; m < 2; ++m)
#pragma unroll
        for (int n = 0; n < 2; ++n)
          acc[m][n] = __builtin_amdgcn_mfma_f32_16x16x32_bf16(af[m], bfr[n], acc[m][n], 0, 0, 0);
    }
#pragma unroll
    for (int m = 0; m < 2; ++m)
#pragma unroll
      for (int n = 0; n < 2; ++n) {
        f32x4 a = acc[m][n];
#pragma unroll
        for (int v = 0; v < 4; ++v) {
          int q = wm * 32 + m * 16 + kg * 4 + v;
          int col = wn * 32 + n * 16 + r;
          AO[base + (size_t)q * HDD + d0 + col] = f2b(a[v]);
        }
      }
    __syncthreads();
  }
}

// ---------------- additive attention phase 1: partial e, 4-q reuse per block ----------------
__global__ __launch_bounds__(256) void addatt_e(const float* __restrict__ QBu,
                                                const float* __restrict__ KAB,
                                                const float* __restrict__ av_,
                                                float* __restrict__ E4) {
  int dq = blockIdx.x, qt = blockIdx.y, b = blockIdx.z;
  int tid = threadIdx.x;
  __shared__ float qs[4][256];
  __shared__ float avs[256];
  __shared__ float red[4];
  int bq0 = b * LNN + qt * 4;
#pragma unroll
  for (int qq = 0; qq < 4; ++qq)
    qs[qq][tid] = QBu[(size_t)(bq0 + qq) * DD + dq * 256 + tid];
  float av = av_[dq * 256 + tid];
  avs[tid] = av;
  float s = av;
  for (int o = 32; o; o >>= 1) s += __shfl_xor(s, o, 64);
  int lane = tid & 63, w = tid >> 6;
  if (lane == 0) red[w] = s;
  __syncthreads();
  float sumav = red[0] + red[1] + red[2] + red[3];
  const float* kr = KAB + (size_t)(b * LTN + tid) * DD + dq * 256;
  float ac0 = 0.f, ac1 = 0.f, ac2 = 0.f, ac3 = 0.f;
#pragma unroll 2
  for (int d = 0; d < 256; d += 4) {
    float4 kv = *(const float4*)(kr + d);
    float4 av4 = *(const float4*)&avs[d];
    float4 q0 = *(const float4*)&qs[0][d];
    float4 q1 = *(const float4*)&qs[1][d];
    float4 q2 = *(const float4*)&qs[2][d];
    float4 q3 = *(const float4*)&qs[3][d];
    ac0 = fmaf(av4.x, __builtin_amdgcn_rcpf(__builtin_amdgcn_exp2f(q0.x + kv.x) + 1.f), ac0);
    ac1 = fmaf(av4.x, __builtin_amdgcn_rcpf(__builtin_amdgcn_exp2f(q1.x + kv.x) + 1.f), ac1);
    ac2 = fmaf(av4.x, __builtin_amdgcn_rcpf(__builtin_amdgcn_exp2f(q2.x + kv.x) + 1.f), ac2);
    ac3 = fmaf(av4.x, __builtin_amdgcn_rcpf(__builtin_amdgcn_exp2f(q3.x + kv.x) + 1.f), ac3);
    ac0 = fmaf(av4.y, __builtin_amdgcn_rcpf(__builtin_amdgcn_exp2f(q0.y + kv.y) + 1.f), ac0);
    ac1 = fmaf(av4.y, __builtin_amdgcn_rcpf(__builtin_amdgcn_exp2f(q1.y + kv.y) + 1.f), ac1);
    ac2 = fmaf(av4.y, __builtin_amdgcn_rcpf(__builtin_amdgcn_exp2f(q2.y + kv.y) + 1.f), ac2);
    ac3 = fmaf(av4.y, __builtin_amdgcn_rcpf(__builtin_amdgcn_exp2f(q3.y + kv.y) + 1.f), ac3);
    ac0 = fmaf(av4.z, __builtin_amdgcn_rcpf(__builtin_amdgcn_exp2f(q0.z + kv.z) + 1.f), ac0);
    ac1 = fmaf(av4.z, __builtin_amdgcn_rcpf(__builtin_amdgcn_exp2f(q1.z + kv.z) + 1.f), ac1);
    ac2 = fmaf(av4.z, __builtin_amdgcn_rcpf(__builtin_amdgcn_exp2f(q2.z + kv.z) + 1.f), ac2);
    ac3 = fmaf(av4.z, __builtin_amdgcn_rcpf(__builtin_amdgcn_exp2f(q3.z + kv.z) + 1.f), ac3);
    ac0 = fmaf(av4.w, __builtin_amdgcn_rcpf(__builtin_amdgcn_exp2f(q0.w + kv.w) + 1.f), ac0);
    ac1 = fmaf(av4.w, __builtin_amdgcn_rcpf(__builtin_amdgcn_exp2f(q1.w + kv.w) + 1.f), ac1);
    ac2 = fmaf(av4.w, __builtin_amdgcn_rcpf(__builtin_amdgcn_exp2f(q2.w + kv.w) + 1.f), ac2);
    ac3 = fmaf(av4.w, __builtin_amdgcn_rcpf(__builtin_amdgcn_exp2f(q3.w + kv.w) + 1.f), ac3);
  }
  size_t ebase = ((size_t)dq * 512 + bq0) * LTN + tid;
  E4[ebase] = sumav - 2.f * ac0;
  E4[ebase + LTN] = sumav - 2.f * ac1;
  E4[ebase + 2 * LTN] = sumav - 2.f * ac2;
  E4[ebase + 3 * LTN] = sumav - 2.f * ac3;
}

// ---------------- additive attention phase 2: sum partials + masked softmax -> w ----------------
__global__ __launch_bounds__(256) void addatt_sm(const float* __restrict__ E4,
                                                 const int* __restrict__ lmask,
                                                 float* __restrict__ Wv) {
  int bq = blockIdx.x;
  int b = bq >> 6;
  int tid = threadIdx.x;
  __shared__ float rb_[8];
  float e = E4[(size_t)bq * LTN + tid] + E4[((size_t)512 + bq) * LTN + tid] +
            E4[((size_t)1024 + bq) * LTN + tid] + E4[((size_t)1536 + bq) * LTN + tid];
  bool valid = lmask[b * LTN + tid] != 0;
  float v = valid ? e : -__builtin_inff();
  int lane = tid & 63, w = tid >> 6;
  float m = v;
  for (int o = 32; o; o >>= 1) m = fmaxf(m, __shfl_xor(m, o, 64));
  if (lane == 0) rb_[w] = m;
  __syncthreads();
  m = fmaxf(fmaxf(rb_[0], rb_[1]), fmaxf(rb_[2], rb_[3]));
  float ex = valid ? __expf(v - m) : 0.f;
  float sm = ex;
  for (int o = 32; o; o >>= 1) sm += __shfl_xor(sm, o, 64);
  if (lane == 0) rb_[4 + w] = sm;
  __syncthreads();
  sm = rb_[4] + rb_[5] + rb_[6] + rb_[7];
  Wv[(size_t)bq * LTN + tid] = __fdividef(ex, sm);
}

// ---------------- additive attention phase 3: pooled context ----------------
__global__ __launch_bounds__(256) void addatt_pool(const float* __restrict__ Wv,
                                                   const float* __restrict__ text,
                                                   const int* __restrict__ gmask,
                                                   float* __restrict__ H4) {
  int dt = blockIdx.x, b = blockIdx.y;
  int tid = threadIdx.x;
  __shared__ float cf[LTN];
  float c = 0.f, cnt = 0.f;
#pragma unroll 8
  for (int q = 0; q < LNN; ++q) {
    float m = (gmask[b * LNN + q] != 0) ? 1.f : 0.f;
    cnt += m;
    c = fmaf(m, Wv[(size_t)(b * LNN + q) * LTN + tid], c);
  }
  cf[tid] = c;
  cnt = fmaxf(cnt, 9.765625e-04f);
  __syncthreads();
  int d = dt * 256 + tid;
  const float* tb = text + (size_t)b * LTN * DD + d;
  float acc = 0.f;
#pragma unroll 8
  for (int k = 0; k < LTN; ++k) acc = fmaf(cf[k], tb[(size_t)k * DD], acc);
  H4[b * DD + d] = acc / cnt;
}

// ---------------- split-K GEMV ----------------
__global__ __launch_bounds__(256) void dp_split(const float* __restrict__ X,
                                                const float* __restrict__ W,
                                                float* __restrict__ P,
                                                int K, int N) {
  int jt = blockIdx.x, kt = blockIdx.y;
  int t = threadIdx.x;
  __shared__ float xs[8][32];
  if (t < 64) {
    int b = t >> 3, kk = (t & 7) * 4;
    *(float4*)&xs[b][kk] = *(const float4*)(X + (size_t)b * K + kt * 32 + kk);
  }
  __syncthreads();
  int j = jt * 64 + (t & 63);
  int bg = (t >> 6) * 2;
  const float* wp = W + (size_t)(kt * 32) * N + j;
  float a0 = 0.f, a1 = 0.f;
#pragma unroll
  for (int k = 0; k < 32; ++k) {
    float w = wp[(size_t)k * N];
    a0 = fmaf(xs[bg + 0][k], w, a0);
    a1 = fmaf(xs[bg + 1][k], w, a1);
  }
  P[((size_t)kt * 8 + bg + 0) * N + j] = a0;
  P[((size_t)kt * 8 + bg + 1) * N + j] = a1;
}

template <int GELU>
__global__ __launch_bounds__(256) void dp_reduce(const float* __restrict__ P,
                                                 const float* __restrict__ bias,
                                                 float* __restrict__ O, int N) {
  int b = blockIdx.y;
  int j = blockIdx.x * 256 + threadIdx.x;
  float s = bias[j];
#pragma unroll 8
  for (int kt = 0; kt < 32; ++kt) s += P[((size_t)kt * 8 + b) * N + j];
  if constexpr (GELU) s = 0.5f * s * (1.f + erff(s * 0.70710678118654752440f));
  O[(size_t)b * N + j] = s;
}

extern "C" void kernel_launch(void* const* d_in, const int* in_sizes, int n_in,
                              void* d_out, int out_size, void* d_ws, size_t ws_size,
                              hipStream_t stream) {
  const float* text = (const float*)d_in[0];
  const float* node = (const float*)d_in[1];
  const float* Wq = (const float*)d_in[2];
  const float* bq = (const float*)d_in[3];
  const float* Wk = (const float*)d_in[4];
  const float* bk = (const float*)d_in[5];
  const float* Wv = (const float*)d_in[6];
  const float* bv = (const float*)d_in[7];
  const float* Wo = (const float*)d_in[8];
  const float* bo = (const float*)d_in[9];
  const float* lng = (const float*)d_in[10];
  const float* lnb = (const float*)d_in[11];
  const float* aqW = (const float*)d_in[12];
  const float* aqb = (const float*)d_in[13];
  const float* akW = (const float*)d_in[14];
  const float* akb = (const float*)d_in[15];
  const float* attv = (const float*)d_in[16];
  const float* attb = (const float*)d_in[17];
  const float* dp1W = (const float*)d_in[18];
  const float* dp1b = (const float*)d_in[19];
  const float* dp2W = (const float*)d_in[20];
  const float* dp2b = (const float*)d_in[21];
  const int* gmask = (const int*)d_in[22];
  const int* lmask = (const int*)d_in[23];
  (void)in_sizes; (void)n_in; (void)out_size;

  char* base = (char*)d_ws;
#define MB(x) (((size_t)(x)) << 20)
  ushort* Twt = (ushort*)(base);               // 8MB (Wo; or AQ@0-2MB + AK@2-4MB; fallback QKV)
  ushort* node_bf = (ushort*)(base + MB(8));   // 1MB
  ushort* text_bf = (ushort*)(base + MB(9));   // 4MB
  ushort* Qb = (ushort*)(base + MB(13));       // 4MB
  ushort* Kb = (ushort*)(base + MB(17));       // 4MB
  ushort* Vb = (ushort*)(base + MB(21));       // 4MB
  ushort* AO = (ushort*)(base + MB(25));       // 4MB
  float* E4 = (float*)(base + MB(13));         // 2MB (Qb dead after attn)
  float* Wvb = (float*)(base + MB(15));        // 512KB
  ushort* H2 = (ushort*)(base + MB(15) + (512 << 10));  // 1MB
  float* P_Wo = (float*)(base + MB(17));       // 8MB (Kb/Vb dead after attn)
  float* P1 = (float*)(base + MB(18));         // 1MB (dp phase; P_Wo dead)
  float* P2 = (float*)(base + MB(19));         // 2MB
  float* QBu = (float*)(base + MB(21));        // 2MB (written after wo_ln)
  float* KAB = (float*)(base + MB(25));        // 8MB (AO dead after Wo gemm)
  float* H4 = (float*)(base + MB(33));         // 32KB
  float* G = (float*)(base + MB(33) + 32768);  // 32KB
  ushort* TwtQKV = (ushort*)(base + MB(34));   // 24MB, bigws only
  float* Z = (float*)d_out;
  const bool bigws = ws_size >= MB(59);
#undef MB

  const int M1 = NB * LNN;  // 512
  dim3 blk(256);

  // activations -> bf16 (one launch)
  cvt_all<<<dim3(1280), blk, 0, stream>>>(node, node_bf, text, text_bf);

  // QKV projections
  if (bigws) {
    tcvt3<<<dim3(HDD / 64, DD / 64, 3), blk, 0, stream>>>(Wq, Wk, Wv, TwtQKV, DD, HDD);
    gemm_qkv3<<<dim3(HDD / 128, M1 / 64, 3), blk, 0, stream>>>(node_bf, TwtQKV, bq, bk, bv, Qb, Kb, Vb, M1, HDD, DD);
  } else {
    tcvt3<<<dim3(HDD / 64, DD / 64, 1), blk, 0, stream>>>(Wq, Wq, Wq, Twt, DD, HDD);
    gemm_qkv3<<<dim3(HDD / 128, M1 / 64, 1), blk, 0, stream>>>(node_bf, Twt, bq, bq, bq, Qb, Qb, Qb, M1, HDD, DD);
    tcvt3<<<dim3(HDD / 64, DD / 64, 1), blk, 0, stream>>>(Wk, Wk, Wk, Twt, DD, HDD);
    gemm_qkv3<<<dim3(HDD / 128, M1 / 64, 1), blk, 0, stream>>>(node_bf, Twt, bk, bk, bk, Kb, Kb, Kb, M1, HDD, DD);
    tcvt3<<<dim3(HDD / 64, DD / 64, 1), blk, 0, stream>>>(Wv, Wv, Wv, Twt, DD, HDD);
    gemm_qkv3<<<dim3(HDD / 128, M1 / 64, 1), blk, 0, stream>>>(node_bf, Twt, bv, bv, bv, Vb, Vb, Vb, M1, HDD, DD);
  }

  // fused self-attention (QK^T + softmax + PV in one launch)
  attn_fused<<<dim3(NB * NH), blk, 0, stream>>>(Qb, Kb, Vb, gmask, AO);

  // output proj: split-K 4-way partials, then fused reduce+residual+LayerNorm
  tcvt3<<<dim3(DD / 64, HDD / 64, 1), blk, 0, stream>>>(Wo, Wo, Wo, Twt, HDD, DD);
  gemm_wo_split<<<dim3(DD / 128, M1 / 64, 4), blk, 0, stream>>>(AO, Twt, P_Wo, M1, DD, HDD);
  wo_ln<<<dim3(M1), blk, 0, stream>>>(P_Wo, bo, node, lng, lnb, H2);

  // aq + ak: one tcvt (z=2) + one M-concat gemm; outputs pre-scaled by C_TANH
  tcvt3<<<dim3(DD / 64, DD / 64, 2), blk, 0, stream>>>(aqW, akW, akW, Twt, DD, DD);
  gemm_aqak<<<dim3(DD / 128, 40), blk, 0, stream>>>(H2, text_bf, Twt, aqb, akb, attb, QBu, KAB, DD, DD);

  // additive attention: partial-e (4-q reuse) -> softmax -> pooled context
  addatt_e<<<dim3(4, 16, NB), blk, 0, stream>>>(QBu, KAB, attv, E4);
  addatt_sm<<<dim3(M1), blk, 0, stream>>>(E4, lmask, Wvb);
  addatt_pool<<<dim3(4, NB), blk, 0, stream>>>(Wvb, text, gmask, H4);

  // MLP via split-K GEMV (weight-read-bound)
  dp_split<<<dim3(DHN / 64, 32), blk, 0, stream>>>(H4, dp1W, P1, DD, DHN);
  dp_reduce<1><<<dim3(DHN / 256, NB), blk, 0, stream>>>(P1, dp1b, G, DHN);
  dp_split<<<dim3(DINN / 64, 32), blk, 0, stream>>>(G, dp2W, P2, DHN, DINN);
  dp_reduce<0><<<dim3(DINN / 256, NB), blk, 0, stream>>>(P2, dp2b, Z, DINN);
}

// Round 8
// 173.671 us; speedup vs baseline: 6.9083x; 1.0612x over previous
//
#include <hip/hip_runtime.h>
#include <hip/hip_bf16.h>
#include <math.h>

#define NB 8        // batch
#define LNN 64      // nodes
#define LTN 256     // text len
#define DD 1024     // model dim
#define NH 4        // heads (each full width D)
#define HDD 4096    // NH*DD
#define DINN 2048
#define DHN 1024    // DIN/2

// 2*log2(e): tanh(x) = 1 - 2/(exp2(x*C)+1)
#define C_TANH 2.8853900817779268f

typedef __bf16 bf16x8 __attribute__((ext_vector_type(8)));
typedef float f32x4 __attribute__((ext_vector_type(4)));

__device__ __forceinline__ float b2f(ushort u) {
  union { float f; unsigned int i; } x; x.i = ((unsigned int)u) << 16; return x.f;
}
__device__ __forceinline__ ushort f2b(float f) {
  unsigned int u = __builtin_bit_cast(unsigned int, f);
  u = (u + 0x7FFFu + ((u >> 16) & 1u)) >> 16;
  return (ushort)u;
}

// ---------------- fused fp32->bf16 for node + text in one launch ----------------
__global__ __launch_bounds__(256) void cvt_all(const float* __restrict__ node,
                                               ushort* __restrict__ node_bf,
                                               const float* __restrict__ text,
                                               ushort* __restrict__ text_bf) {
  int bid = blockIdx.x;
  const float* in;
  ushort* out;
  int i;
  if (bid < 256) { in = node; out = node_bf; i = (bid * 256 + threadIdx.x) * 8; }
  else { in = text; out = text_bf; i = ((bid - 256) * 256 + threadIdx.x) * 8; }
  float4 a = *(const float4*)(in + i);
  float4 b = *(const float4*)(in + i + 4);
  ushort4 o0 = {f2b(a.x), f2b(a.y), f2b(a.z), f2b(a.w)};
  ushort4 o1 = {f2b(b.x), f2b(b.y), f2b(b.z), f2b(b.w)};
  *(ushort4*)(out + i) = o0;
  *(ushort4*)(out + i + 4) = o1;
}

// ---------------- transpose+convert up to 3 weights: W[K][N] fp32 -> Wt[z][N][K] bf16 ----------------
__global__ __launch_bounds__(256) void tcvt3(const float* __restrict__ W0,
                                             const float* __restrict__ W1,
                                             const float* __restrict__ W2,
                                             ushort* __restrict__ Wt, int K, int N) {
  int z = blockIdx.z;
  const float* W = (z == 0) ? W0 : ((z == 1) ? W1 : W2);
  ushort* dst0 = Wt + (size_t)z * K * N;
  __shared__ float tf[64][65];
  int k0 = blockIdx.y << 6, n0 = blockIdx.x << 6;
  int t = threadIdx.x;
  int r = t >> 2, c4 = (t & 3) * 16;
  const float* src = W + (size_t)(k0 + r) * N + n0 + c4;
  float4 v0 = *(const float4*)(src);
  float4 v1 = *(const float4*)(src + 4);
  float4 v2 = *(const float4*)(src + 8);
  float4 v3 = *(const float4*)(src + 12);
  *(float4*)&tf[r][c4] = v0;
  *(float4*)&tf[r][c4 + 4] = v1;
  *(float4*)&tf[r][c4 + 8] = v2;
  *(float4*)&tf[r][c4 + 12] = v3;
  __syncthreads();
  int nl = t >> 2, kc = (t & 3) * 16;
  ushort tmp[16];
#pragma unroll
  for (int j = 0; j < 16; ++j) tmp[j] = f2b(tf[kc + j][nl]);
  ushort* dst = dst0 + (size_t)(n0 + nl) * K + k0 + kc;
  *(uint4*)(dst) = *(uint4*)&tmp[0];
  *(uint4*)(dst + 8) = *(uint4*)&tmp[8];
}

// ---------------- QKV gemm (up to 3 via grid.z): bf16 out, +bias ----------------
__global__ __launch_bounds__(256) void gemm_qkv3(const ushort* __restrict__ A,
                                                 const ushort* __restrict__ BtB,
                                                 const float* __restrict__ b0,
                                                 const float* __restrict__ b1,
                                                 const float* __restrict__ b2,
                                                 ushort* __restrict__ o0,
                                                 ushort* __restrict__ o1,
                                                 ushort* __restrict__ o2,
                                                 int M, int N, int K) {
  int z = blockIdx.z;
  const ushort* Bt = BtB + (size_t)z * N * K;
  const float* bias = (z == 0) ? b0 : ((z == 1) ? b1 : b2);
  ushort* Cout = (z == 0) ? o0 : ((z == 1) ? o1 : o2);
  __shared__ ushort Als[64 * 64];
  __shared__ ushort Bls[128 * 64];
  int tid = threadIdx.x;
  int m0 = blockIdx.y << 6, n0 = blockIdx.x << 7;
  int srow = tid >> 3, su = tid & 7;
  int sx = (su ^ (srow & 7)) * 8;
  const ushort* ga = A + (size_t)(m0 + srow) * K + su * 8;
  const ushort* gb = Bt + (size_t)(n0 + srow) * K + su * 8;
  int wa0 = srow * 64 + sx, wa1 = (srow + 32) * 64 + sx;
  int wb2 = (srow + 64) * 64 + sx, wb3 = (srow + 96) * 64 + sx;
  const size_t rs32 = (size_t)32 * K;
  int lane = tid & 63, w = tid >> 6;
  int wm = w >> 1, wn = w & 1;
  int r = lane & 15, kg = lane >> 4;
  f32x4 acc[2][4] = {};
  uint4 pa0 = *(const uint4*)(ga);
  uint4 pa1 = *(const uint4*)(ga + rs32);
  uint4 pb0 = *(const uint4*)(gb);
  uint4 pb1 = *(const uint4*)(gb + rs32);
  uint4 pb2 = *(const uint4*)(gb + 2 * rs32);
  uint4 pb3 = *(const uint4*)(gb + 3 * rs32);
  for (int k0 = 0; k0 < K; k0 += 64) {
    __syncthreads();
    *(uint4*)&Als[wa0] = pa0; *(uint4*)&Als[wa1] = pa1;
    *(uint4*)&Bls[wa0] = pb0; *(uint4*)&Bls[wa1] = pb1;
    *(uint4*)&Bls[wb2] = pb2; *(uint4*)&Bls[wb3] = pb3;
    __syncthreads();
    int kn = k0 + 64;
    if (kn < K) {
      pa0 = *(const uint4*)(ga + kn);
      pa1 = *(const uint4*)(ga + rs32 + kn);
      pb0 = *(const uint4*)(gb + kn);
      pb1 = *(const uint4*)(gb + rs32 + kn);
      pb2 = *(const uint4*)(gb + 2 * rs32 + kn);
      pb3 = *(const uint4*)(gb + 3 * rs32 + kn);
    }
#pragma unroll
    for (int h = 0; h < 2; ++h) {
      int sa = ((h * 4 + kg) ^ (r & 7)) * 8;
      bf16x8 af[2], bfr[4];
#pragma unroll
      for (int m = 0; m < 2; ++m)
        af[m] = *(const bf16x8*)&Als[(wm * 32 + m * 16 + r) * 64 + sa];
#pragma unroll
      for (int n = 0; n < 4; ++n)
        bfr[n] = *(const bf16x8*)&Bls[(wn * 64 + n * 16 + r) * 64 + sa];
#pragma unroll
      for (int m = 0; m < 2; ++m)
#pragma unroll
        for (int n = 0; n < 4; ++n)
          acc[m][n] = __builtin_amdgcn_mfma_f32_16x16x32_bf16(af[m], bfr[n], acc[m][n], 0, 0, 0);
    }
  }
#pragma unroll
  for (int m = 0; m < 2; ++m)
#pragma unroll
    for (int n = 0; n < 4; ++n) {
      f32x4 a = acc[m][n];
#pragma unroll
      for (int v = 0; v < 4; ++v) {
        int row = m0 + wm * 32 + m * 16 + kg * 4 + v;
        int col = n0 + wn * 64 + n * 16 + r;
        Cout[(size_t)row * N + col] = f2b(a[v] + bias[col]);
      }
    }
}

// ---------------- Wo gemm with split-K (grid.z): fp32 partials, no bias ----------------
__global__ __launch_bounds__(256) void gemm_wo_split(const ushort* __restrict__ A,
                                                     const ushort* __restrict__ Bt,
                                                     float* __restrict__ P,
                                                     int M, int N, int K) {
  __shared__ ushort Als[64 * 64];
  __shared__ ushort Bls[128 * 64];
  int tid = threadIdx.x;
  int m0 = blockIdx.y << 6, n0 = blockIdx.x << 7;
  int Ks = K >> 2, kbase = blockIdx.z * Ks;
  int srow = tid >> 3, su = tid & 7;
  int sx = (su ^ (srow & 7)) * 8;
  const ushort* ga = A + (size_t)(m0 + srow) * K + kbase + su * 8;
  const ushort* gb = Bt + (size_t)(n0 + srow) * K + kbase + su * 8;
  int wa0 = srow * 64 + sx, wa1 = (srow + 32) * 64 + sx;
  int wb2 = (srow + 64) * 64 + sx, wb3 = (srow + 96) * 64 + sx;
  const size_t rs32 = (size_t)32 * K;
  int lane = tid & 63, w = tid >> 6;
  int wm = w >> 1, wn = w & 1;
  int r = lane & 15, kg = lane >> 4;
  f32x4 acc[2][4] = {};
  uint4 pa0 = *(const uint4*)(ga);
  uint4 pa1 = *(const uint4*)(ga + rs32);
  uint4 pb0 = *(const uint4*)(gb);
  uint4 pb1 = *(const uint4*)(gb + rs32);
  uint4 pb2 = *(const uint4*)(gb + 2 * rs32);
  uint4 pb3 = *(const uint4*)(gb + 3 * rs32);
  for (int k0 = 0; k0 < Ks; k0 += 64) {
    __syncthreads();
    *(uint4*)&Als[wa0] = pa0; *(uint4*)&Als[wa1] = pa1;
    *(uint4*)&Bls[wa0] = pb0; *(uint4*)&Bls[wa1] = pb1;
    *(uint4*)&Bls[wb2] = pb2; *(uint4*)&Bls[wb3] = pb3;
    __syncthreads();
    int kn = k0 + 64;
    if (kn < Ks) {
      pa0 = *(const uint4*)(ga + kn);
      pa1 = *(const uint4*)(ga + rs32 + kn);
      pb0 = *(const uint4*)(gb + kn);
      pb1 = *(const uint4*)(gb + rs32 + kn);
      pb2 = *(const uint4*)(gb + 2 * rs32 + kn);
      pb3 = *(const uint4*)(gb + 3 * rs32 + kn);
    }
#pragma unroll
    for (int h = 0; h < 2; ++h) {
      int sa = ((h * 4 + kg) ^ (r & 7)) * 8;
      bf16x8 af[2], bfr[4];
#pragma unroll
      for (int m = 0; m < 2; ++m)
        af[m] = *(const bf16x8*)&Als[(wm * 32 + m * 16 + r) * 64 + sa];
#pragma unroll
      for (int n = 0; n < 4; ++n)
        bfr[n] = *(const bf16x8*)&Bls[(wn * 64 + n * 16 + r) * 64 + sa];
#pragma unroll
      for (int m = 0; m < 2; ++m)
#pragma unroll
        for (int n = 0; n < 4; ++n)
          acc[m][n] = __builtin_amdgcn_mfma_f32_16x16x32_bf16(af[m], bfr[n], acc[m][n], 0, 0, 0);
    }
  }
#pragma unroll
  for (int m = 0; m < 2; ++m)
#pragma unroll
    for (int n = 0; n < 4; ++n) {
      f32x4 a = acc[m][n];
#pragma unroll
      for (int v = 0; v < 4; ++v) {
        int row = m0 + wm * 32 + m * 16 + kg * 4 + v;
        int col = n0 + wn * 64 + n * 16 + r;
        P[((size_t)blockIdx.z * M + row) * N + col] = a[v];
      }
    }
}

// ---------------- aq+ak gemm (M-concat row select): fp32 out, *C_TANH ----------------
__global__ __launch_bounds__(256) void gemm_aqak(const ushort* __restrict__ H2,
                                                 const ushort* __restrict__ Tbf,
                                                 const ushort* __restrict__ TwtAQ,
                                                 const float* __restrict__ aqb,
                                                 const float* __restrict__ akb,
                                                 const float* __restrict__ attb,
                                                 float* __restrict__ QBu,
                                                 float* __restrict__ KAB,
                                                 int N, int K) {
  __shared__ ushort Als[64 * 64];
  __shared__ ushort Bls[128 * 64];
  int tid = threadIdx.x;
  int gm0 = blockIdx.y << 6, n0 = blockIdx.x << 7;
  const ushort* Abase;
  const ushort* Bt;
  const float* bias;
  const float* bias2;
  float* Obase;
  if (gm0 < 512) {
    Abase = H2 + (size_t)gm0 * K;
    Bt = TwtAQ;
    bias = aqb; bias2 = nullptr;
    Obase = QBu + (size_t)gm0 * N;
  } else {
    Abase = Tbf + (size_t)(gm0 - 512) * K;
    Bt = TwtAQ + (size_t)N * K;
    bias = akb; bias2 = attb;
    Obase = KAB + (size_t)(gm0 - 512) * N;
  }
  int srow = tid >> 3, su = tid & 7;
  int sx = (su ^ (srow & 7)) * 8;
  const ushort* ga = Abase + (size_t)srow * K + su * 8;
  const ushort* gb = Bt + (size_t)(n0 + srow) * K + su * 8;
  int wa0 = srow * 64 + sx, wa1 = (srow + 32) * 64 + sx;
  int wb2 = (srow + 64) * 64 + sx, wb3 = (srow + 96) * 64 + sx;
  const size_t rs32 = (size_t)32 * K;
  int lane = tid & 63, w = tid >> 6;
  int wm = w >> 1, wn = w & 1;
  int r = lane & 15, kg = lane >> 4;
  f32x4 acc[2][4] = {};
  uint4 pa0 = *(const uint4*)(ga);
  uint4 pa1 = *(const uint4*)(ga + rs32);
  uint4 pb0 = *(const uint4*)(gb);
  uint4 pb1 = *(const uint4*)(gb + rs32);
  uint4 pb2 = *(const uint4*)(gb + 2 * rs32);
  uint4 pb3 = *(const uint4*)(gb + 3 * rs32);
  for (int k0 = 0; k0 < K; k0 += 64) {
    __syncthreads();
    *(uint4*)&Als[wa0] = pa0; *(uint4*)&Als[wa1] = pa1;
    *(uint4*)&Bls[wa0] = pb0; *(uint4*)&Bls[wa1] = pb1;
    *(uint4*)&Bls[wb2] = pb2; *(uint4*)&Bls[wb3] = pb3;
    __syncthreads();
    int kn = k0 + 64;
    if (kn < K) {
      pa0 = *(const uint4*)(ga + kn);
      pa1 = *(const uint4*)(ga + rs32 + kn);
      pb0 = *(const uint4*)(gb + kn);
      pb1 = *(const uint4*)(gb + rs32 + kn);
      pb2 = *(const uint4*)(gb + 2 * rs32 + kn);
      pb3 = *(const uint4*)(gb + 3 * rs32 + kn);
    }
#pragma unroll
    for (int h = 0; h < 2; ++h) {
      int sa = ((h * 4 + kg) ^ (r & 7)) * 8;
      bf16x8 af[2], bfr[4];
#pragma unroll
      for (int m = 0; m < 2; ++m)
        af[m] = *(const bf16x8*)&Als[(wm * 32 + m * 16 + r) * 64 + sa];
#pragma unroll
      for (int n = 0; n < 4; ++n)
        bfr[n] = *(const bf16x8*)&Bls[(wn * 64 + n * 16 + r) * 64 + sa];
#pragma unroll
      for (int m = 0; m < 2; ++m)
#pragma unroll
        for (int n = 0; n < 4; ++n)
          acc[m][n] = __builtin_amdgcn_mfma_f32_16x16x32_bf16(af[m], bfr[n], acc[m][n], 0, 0, 0);
    }
  }
#pragma unroll
  for (int m = 0; m < 2; ++m)
#pragma unroll
    for (int n = 0; n < 4; ++n) {
      f32x4 a = acc[m][n];
#pragma unroll
      for (int v = 0; v < 4; ++v) {
        int lrow = wm * 32 + m * 16 + kg * 4 + v;
        int col = n0 + wn * 64 + n * 16 + r;
        float x = a[v] + bias[col];
        if (bias2) x += bias2[col];
        Obase[(size_t)lrow * N + col] = x * C_TANH;
      }
    }
}

// ---------------- Wo split-K reduce + bias + residual + LayerNorm -> bf16 ----------------
__global__ __launch_bounds__(256) void wo_ln(const float* __restrict__ P,
                                             const float* __restrict__ bo,
                                             const float* __restrict__ node,
                                             const float* __restrict__ g,
                                             const float* __restrict__ be,
                                             ushort* __restrict__ Y) {
  int row = blockIdx.x, tid = threadIdx.x;
  int c = tid * 4;
  const size_t MN = (size_t)512 * 1024;
  size_t o = (size_t)row * DD + c;
  float4 v0 = *(const float4*)(P + o);
  float4 v1 = *(const float4*)(P + MN + o);
  float4 v2 = *(const float4*)(P + 2 * MN + o);
  float4 v3 = *(const float4*)(P + 3 * MN + o);
  float4 rv = *(const float4*)(node + o);
  float4 bv = *(const float4*)(bo + c);
  float4 v;
  v.x = v0.x + v1.x + v2.x + v3.x + rv.x + bv.x;
  v.y = v0.y + v1.y + v2.y + v3.y + rv.y + bv.y;
  v.z = v0.z + v1.z + v2.z + v3.z + rv.z + bv.z;
  v.w = v0.w + v1.w + v2.w + v3.w + rv.w + bv.w;
  float s = v.x + v.y + v.z + v.w;
  float ss = v.x * v.x + v.y * v.y + v.z * v.z + v.w * v.w;
  for (int o2 = 32; o2; o2 >>= 1) {
    s += __shfl_xor(s, o2, 64);
    ss += __shfl_xor(ss, o2, 64);
  }
  __shared__ float rb_[8];
  int lane = tid & 63, w = tid >> 6;
  if (lane == 0) { rb_[w] = s; rb_[4 + w] = ss; }
  __syncthreads();
  s = rb_[0] + rb_[1] + rb_[2] + rb_[3];
  ss = rb_[4] + rb_[5] + rb_[6] + rb_[7];
  float mu = s * (1.f / 1024.f);
  float var = ss * (1.f / 1024.f) - mu * mu;
  float rstd = rsqrtf(var + 1e-5f);
  ushort4 o4;
  o4.x = f2b((v.x - mu) * rstd * g[c + 0] + be[c + 0]);
  o4.y = f2b((v.y - mu) * rstd * g[c + 1] + be[c + 1]);
  o4.z = f2b((v.z - mu) * rstd * g[c + 2] + be[c + 2]);
  o4.w = f2b((v.w - mu) * rstd * g[c + 3] + be[c + 3]);
  *(ushort4*)(Y + (size_t)row * DD + c) = o4;
}

// ---------------- attn 1: QK^T split-K over D: Sp[ks][bh][64][64] fp32 ----------------
__global__ __launch_bounds__(256) void attn_qk(const ushort* __restrict__ Qb,
                                               const ushort* __restrict__ Kb,
                                               float* __restrict__ Sp) {
  int bh = blockIdx.x, ks = blockIdx.y;
  int b = bh >> 2;
  size_t base = ((size_t)b * LNN) * HDD + (size_t)(bh & 3) * DD + ks * 128;
  __shared__ ushort Als[64 * 64];
  __shared__ ushort Bls[64 * 64];
  int tid = threadIdx.x;
  int srow = tid >> 2, su0 = (tid & 3) * 2;
  const ushort* ga = Qb + base + (size_t)srow * HDD + su0 * 8;
  const ushort* gb = Kb + base + (size_t)srow * HDD + su0 * 8;
  int wa0 = srow * 64 + ((su0) ^ (srow & 7)) * 8;
  int wa1 = srow * 64 + ((su0 + 1) ^ (srow & 7)) * 8;
  int lane = tid & 63, w = tid >> 6;
  int wm = w >> 1, wn = w & 1;
  int r = lane & 15, kg = lane >> 4;
  f32x4 acc[2][2] = {};
  uint4 pa0 = *(const uint4*)(ga);
  uint4 pa1 = *(const uint4*)(ga + 8);
  uint4 pb0 = *(const uint4*)(gb);
  uint4 pb1 = *(const uint4*)(gb + 8);
  for (int k0 = 0; k0 < 128; k0 += 64) {
    __syncthreads();
    *(uint4*)&Als[wa0] = pa0; *(uint4*)&Als[wa1] = pa1;
    *(uint4*)&Bls[wa0] = pb0; *(uint4*)&Bls[wa1] = pb1;
    __syncthreads();
    if (k0 == 0) {
      pa0 = *(const uint4*)(ga + 64);
      pa1 = *(const uint4*)(ga + 64 + 8);
      pb0 = *(const uint4*)(gb + 64);
      pb1 = *(const uint4*)(gb + 64 + 8);
    }
#pragma unroll
    for (int h = 0; h < 2; ++h) {
      int sa = ((h * 4 + kg) ^ (r & 7)) * 8;
      bf16x8 af[2], bfr[2];
#pragma unroll
      for (int m = 0; m < 2; ++m)
        af[m] = *(const bf16x8*)&Als[(wm * 32 + m * 16 + r) * 64 + sa];
#pragma unroll
      for (int n = 0; n < 2; ++n)
        bfr[n] = *(const bf16x8*)&Bls[(wn * 32 + n * 16 + r) * 64 + sa];
#pragma unroll
      for (int m = 0; m < 2; ++m)
#pragma unroll
        for (int n = 0; n < 2; ++n)
          acc[m][n] = __builtin_amdgcn_mfma_f32_16x16x32_bf16(af[m], bfr[n], acc[m][n], 0, 0, 0);
    }
  }
  float* out = Sp + ((size_t)ks * 32 + bh) * 4096;
#pragma unroll
  for (int m = 0; m < 2; ++m)
#pragma unroll
    for (int n = 0; n < 2; ++n) {
      f32x4 a = acc[m][n];
#pragma unroll
      for (int v = 0; v < 4; ++v) {
        int row = wm * 32 + m * 16 + kg * 4 + v;
        int col = wn * 32 + n * 16 + r;
        out[row * 64 + col] = a[v];
      }
    }
}

// ---------------- attn 2: sum partials + softmax + PV (128-wide d tile) ----------------
__global__ __launch_bounds__(256) void attn_pv(const float* __restrict__ Sp,
                                               const ushort* __restrict__ Vb,
                                               const int* __restrict__ gmask,
                                               ushort* __restrict__ AO) {
  int bid = blockIdx.x;
  int bh = bid >> 3, dt = bid & 7;
  int b = bh >> 2;
  int d0 = dt * 128;
  size_t base = ((size_t)b * LNN) * HDD + (size_t)(bh & 3) * DD;
  __shared__ float S[64][68];
  __shared__ ushort Pls[64 * 72];
  __shared__ ushort Vt[128 * 72];
  int tid = threadIdx.x;
  int lane = tid & 63, w = tid >> 6;
  // sum 8 partial slices; thread handles flat [tid*16, tid*16+16)
  {
    int fbase = tid * 16;
    float a[16];
#pragma unroll
    for (int i = 0; i < 16; i += 4) {
      float4 v = *(const float4*)(Sp + (size_t)bh * 4096 + fbase + i);
      a[i] = v.x; a[i + 1] = v.y; a[i + 2] = v.z; a[i + 3] = v.w;
    }
#pragma unroll
    for (int ks = 1; ks < 8; ++ks) {
      const float* p = Sp + ((size_t)ks * 32 + bh) * 4096 + fbase;
#pragma unroll
      for (int i = 0; i < 16; i += 4) {
        float4 v = *(const float4*)(p + i);
        a[i] += v.x; a[i + 1] += v.y; a[i + 2] += v.z; a[i + 3] += v.w;
      }
    }
    int q = fbase >> 6, k = fbase & 63;
#pragma unroll
    for (int i = 0; i < 16; ++i) S[q][k + i] = a[i];
  }
  // stage V^T: lane = k row, wave picks 32-d group
  {
    int kq = lane, dq = w * 32;
    const ushort* src = Vb + base + (size_t)kq * HDD + d0 + dq;
    uint4 v0 = *(const uint4*)src;
    uint4 v1 = *(const uint4*)(src + 8);
    uint4 v2 = *(const uint4*)(src + 16);
    uint4 v3 = *(const uint4*)(src + 24);
    ushort tmp[32];
    *(uint4*)&tmp[0] = v0; *(uint4*)&tmp[8] = v1;
    *(uint4*)&tmp[16] = v2; *(uint4*)&tmp[24] = v3;
#pragma unroll
    for (int j = 0; j < 32; ++j) Vt[(dq + j) * 72 + kq] = tmp[j];
  }
  __syncthreads();
  // masked softmax: wave w owns rows w*16..w*16+15, lane = k
  bool valid = gmask[b * LNN + lane] != 0;
  for (int i = 0; i < 16; ++i) {
    int q = w * 16 + i;
    float v = valid ? S[q][lane] * 0.03125f : -__builtin_inff();
    float mx = v;
    for (int o = 32; o; o >>= 1) mx = fmaxf(mx, __shfl_xor(mx, o, 64));
    float e = valid ? __expf(v - mx) : 0.f;
    float s = e;
    for (int o = 32; o; o >>= 1) s += __shfl_xor(s, o, 64);
    Pls[q * 72 + lane] = f2b(__fdividef(e, s));
  }
  __syncthreads();
  int wm = w >> 1, wn = w & 1;
  int r = lane & 15, kg = lane >> 4;
  f32x4 acc[2][4] = {};
#pragma unroll
  for (int h = 0; h < 2; ++h) {
    int ko = h * 32 + kg * 8;
    bf16x8 af[2], bfr[4];
#pragma unroll
    for (int m = 0; m < 2; ++m)
      af[m] = *(const bf16x8*)&Pls[(wm * 32 + m * 16 + r) * 72 + ko];
#pragma unroll
    for (int n = 0; n < 4; ++n)
      bfr[n] = *(const bf16x8*)&Vt[(wn * 64 + n * 16 + r) * 72 + ko];
#pragma unroll
    for (int m = 0; m < 2; ++m)
#pragma unroll
      for (int n = 0; n < 4; ++n)
        acc[m][n] = __builtin_amdgcn_mfma_f32_16x16x32_bf16(af[m], bfr[n], acc[m][n], 0, 0, 0);
  }
#pragma unroll
  for (int m = 0; m < 2; ++m)
#pragma unroll
    for (int n = 0; n < 4; ++n) {
      f32x4 a = acc[m][n];
#pragma unroll
      for (int v = 0; v < 4; ++v) {
        int q = wm * 32 + m * 16 + kg * 4 + v;
        int col = wn * 64 + n * 16 + r;
        AO[base + (size_t)q * HDD + d0 + col] = f2b(a[v]);
      }
    }
}

// ---------------- additive attention phase 1: partial e, 4-q reuse per block ----------------
__global__ __launch_bounds__(256) void addatt_e(const float* __restrict__ QBu,
                                                const float* __restrict__ KAB,
                                                const float* __restrict__ av_,
                                                float* __restrict__ E4) {
  int dq = blockIdx.x, qt = blockIdx.y, b = blockIdx.z;
  int tid = threadIdx.x;
  __shared__ float qs[4][256];
  __shared__ float avs[256];
  __shared__ float red[4];
  int bq0 = b * LNN + qt * 4;
#pragma unroll
  for (int qq = 0; qq < 4; ++qq)
    qs[qq][tid] = QBu[(size_t)(bq0 + qq) * DD + dq * 256 + tid];
  float av = av_[dq * 256 + tid];
  avs[tid] = av;
  float s = av;
  for (int o = 32; o; o >>= 1) s += __shfl_xor(s, o, 64);
  int lane = tid & 63, w = tid >> 6;
  if (lane == 0) red[w] = s;
  __syncthreads();
  float sumav = red[0] + red[1] + red[2] + red[3];
  const float* kr = KAB + (size_t)(b * LTN + tid) * DD + dq * 256;
  float ac0 = 0.f, ac1 = 0.f, ac2 = 0.f, ac3 = 0.f;
#pragma unroll 2
  for (int d = 0; d < 256; d += 4) {
    float4 kv = *(const float4*)(kr + d);
    float4 av4 = *(const float4*)&avs[d];
    float4 q0 = *(const float4*)&qs[0][d];
    float4 q1 = *(const float4*)&qs[1][d];
    float4 q2 = *(const float4*)&qs[2][d];
    float4 q3 = *(const float4*)&qs[3][d];
    ac0 = fmaf(av4.x, __builtin_amdgcn_rcpf(__builtin_amdgcn_exp2f(q0.x + kv.x) + 1.f), ac0);
    ac1 = fmaf(av4.x, __builtin_amdgcn_rcpf(__builtin_amdgcn_exp2f(q1.x + kv.x) + 1.f), ac1);
    ac2 = fmaf(av4.x, __builtin_amdgcn_rcpf(__builtin_amdgcn_exp2f(q2.x + kv.x) + 1.f), ac2);
    ac3 = fmaf(av4.x, __builtin_amdgcn_rcpf(__builtin_amdgcn_exp2f(q3.x + kv.x) + 1.f), ac3);
    ac0 = fmaf(av4.y, __builtin_amdgcn_rcpf(__builtin_amdgcn_exp2f(q0.y + kv.y) + 1.f), ac0);
    ac1 = fmaf(av4.y, __builtin_amdgcn_rcpf(__builtin_amdgcn_exp2f(q1.y + kv.y) + 1.f), ac1);
    ac2 = fmaf(av4.y, __builtin_amdgcn_rcpf(__builtin_amdgcn_exp2f(q2.y + kv.y) + 1.f), ac2);
    ac3 = fmaf(av4.y, __builtin_amdgcn_rcpf(__builtin_amdgcn_exp2f(q3.y + kv.y) + 1.f), ac3);
    ac0 = fmaf(av4.z, __builtin_amdgcn_rcpf(__builtin_amdgcn_exp2f(q0.z + kv.z) + 1.f), ac0);
    ac1 = fmaf(av4.z, __builtin_amdgcn_rcpf(__builtin_amdgcn_exp2f(q1.z + kv.z) + 1.f), ac1);
    ac2 = fmaf(av4.z, __builtin_amdgcn_rcpf(__builtin_amdgcn_exp2f(q2.z + kv.z) + 1.f), ac2);
    ac3 = fmaf(av4.z, __builtin_amdgcn_rcpf(__builtin_amdgcn_exp2f(q3.z + kv.z) + 1.f), ac3);
    ac0 = fmaf(av4.w, __builtin_amdgcn_rcpf(__builtin_amdgcn_exp2f(q0.w + kv.w) + 1.f), ac0);
    ac1 = fmaf(av4.w, __builtin_amdgcn_rcpf(__builtin_amdgcn_exp2f(q1.w + kv.w) + 1.f), ac1);
    ac2 = fmaf(av4.w, __builtin_amdgcn_rcpf(__builtin_amdgcn_exp2f(q2.w + kv.w) + 1.f), ac2);
    ac3 = fmaf(av4.w, __builtin_amdgcn_rcpf(__builtin_amdgcn_exp2f(q3.w + kv.w) + 1.f), ac3);
  }
  size_t ebase = ((size_t)dq * 512 + bq0) * LTN + tid;
  E4[ebase] = sumav - 2.f * ac0;
  E4[ebase + LTN] = sumav - 2.f * ac1;
  E4[ebase + 2 * LTN] = sumav - 2.f * ac2;
  E4[ebase + 3 * LTN] = sumav - 2.f * ac3;
}

// ---------------- additive attention phase 2: sum partials + masked softmax -> w ----------------
__global__ __launch_bounds__(256) void addatt_sm(const float* __restrict__ E4,
                                                 const int* __restrict__ lmask,
                                                 float* __restrict__ Wv) {
  int bq = blockIdx.x;
  int b = bq >> 6;
  int tid = threadIdx.x;
  __shared__ float rb_[8];
  float e = E4[(size_t)bq * LTN + tid] + E4[((size_t)512 + bq) * LTN + tid] +
            E4[((size_t)1024 + bq) * LTN + tid] + E4[((size_t)1536 + bq) * LTN + tid];
  bool valid = lmask[b * LTN + tid] != 0;
  float v = valid ? e : -__builtin_inff();
  int lane = tid & 63, w = tid >> 6;
  float m = v;
  for (int o = 32; o; o >>= 1) m = fmaxf(m, __shfl_xor(m, o, 64));
  if (lane == 0) rb_[w] = m;
  __syncthreads();
  m = fmaxf(fmaxf(rb_[0], rb_[1]), fmaxf(rb_[2], rb_[3]));
  float ex = valid ? __expf(v - m) : 0.f;
  float sm = ex;
  for (int o = 32; o; o >>= 1) sm += __shfl_xor(sm, o, 64);
  if (lane == 0) rb_[4 + w] = sm;
  __syncthreads();
  sm = rb_[4] + rb_[5] + rb_[6] + rb_[7];
  Wv[(size_t)bq * LTN + tid] = __fdividef(ex, sm);
}

// ---------------- additive attention phase 3: pooled context ----------------
__global__ __launch_bounds__(256) void addatt_pool(const float* __restrict__ Wv,
                                                   const float* __restrict__ text,
                                                   const int* __restrict__ gmask,
                                                   float* __restrict__ H4) {
  int dt = blockIdx.x, b = blockIdx.y;
  int tid = threadIdx.x;
  __shared__ float cf[LTN];
  float c = 0.f, cnt = 0.f;
#pragma unroll 8
  for (int q = 0; q < LNN; ++q) {
    float m = (gmask[b * LNN + q] != 0) ? 1.f : 0.f;
    cnt += m;
    c = fmaf(m, Wv[(size_t)(b * LNN + q) * LTN + tid], c);
  }
  cf[tid] = c;
  cnt = fmaxf(cnt, 9.765625e-04f);
  __syncthreads();
  int d = dt * 256 + tid;
  const float* tb = text + (size_t)b * LTN * DD + d;
  float acc = 0.f;
#pragma unroll 8
  for (int k = 0; k < LTN; ++k) acc = fmaf(cf[k], tb[(size_t)k * DD], acc);
  H4[b * DD + d] = acc / cnt;
}

// ---------------- split-K GEMV ----------------
__global__ __launch_bounds__(256) void dp_split(const float* __restrict__ X,
                                                const float* __restrict__ W,
                                                float* __restrict__ P,
                                                int K, int N) {
  int jt = blockIdx.x, kt = blockIdx.y;
  int t = threadIdx.x;
  __shared__ float xs[8][32];
  if (t < 64) {
    int b = t >> 3, kk = (t & 7) * 4;
    *(float4*)&xs[b][kk] = *(const float4*)(X + (size_t)b * K + kt * 32 + kk);
  }
  __syncthreads();
  int j = jt * 64 + (t & 63);
  int bg = (t >> 6) * 2;
  const float* wp = W + (size_t)(kt * 32) * N + j;
  float a0 = 0.f, a1 = 0.f;
#pragma unroll
  for (int k = 0; k < 32; ++k) {
    float w = wp[(size_t)k * N];
    a0 = fmaf(xs[bg + 0][k], w, a0);
    a1 = fmaf(xs[bg + 1][k], w, a1);
  }
  P[((size_t)kt * 8 + bg + 0) * N + j] = a0;
  P[((size_t)kt * 8 + bg + 1) * N + j] = a1;
}

template <int GELU>
__global__ __launch_bounds__(256) void dp_reduce(const float* __restrict__ P,
                                                 const float* __restrict__ bias,
                                                 float* __restrict__ O, int N) {
  int b = blockIdx.y;
  int j = blockIdx.x * 256 + threadIdx.x;
  float s = bias[j];
#pragma unroll 8
  for (int kt = 0; kt < 32; ++kt) s += P[((size_t)kt * 8 + b) * N + j];
  if constexpr (GELU) s = 0.5f * s * (1.f + erff(s * 0.70710678118654752440f));
  O[(size_t)b * N + j] = s;
}

extern "C" void kernel_launch(void* const* d_in, const int* in_sizes, int n_in,
                              void* d_out, int out_size, void* d_ws, size_t ws_size,
                              hipStream_t stream) {
  const float* text = (const float*)d_in[0];
  const float* node = (const float*)d_in[1];
  const float* Wq = (const float*)d_in[2];
  const float* bq = (const float*)d_in[3];
  const float* Wk = (const float*)d_in[4];
  const float* bk = (const float*)d_in[5];
  const float* Wv = (const float*)d_in[6];
  const float* bv = (const float*)d_in[7];
  const float* Wo = (const float*)d_in[8];
  const float* bo = (const float*)d_in[9];
  const float* lng = (const float*)d_in[10];
  const float* lnb = (const float*)d_in[11];
  const float* aqW = (const float*)d_in[12];
  const float* aqb = (const float*)d_in[13];
  const float* akW = (const float*)d_in[14];
  const float* akb = (const float*)d_in[15];
  const float* attv = (const float*)d_in[16];
  const float* attb = (const float*)d_in[17];
  const float* dp1W = (const float*)d_in[18];
  const float* dp1b = (const float*)d_in[19];
  const float* dp2W = (const float*)d_in[20];
  const float* dp2b = (const float*)d_in[21];
  const int* gmask = (const int*)d_in[22];
  const int* lmask = (const int*)d_in[23];
  (void)in_sizes; (void)n_in; (void)out_size;

  char* base = (char*)d_ws;
#define MB(x) (((size_t)(x)) << 20)
  ushort* Twt = (ushort*)(base);               // 8MB (Sp during attn; Wo/aqak weights after)
  float* Sp = (float*)(base);                  // 4MB QK^T partials (before Wo tcvt)
  ushort* node_bf = (ushort*)(base + MB(8));   // 1MB
  ushort* text_bf = (ushort*)(base + MB(9));   // 4MB
  ushort* Qb = (ushort*)(base + MB(13));       // 4MB
  ushort* Kb = (ushort*)(base + MB(17));       // 4MB
  ushort* Vb = (ushort*)(base + MB(21));       // 4MB
  ushort* AO = (ushort*)(base + MB(25));       // 4MB
  float* E4 = (float*)(base + MB(13));         // 2MB (Qb dead after attn)
  float* Wvb = (float*)(base + MB(15));        // 512KB
  ushort* H2 = (ushort*)(base + MB(15) + (512 << 10));  // 1MB
  float* P_Wo = (float*)(base + MB(17));       // 8MB (Kb/Vb dead after attn)
  float* P1 = (float*)(base + MB(18));         // 1MB (dp phase; P_Wo dead)
  float* P2 = (float*)(base + MB(19));         // 2MB
  float* QBu = (float*)(base + MB(21));        // 2MB (written after wo_ln)
  float* KAB = (float*)(base + MB(25));        // 8MB (AO dead after Wo gemm)
  float* H4 = (float*)(base + MB(33));         // 32KB
  float* G = (float*)(base + MB(33) + 32768);  // 32KB
  ushort* TwtQKV = (ushort*)(base + MB(34));   // 24MB, bigws only
  float* Z = (float*)d_out;
  const bool bigws = ws_size >= MB(59);
#undef MB

  const int M1 = NB * LNN;  // 512
  dim3 blk(256);

  // activations -> bf16 (one launch)
  cvt_all<<<dim3(1280), blk, 0, stream>>>(node, node_bf, text, text_bf);

  // QKV projections
  if (bigws) {
    tcvt3<<<dim3(HDD / 64, DD / 64, 3), blk, 0, stream>>>(Wq, Wk, Wv, TwtQKV, DD, HDD);
    gemm_qkv3<<<dim3(HDD / 128, M1 / 64, 3), blk, 0, stream>>>(node_bf, TwtQKV, bq, bk, bv, Qb, Kb, Vb, M1, HDD, DD);
  } else {
    tcvt3<<<dim3(HDD / 64, DD / 64, 1), blk, 0, stream>>>(Wq, Wq, Wq, Twt, DD, HDD);
    gemm_qkv3<<<dim3(HDD / 128, M1 / 64, 1), blk, 0, stream>>>(node_bf, Twt, bq, bq, bq, Qb, Qb, Qb, M1, HDD, DD);
    tcvt3<<<dim3(HDD / 64, DD / 64, 1), blk, 0, stream>>>(Wk, Wk, Wk, Twt, DD, HDD);
    gemm_qkv3<<<dim3(HDD / 128, M1 / 64, 1), blk, 0, stream>>>(node_bf, Twt, bk, bk, bk, Kb, Kb, Kb, M1, HDD, DD);
    tcvt3<<<dim3(HDD / 64, DD / 64, 1), blk, 0, stream>>>(Wv, Wv, Wv, Twt, DD, HDD);
    gemm_qkv3<<<dim3(HDD / 128, M1 / 64, 1), blk, 0, stream>>>(node_bf, Twt, bv, bv, bv, Vb, Vb, Vb, M1, HDD, DD);
  }

  // self-attention: QK^T split-K (256 blocks) then softmax+PV (256 blocks)
  attn_qk<<<dim3(NB * NH, 8), blk, 0, stream>>>(Qb, Kb, Sp);
  attn_pv<<<dim3(NB * NH * 8), blk, 0, stream>>>(Sp, Vb, gmask, AO);

  // output proj: split-K 4-way partials, then fused reduce+residual+LayerNorm
  tcvt3<<<dim3(DD / 64, HDD / 64, 1), blk, 0, stream>>>(Wo, Wo, Wo, Twt, HDD, DD);
  gemm_wo_split<<<dim3(DD / 128, M1 / 64, 4), blk, 0, stream>>>(AO, Twt, P_Wo, M1, DD, HDD);
  wo_ln<<<dim3(M1), blk, 0, stream>>>(P_Wo, bo, node, lng, lnb, H2);

  // aq + ak: one tcvt (z=2) + one M-concat gemm; outputs pre-scaled by C_TANH
  tcvt3<<<dim3(DD / 64, DD / 64, 2), blk, 0, stream>>>(aqW, akW, akW, Twt, DD, DD);
  gemm_aqak<<<dim3(DD / 128, 40), blk, 0, stream>>>(H2, text_bf, Twt, aqb, akb, attb, QBu, KAB, DD, DD);

  // additive attention: partial-e (4-q reuse) -> softmax -> pooled context
  addatt_e<<<dim3(4, 16, NB), blk, 0, stream>>>(QBu, KAB, attv, E4);
  addatt_sm<<<dim3(M1), blk, 0, stream>>>(E4, lmask, Wvb);
  addatt_pool<<<dim3(4, NB), blk, 0, stream>>>(Wvb, text, gmask, H4);

  // MLP via split-K GEMV (weight-read-bound)
  dp_split<<<dim3(DHN / 64, 32), blk, 0, stream>>>(H4, dp1W, P1, DD, DHN);
  dp_reduce<1><<<dim3(DHN / 256, NB), blk, 0, stream>>>(P1, dp1b, G, DHN);
  dp_split<<<dim3(DINN / 64, 32), blk, 0, stream>>>(G, dp2W, P2, DHN, DINN);
  dp_reduce<0><<<dim3(DINN / 256, NB), blk, 0, stream>>>(P2, dp2b, Z, DINN);
}

// Round 9
// 161.985 us; speedup vs baseline: 7.4067x; 1.0721x over previous
//
#include <hip/hip_runtime.h>
#include <hip/hip_bf16.h>
#include <math.h>

#define NB 8        // batch
#define LNN 64      // nodes
#define LTN 256     // text len
#define DD 1024     // model dim
#define NH 4        // heads (each full width D)
#define HDD 4096    // NH*DD
#define DINN 2048
#define DHN 1024    // DIN/2

// 2*log2(e): tanh(x) = 1 - 2/(exp2(x*C)+1)
#define C_TANH 2.8853900817779268f

typedef __bf16 bf16x8 __attribute__((ext_vector_type(8)));
typedef float f32x4 __attribute__((ext_vector_type(4)));

__device__ __forceinline__ ushort f2b(float f) {
  unsigned int u = __builtin_bit_cast(unsigned int, f);
  u = (u + 0x7FFFu + ((u >> 16) & 1u)) >> 16;
  return (ushort)u;
}

// ---------------- mega-prep: activations cvt + all 6 weight transposes, 1 launch ----------------
// blocks: [0,256) node cvt, [256,1280) text cvt, [1280,4352) Wq/Wk/Wv (1024 ea),
// [4352,5376) Wo, [5376,5632) aq, [5632,5888) ak
__global__ __launch_bounds__(256) void prep(const float* __restrict__ node,
                                            ushort* __restrict__ node_bf,
                                            const float* __restrict__ text,
                                            ushort* __restrict__ text_bf,
                                            const float* __restrict__ Wq,
                                            const float* __restrict__ Wk,
                                            const float* __restrict__ Wv,
                                            const float* __restrict__ Wo,
                                            const float* __restrict__ aqW,
                                            const float* __restrict__ akW,
                                            ushort* __restrict__ TwtQKV,
                                            ushort* __restrict__ TwtWo,
                                            ushort* __restrict__ TwtAQ) {
  int bid = blockIdx.x;
  int t = threadIdx.x;
  if (bid < 1280) {
    const float* in;
    ushort* out;
    int i;
    if (bid < 256) { in = node; out = node_bf; i = (bid * 256 + t) * 8; }
    else { in = text; out = text_bf; i = ((bid - 256) * 256 + t) * 8; }
    float4 a = *(const float4*)(in + i);
    float4 b = *(const float4*)(in + i + 4);
    ushort4 o0 = {f2b(a.x), f2b(a.y), f2b(a.z), f2b(a.w)};
    ushort4 o1 = {f2b(b.x), f2b(b.y), f2b(b.z), f2b(b.w)};
    *(ushort4*)(out + i) = o0;
    *(ushort4*)(out + i + 4) = o1;
    return;
  }
  bid -= 1280;
  const float* W;
  ushort* dst0;
  int K, N, tt;
  if (bid < 3072) {
    int z = bid >> 10;
    tt = bid & 1023;
    W = (z == 0) ? Wq : ((z == 1) ? Wk : Wv);
    dst0 = TwtQKV + (size_t)z * DD * HDD;
    K = DD; N = HDD;
  } else if (bid < 4096) {
    tt = bid - 3072; W = Wo; dst0 = TwtWo; K = HDD; N = DD;
  } else if (bid < 4352) {
    tt = bid - 4096; W = aqW; dst0 = TwtAQ; K = DD; N = DD;
  } else {
    tt = bid - 4352; W = akW; dst0 = TwtAQ + (size_t)DD * DD; K = DD; N = DD;
  }
  int ntn = N >> 6;
  int n0 = (tt % ntn) << 6, k0 = (tt / ntn) << 6;
  __shared__ float tf[64][65];
  int r = t >> 2, c4 = (t & 3) * 16;
  const float* src = W + (size_t)(k0 + r) * N + n0 + c4;
  float4 v0 = *(const float4*)(src);
  float4 v1 = *(const float4*)(src + 4);
  float4 v2 = *(const float4*)(src + 8);
  float4 v3 = *(const float4*)(src + 12);
  *(float4*)&tf[r][c4] = v0;
  *(float4*)&tf[r][c4 + 4] = v1;
  *(float4*)&tf[r][c4 + 8] = v2;
  *(float4*)&tf[r][c4 + 12] = v3;
  __syncthreads();
  int nl = t >> 2, kc = (t & 3) * 16;
  ushort tmp[16];
#pragma unroll
  for (int j = 0; j < 16; ++j) tmp[j] = f2b(tf[kc + j][nl]);
  ushort* dst = dst0 + (size_t)(n0 + nl) * K + k0 + kc;
  *(uint4*)(dst) = *(uint4*)&tmp[0];
  *(uint4*)(dst + 8) = *(uint4*)&tmp[8];
}

// ---------------- QKV gemm (3 via grid.z): bf16 out, +bias ----------------
__global__ __launch_bounds__(256) void gemm_qkv3(const ushort* __restrict__ A,
                                                 const ushort* __restrict__ BtB,
                                                 const float* __restrict__ b0,
                                                 const float* __restrict__ b1,
                                                 const float* __restrict__ b2,
                                                 ushort* __restrict__ o0,
                                                 ushort* __restrict__ o1,
                                                 ushort* __restrict__ o2,
                                                 int M, int N, int K) {
  int z = blockIdx.z;
  const ushort* Bt = BtB + (size_t)z * N * K;
  const float* bias = (z == 0) ? b0 : ((z == 1) ? b1 : b2);
  ushort* Cout = (z == 0) ? o0 : ((z == 1) ? o1 : o2);
  __shared__ ushort Als[64 * 64];
  __shared__ ushort Bls[128 * 64];
  int tid = threadIdx.x;
  int m0 = blockIdx.y << 6, n0 = blockIdx.x << 7;
  int srow = tid >> 3, su = tid & 7;
  int sx = (su ^ (srow & 7)) * 8;
  const ushort* ga = A + (size_t)(m0 + srow) * K + su * 8;
  const ushort* gb = Bt + (size_t)(n0 + srow) * K + su * 8;
  int wa0 = srow * 64 + sx, wa1 = (srow + 32) * 64 + sx;
  int wb2 = (srow + 64) * 64 + sx, wb3 = (srow + 96) * 64 + sx;
  const size_t rs32 = (size_t)32 * K;
  int lane = tid & 63, w = tid >> 6;
  int wm = w >> 1, wn = w & 1;
  int r = lane & 15, kg = lane >> 4;
  f32x4 acc[2][4] = {};
  uint4 pa0 = *(const uint4*)(ga);
  uint4 pa1 = *(const uint4*)(ga + rs32);
  uint4 pb0 = *(const uint4*)(gb);
  uint4 pb1 = *(const uint4*)(gb + rs32);
  uint4 pb2 = *(const uint4*)(gb + 2 * rs32);
  uint4 pb3 = *(const uint4*)(gb + 3 * rs32);
  for (int k0 = 0; k0 < K; k0 += 64) {
    __syncthreads();
    *(uint4*)&Als[wa0] = pa0; *(uint4*)&Als[wa1] = pa1;
    *(uint4*)&Bls[wa0] = pb0; *(uint4*)&Bls[wa1] = pb1;
    *(uint4*)&Bls[wb2] = pb2; *(uint4*)&Bls[wb3] = pb3;
    __syncthreads();
    int kn = k0 + 64;
    if (kn < K) {
      pa0 = *(const uint4*)(ga + kn);
      pa1 = *(const uint4*)(ga + rs32 + kn);
      pb0 = *(const uint4*)(gb + kn);
      pb1 = *(const uint4*)(gb + rs32 + kn);
      pb2 = *(const uint4*)(gb + 2 * rs32 + kn);
      pb3 = *(const uint4*)(gb + 3 * rs32 + kn);
    }
#pragma unroll
    for (int h = 0; h < 2; ++h) {
      int sa = ((h * 4 + kg) ^ (r & 7)) * 8;
      bf16x8 af[2], bfr[4];
#pragma unroll
      for (int m = 0; m < 2; ++m)
        af[m] = *(const bf16x8*)&Als[(wm * 32 + m * 16 + r) * 64 + sa];
#pragma unroll
      for (int n = 0; n < 4; ++n)
        bfr[n] = *(const bf16x8*)&Bls[(wn * 64 + n * 16 + r) * 64 + sa];
#pragma unroll
      for (int m = 0; m < 2; ++m)
#pragma unroll
        for (int n = 0; n < 4; ++n)
          acc[m][n] = __builtin_amdgcn_mfma_f32_16x16x32_bf16(af[m], bfr[n], acc[m][n], 0, 0, 0);
    }
  }
#pragma unroll
  for (int m = 0; m < 2; ++m)
#pragma unroll
    for (int n = 0; n < 4; ++n) {
      f32x4 a = acc[m][n];
#pragma unroll
      for (int v = 0; v < 4; ++v) {
        int row = m0 + wm * 32 + m * 16 + kg * 4 + v;
        int col = n0 + wn * 64 + n * 16 + r;
        Cout[(size_t)row * N + col] = f2b(a[v] + bias[col]);
      }
    }
}

// ---------------- Wo gemm with split-K (grid.z): fp32 partials ----------------
__global__ __launch_bounds__(256) void gemm_wo_split(const ushort* __restrict__ A,
                                                     const ushort* __restrict__ Bt,
                                                     float* __restrict__ P,
                                                     int M, int N, int K) {
  __shared__ ushort Als[64 * 64];
  __shared__ ushort Bls[128 * 64];
  int tid = threadIdx.x;
  int m0 = blockIdx.y << 6, n0 = blockIdx.x << 7;
  int Ks = K >> 2, kbase = blockIdx.z * Ks;
  int srow = tid >> 3, su = tid & 7;
  int sx = (su ^ (srow & 7)) * 8;
  const ushort* ga = A + (size_t)(m0 + srow) * K + kbase + su * 8;
  const ushort* gb = Bt + (size_t)(n0 + srow) * K + kbase + su * 8;
  int wa0 = srow * 64 + sx, wa1 = (srow + 32) * 64 + sx;
  int wb2 = (srow + 64) * 64 + sx, wb3 = (srow + 96) * 64 + sx;
  const size_t rs32 = (size_t)32 * K;
  int lane = tid & 63, w = tid >> 6;
  int wm = w >> 1, wn = w & 1;
  int r = lane & 15, kg = lane >> 4;
  f32x4 acc[2][4] = {};
  uint4 pa0 = *(const uint4*)(ga);
  uint4 pa1 = *(const uint4*)(ga + rs32);
  uint4 pb0 = *(const uint4*)(gb);
  uint4 pb1 = *(const uint4*)(gb + rs32);
  uint4 pb2 = *(const uint4*)(gb + 2 * rs32);
  uint4 pb3 = *(const uint4*)(gb + 3 * rs32);
  for (int k0 = 0; k0 < Ks; k0 += 64) {
    __syncthreads();
    *(uint4*)&Als[wa0] = pa0; *(uint4*)&Als[wa1] = pa1;
    *(uint4*)&Bls[wa0] = pb0; *(uint4*)&Bls[wa1] = pb1;
    *(uint4*)&Bls[wb2] = pb2; *(uint4*)&Bls[wb3] = pb3;
    __syncthreads();
    int kn = k0 + 64;
    if (kn < Ks) {
      pa0 = *(const uint4*)(ga + kn);
      pa1 = *(const uint4*)(ga + rs32 + kn);
      pb0 = *(const uint4*)(gb + kn);
      pb1 = *(const uint4*)(gb + rs32 + kn);
      pb2 = *(const uint4*)(gb + 2 * rs32 + kn);
      pb3 = *(const uint4*)(gb + 3 * rs32 + kn);
    }
#pragma unroll
    for (int h = 0; h < 2; ++h) {
      int sa = ((h * 4 + kg) ^ (r & 7)) * 8;
      bf16x8 af[2], bfr[4];
#pragma unroll
      for (int m = 0; m < 2; ++m)
        af[m] = *(const bf16x8*)&Als[(wm * 32 + m * 16 + r) * 64 + sa];
#pragma unroll
      for (int n = 0; n < 4; ++n)
        bfr[n] = *(const bf16x8*)&Bls[(wn * 64 + n * 16 + r) * 64 + sa];
#pragma unroll
      for (int m = 0; m < 2; ++m)
#pragma unroll
        for (int n = 0; n < 4; ++n)
          acc[m][n] = __builtin_amdgcn_mfma_f32_16x16x32_bf16(af[m], bfr[n], acc[m][n], 0, 0, 0);
    }
  }
#pragma unroll
  for (int m = 0; m < 2; ++m)
#pragma unroll
    for (int n = 0; n < 4; ++n) {
      f32x4 a = acc[m][n];
#pragma unroll
      for (int v = 0; v < 4; ++v) {
        int row = m0 + wm * 32 + m * 16 + kg * 4 + v;
        int col = n0 + wn * 64 + n * 16 + r;
        P[((size_t)blockIdx.z * M + row) * N + col] = a[v];
      }
    }
}

// ---------------- aq+ak gemm (M-concat row select): fp32 out, *C_TANH ----------------
__global__ __launch_bounds__(256) void gemm_aqak(const ushort* __restrict__ H2,
                                                 const ushort* __restrict__ Tbf,
                                                 const ushort* __restrict__ TwtAQ,
                                                 const float* __restrict__ aqb,
                                                 const float* __restrict__ akb,
                                                 const float* __restrict__ attb,
                                                 float* __restrict__ QBu,
                                                 float* __restrict__ KAB,
                                                 int N, int K) {
  __shared__ ushort Als[64 * 64];
  __shared__ ushort Bls[128 * 64];
  int tid = threadIdx.x;
  int gm0 = blockIdx.y << 6, n0 = blockIdx.x << 7;
  const ushort* Abase;
  const ushort* Bt;
  const float* bias;
  const float* bias2;
  float* Obase;
  if (gm0 < 512) {
    Abase = H2 + (size_t)gm0 * K;
    Bt = TwtAQ;
    bias = aqb; bias2 = nullptr;
    Obase = QBu + (size_t)gm0 * N;
  } else {
    Abase = Tbf + (size_t)(gm0 - 512) * K;
    Bt = TwtAQ + (size_t)N * K;
    bias = akb; bias2 = attb;
    Obase = KAB + (size_t)(gm0 - 512) * N;
  }
  int srow = tid >> 3, su = tid & 7;
  int sx = (su ^ (srow & 7)) * 8;
  const ushort* ga = Abase + (size_t)srow * K + su * 8;
  const ushort* gb = Bt + (size_t)(n0 + srow) * K + su * 8;
  int wa0 = srow * 64 + sx, wa1 = (srow + 32) * 64 + sx;
  int wb2 = (srow + 64) * 64 + sx, wb3 = (srow + 96) * 64 + sx;
  const size_t rs32 = (size_t)32 * K;
  int lane = tid & 63, w = tid >> 6;
  int wm = w >> 1, wn = w & 1;
  int r = lane & 15, kg = lane >> 4;
  f32x4 acc[2][4] = {};
  uint4 pa0 = *(const uint4*)(ga);
  uint4 pa1 = *(const uint4*)(ga + rs32);
  uint4 pb0 = *(const uint4*)(gb);
  uint4 pb1 = *(const uint4*)(gb + rs32);
  uint4 pb2 = *(const uint4*)(gb + 2 * rs32);
  uint4 pb3 = *(const uint4*)(gb + 3 * rs32);
  for (int k0 = 0; k0 < K; k0 += 64) {
    __syncthreads();
    *(uint4*)&Als[wa0] = pa0; *(uint4*)&Als[wa1] = pa1;
    *(uint4*)&Bls[wa0] = pb0; *(uint4*)&Bls[wa1] = pb1;
    *(uint4*)&Bls[wb2] = pb2; *(uint4*)&Bls[wb3] = pb3;
    __syncthreads();
    int kn = k0 + 64;
    if (kn < K) {
      pa0 = *(const uint4*)(ga + kn);
      pa1 = *(const uint4*)(ga + rs32 + kn);
      pb0 = *(const uint4*)(gb + kn);
      pb1 = *(const uint4*)(gb + rs32 + kn);
      pb2 = *(const uint4*)(gb + 2 * rs32 + kn);
      pb3 = *(const uint4*)(gb + 3 * rs32 + kn);
    }
#pragma unroll
    for (int h = 0; h < 2; ++h) {
      int sa = ((h * 4 + kg) ^ (r & 7)) * 8;
      bf16x8 af[2], bfr[4];
#pragma unroll
      for (int m = 0; m < 2; ++m)
        af[m] = *(const bf16x8*)&Als[(wm * 32 + m * 16 + r) * 64 + sa];
#pragma unroll
      for (int n = 0; n < 4; ++n)
        bfr[n] = *(const bf16x8*)&Bls[(wn * 64 + n * 16 + r) * 64 + sa];
#pragma unroll
      for (int m = 0; m < 2; ++m)
#pragma unroll
        for (int n = 0; n < 4; ++n)
          acc[m][n] = __builtin_amdgcn_mfma_f32_16x16x32_bf16(af[m], bfr[n], acc[m][n], 0, 0, 0);
    }
  }
#pragma unroll
  for (int m = 0; m < 2; ++m)
#pragma unroll
    for (int n = 0; n < 4; ++n) {
      f32x4 a = acc[m][n];
#pragma unroll
      for (int v = 0; v < 4; ++v) {
        int lrow = wm * 32 + m * 16 + kg * 4 + v;
        int col = n0 + wn * 64 + n * 16 + r;
        float x = a[v] + bias[col];
        if (bias2) x += bias2[col];
        Obase[(size_t)lrow * N + col] = x * C_TANH;
      }
    }
}

// ---------------- Wo split-K reduce + bias + residual + LayerNorm -> bf16 ----------------
__global__ __launch_bounds__(256) void wo_ln(const float* __restrict__ P,
                                             const float* __restrict__ bo,
                                             const float* __restrict__ node,
                                             const float* __restrict__ g,
                                             const float* __restrict__ be,
                                             ushort* __restrict__ Y) {
  int row = blockIdx.x, tid = threadIdx.x;
  int c = tid * 4;
  const size_t MN = (size_t)512 * 1024;
  size_t o = (size_t)row * DD + c;
  float4 v0 = *(const float4*)(P + o);
  float4 v1 = *(const float4*)(P + MN + o);
  float4 v2 = *(const float4*)(P + 2 * MN + o);
  float4 v3 = *(const float4*)(P + 3 * MN + o);
  float4 rv = *(const float4*)(node + o);
  float4 bv = *(const float4*)(bo + c);
  float4 v;
  v.x = v0.x + v1.x + v2.x + v3.x + rv.x + bv.x;
  v.y = v0.y + v1.y + v2.y + v3.y + rv.y + bv.y;
  v.z = v0.z + v1.z + v2.z + v3.z + rv.z + bv.z;
  v.w = v0.w + v1.w + v2.w + v3.w + rv.w + bv.w;
  float s = v.x + v.y + v.z + v.w;
  float ss = v.x * v.x + v.y * v.y + v.z * v.z + v.w * v.w;
  for (int o2 = 32; o2; o2 >>= 1) {
    s += __shfl_xor(s, o2, 64);
    ss += __shfl_xor(ss, o2, 64);
  }
  __shared__ float rb_[8];
  int lane = tid & 63, w = tid >> 6;
  if (lane == 0) { rb_[w] = s; rb_[4 + w] = ss; }
  __syncthreads();
  s = rb_[0] + rb_[1] + rb_[2] + rb_[3];
  ss = rb_[4] + rb_[5] + rb_[6] + rb_[7];
  float mu = s * (1.f / 1024.f);
  float var = ss * (1.f / 1024.f) - mu * mu;
  float rstd = rsqrtf(var + 1e-5f);
  ushort4 o4;
  o4.x = f2b((v.x - mu) * rstd * g[c + 0] + be[c + 0]);
  o4.y = f2b((v.y - mu) * rstd * g[c + 1] + be[c + 1]);
  o4.z = f2b((v.z - mu) * rstd * g[c + 2] + be[c + 2]);
  o4.w = f2b((v.w - mu) * rstd * g[c + 3] + be[c + 3]);
  *(ushort4*)(Y + (size_t)row * DD + c) = o4;
}

// ---------------- attn 1: QK^T split-K over D: Sp[ks][bh][64][64] fp32 ----------------
__global__ __launch_bounds__(256) void attn_qk(const ushort* __restrict__ Qb,
                                               const ushort* __restrict__ Kb,
                                               float* __restrict__ Sp) {
  int bh = blockIdx.x, ks = blockIdx.y;
  int b = bh >> 2;
  size_t base = ((size_t)b * LNN) * HDD + (size_t)(bh & 3) * DD + ks * 128;
  __shared__ ushort Als[64 * 64];
  __shared__ ushort Bls[64 * 64];
  int tid = threadIdx.x;
  int srow = tid >> 2, su0 = (tid & 3) * 2;
  const ushort* ga = Qb + base + (size_t)srow * HDD + su0 * 8;
  const ushort* gb = Kb + base + (size_t)srow * HDD + su0 * 8;
  int wa0 = srow * 64 + ((su0) ^ (srow & 7)) * 8;
  int wa1 = srow * 64 + ((su0 + 1) ^ (srow & 7)) * 8;
  int lane = tid & 63, w = tid >> 6;
  int wm = w >> 1, wn = w & 1;
  int r = lane & 15, kg = lane >> 4;
  f32x4 acc[2][2] = {};
  uint4 pa0 = *(const uint4*)(ga);
  uint4 pa1 = *(const uint4*)(ga + 8);
  uint4 pb0 = *(const uint4*)(gb);
  uint4 pb1 = *(const uint4*)(gb + 8);
  for (int k0 = 0; k0 < 128; k0 += 64) {
    __syncthreads();
    *(uint4*)&Als[wa0] = pa0; *(uint4*)&Als[wa1] = pa1;
    *(uint4*)&Bls[wa0] = pb0; *(uint4*)&Bls[wa1] = pb1;
    __syncthreads();
    if (k0 == 0) {
      pa0 = *(const uint4*)(ga + 64);
      pa1 = *(const uint4*)(ga + 64 + 8);
      pb0 = *(const uint4*)(gb + 64);
      pb1 = *(const uint4*)(gb + 64 + 8);
    }
#pragma unroll
    for (int h = 0; h < 2; ++h) {
      int sa = ((h * 4 + kg) ^ (r & 7)) * 8;
      bf16x8 af[2], bfr[2];
#pragma unroll
      for (int m = 0; m < 2; ++m)
        af[m] = *(const bf16x8*)&Als[(wm * 32 + m * 16 + r) * 64 + sa];
#pragma unroll
      for (int n = 0; n < 2; ++n)
        bfr[n] = *(const bf16x8*)&Bls[(wn * 32 + n * 16 + r) * 64 + sa];
#pragma unroll
      for (int m = 0; m < 2; ++m)
#pragma unroll
        for (int n = 0; n < 2; ++n)
          acc[m][n] = __builtin_amdgcn_mfma_f32_16x16x32_bf16(af[m], bfr[n], acc[m][n], 0, 0, 0);
    }
  }
  float* out = Sp + ((size_t)ks * 32 + bh) * 4096;
#pragma unroll
  for (int m = 0; m < 2; ++m)
#pragma unroll
    for (int n = 0; n < 2; ++n) {
      f32x4 a = acc[m][n];
#pragma unroll
      for (int v = 0; v < 4; ++v) {
        int row = wm * 32 + m * 16 + kg * 4 + v;
        int col = wn * 32 + n * 16 + r;
        out[row * 64 + col] = a[v];
      }
    }
}

// ---------------- attn 2: sum partials + softmax + PV (128-wide d tile) ----------------
__global__ __launch_bounds__(256) void attn_pv(const float* __restrict__ Sp,
                                               const ushort* __restrict__ Vb,
                                               const int* __restrict__ gmask,
                                               ushort* __restrict__ AO) {
  int bid = blockIdx.x;
  int bh = bid >> 3, dt = bid & 7;
  int b = bh >> 2;
  int d0 = dt * 128;
  size_t base = ((size_t)b * LNN) * HDD + (size_t)(bh & 3) * DD;
  __shared__ float S[64][68];
  __shared__ ushort Pls[64 * 72];
  __shared__ ushort Vt[128 * 72];
  int tid = threadIdx.x;
  int lane = tid & 63, w = tid >> 6;
  {
    int fbase = tid * 16;
    float a[16];
#pragma unroll
    for (int i = 0; i < 16; i += 4) {
      float4 v = *(const float4*)(Sp + (size_t)bh * 4096 + fbase + i);
      a[i] = v.x; a[i + 1] = v.y; a[i + 2] = v.z; a[i + 3] = v.w;
    }
#pragma unroll
    for (int ks = 1; ks < 8; ++ks) {
      const float* p = Sp + ((size_t)ks * 32 + bh) * 4096 + fbase;
#pragma unroll
      for (int i = 0; i < 16; i += 4) {
        float4 v = *(const float4*)(p + i);
        a[i] += v.x; a[i + 1] += v.y; a[i + 2] += v.z; a[i + 3] += v.w;
      }
    }
    int q = fbase >> 6, k = fbase & 63;
#pragma unroll
    for (int i = 0; i < 16; ++i) S[q][k + i] = a[i];
  }
  {
    int kq = lane, dq = w * 32;
    const ushort* src = Vb + base + (size_t)kq * HDD + d0 + dq;
    uint4 v0 = *(const uint4*)src;
    uint4 v1 = *(const uint4*)(src + 8);
    uint4 v2 = *(const uint4*)(src + 16);
    uint4 v3 = *(const uint4*)(src + 24);
    ushort tmp[32];
    *(uint4*)&tmp[0] = v0; *(uint4*)&tmp[8] = v1;
    *(uint4*)&tmp[16] = v2; *(uint4*)&tmp[24] = v3;
#pragma unroll
    for (int j = 0; j < 32; ++j) Vt[(dq + j) * 72 + kq] = tmp[j];
  }
  __syncthreads();
  bool valid = gmask[b * LNN + lane] != 0;
  for (int i = 0; i < 16; ++i) {
    int q = w * 16 + i;
    float v = valid ? S[q][lane] * 0.03125f : -__builtin_inff();
    float mx = v;
    for (int o = 32; o; o >>= 1) mx = fmaxf(mx, __shfl_xor(mx, o, 64));
    float e = valid ? __expf(v - mx) : 0.f;
    float s = e;
    for (int o = 32; o; o >>= 1) s += __shfl_xor(s, o, 64);
    Pls[q * 72 + lane] = f2b(__fdividef(e, s));
  }
  __syncthreads();
  int wm = w >> 1, wn = w & 1;
  int r = lane & 15, kg = lane >> 4;
  f32x4 acc[2][4] = {};
#pragma unroll
  for (int h = 0; h < 2; ++h) {
    int ko = h * 32 + kg * 8;
    bf16x8 af[2], bfr[4];
#pragma unroll
    for (int m = 0; m < 2; ++m)
      af[m] = *(const bf16x8*)&Pls[(wm * 32 + m * 16 + r) * 72 + ko];
#pragma unroll
    for (int n = 0; n < 4; ++n)
      bfr[n] = *(const bf16x8*)&Vt[(wn * 64 + n * 16 + r) * 72 + ko];
#pragma unroll
    for (int m = 0; m < 2; ++m)
#pragma unroll
      for (int n = 0; n < 4; ++n)
        acc[m][n] = __builtin_amdgcn_mfma_f32_16x16x32_bf16(af[m], bfr[n], acc[m][n], 0, 0, 0);
  }
#pragma unroll
  for (int m = 0; m < 2; ++m)
#pragma unroll
    for (int n = 0; n < 4; ++n) {
      f32x4 a = acc[m][n];
#pragma unroll
      for (int v = 0; v < 4; ++v) {
        int q = wm * 32 + m * 16 + kg * 4 + v;
        int col = wn * 64 + n * 16 + r;
        AO[base + (size_t)q * HDD + d0 + col] = f2b(a[v]);
      }
    }
}

// ---------------- additive attention phase 1: 8-q reuse, 128-d slices ----------------
// grid (8 dsl, 8 qt, 8 b). E8[ds][bq][k] partials.
__global__ __launch_bounds__(256) void addatt_e(const float* __restrict__ QBu,
                                                const float* __restrict__ KAB,
                                                const float* __restrict__ av_,
                                                float* __restrict__ E8) {
  int ds = blockIdx.x, qt = blockIdx.y, b = blockIdx.z;
  int tid = threadIdx.x;
  __shared__ float qs[8][128];
  __shared__ float avs[128];
  __shared__ float red[4];
  int bq0 = b * LNN + qt * 8;
  {
    int qq = tid >> 5, dd = (tid & 31) * 4;
    *(float4*)&qs[qq][dd] = *(const float4*)(QBu + (size_t)(bq0 + qq) * DD + ds * 128 + dd);
  }
  float av = (tid < 128) ? av_[ds * 128 + tid] : 0.f;
  if (tid < 128) avs[tid] = av;
  float s = av;
  for (int o = 32; o; o >>= 1) s += __shfl_xor(s, o, 64);
  int lane = tid & 63, w = tid >> 6;
  if (lane == 0) red[w] = s;
  __syncthreads();
  float sumav = red[0] + red[1] + red[2] + red[3];
  const float* kr = KAB + (size_t)(b * LTN + tid) * DD + ds * 128;
  float ac[8] = {};
#pragma unroll 2
  for (int d = 0; d < 128; d += 4) {
    float4 kv = *(const float4*)(kr + d);
    float4 av4 = *(const float4*)&avs[d];
#pragma unroll
    for (int qq = 0; qq < 8; ++qq) {
      float4 q4 = *(const float4*)&qs[qq][d];
      ac[qq] = fmaf(av4.x, __builtin_amdgcn_rcpf(__builtin_amdgcn_exp2f(q4.x + kv.x) + 1.f), ac[qq]);
      ac[qq] = fmaf(av4.y, __builtin_amdgcn_rcpf(__builtin_amdgcn_exp2f(q4.y + kv.y) + 1.f), ac[qq]);
      ac[qq] = fmaf(av4.z, __builtin_amdgcn_rcpf(__builtin_amdgcn_exp2f(q4.z + kv.z) + 1.f), ac[qq]);
      ac[qq] = fmaf(av4.w, __builtin_amdgcn_rcpf(__builtin_amdgcn_exp2f(q4.w + kv.w) + 1.f), ac[qq]);
    }
  }
  size_t ebase = ((size_t)ds * 512 + bq0) * LTN + tid;
#pragma unroll
  for (int qq = 0; qq < 8; ++qq)
    E8[ebase + (size_t)qq * LTN] = sumav - 2.f * ac[qq];
}

// ---------------- additive attention phase 2: sum 8 partials + masked softmax ----------------
__global__ __launch_bounds__(256) void addatt_sm(const float* __restrict__ E8,
                                                 const int* __restrict__ lmask,
                                                 float* __restrict__ Wv) {
  int bq = blockIdx.x;
  int b = bq >> 6;
  int tid = threadIdx.x;
  __shared__ float rb_[8];
  float e = 0.f;
#pragma unroll
  for (int ks = 0; ks < 8; ++ks)
    e += E8[((size_t)ks * 512 + bq) * LTN + tid];
  bool valid = lmask[b * LTN + tid] != 0;
  float v = valid ? e : -__builtin_inff();
  int lane = tid & 63, w = tid >> 6;
  float m = v;
  for (int o = 32; o; o >>= 1) m = fmaxf(m, __shfl_xor(m, o, 64));
  if (lane == 0) rb_[w] = m;
  __syncthreads();
  m = fmaxf(fmaxf(rb_[0], rb_[1]), fmaxf(rb_[2], rb_[3]));
  float ex = valid ? __expf(v - m) : 0.f;
  float sm = ex;
  for (int o = 32; o; o >>= 1) sm += __shfl_xor(sm, o, 64);
  if (lane == 0) rb_[4 + w] = sm;
  __syncthreads();
  sm = rb_[4] + rb_[5] + rb_[6] + rb_[7];
  Wv[(size_t)bq * LTN + tid] = __fdividef(ex, sm);
}

// ---------------- additive attention phase 3: pooled context ----------------
__global__ __launch_bounds__(256) void addatt_pool(const float* __restrict__ Wv,
                                                   const float* __restrict__ text,
                                                   const int* __restrict__ gmask,
                                                   float* __restrict__ H4) {
  int dt = blockIdx.x, b = blockIdx.y;
  int tid = threadIdx.x;
  __shared__ float cf[LTN];
  float c = 0.f, cnt = 0.f;
#pragma unroll 8
  for (int q = 0; q < LNN; ++q) {
    float m = (gmask[b * LNN + q] != 0) ? 1.f : 0.f;
    cnt += m;
    c = fmaf(m, Wv[(size_t)(b * LNN + q) * LTN + tid], c);
  }
  cf[tid] = c;
  cnt = fmaxf(cnt, 9.765625e-04f);
  __syncthreads();
  int d = dt * 256 + tid;
  const float* tb = text + (size_t)b * LTN * DD + d;
  float acc = 0.f;
#pragma unroll 8
  for (int k = 0; k < LTN; ++k) acc = fmaf(cf[k], tb[(size_t)k * DD], acc);
  H4[b * DD + d] = acc / cnt;
}

// ---------------- split-K GEMV ----------------
__global__ __launch_bounds__(256) void dp_split(const float* __restrict__ X,
                                                const float* __restrict__ W,
                                                float* __restrict__ P,
                                                int K, int N) {
  int jt = blockIdx.x, kt = blockIdx.y;
  int t = threadIdx.x;
  __shared__ float xs[8][32];
  if (t < 64) {
    int b = t >> 3, kk = (t & 7) * 4;
    *(float4*)&xs[b][kk] = *(const float4*)(X + (size_t)b * K + kt * 32 + kk);
  }
  __syncthreads();
  int j = jt * 64 + (t & 63);
  int bg = (t >> 6) * 2;
  const float* wp = W + (size_t)(kt * 32) * N + j;
  float a0 = 0.f, a1 = 0.f;
#pragma unroll
  for (int k = 0; k < 32; ++k) {
    float w = wp[(size_t)k * N];
    a0 = fmaf(xs[bg + 0][k], w, a0);
    a1 = fmaf(xs[bg + 1][k], w, a1);
  }
  P[((size_t)kt * 8 + bg + 0) * N + j] = a0;
  P[((size_t)kt * 8 + bg + 1) * N + j] = a1;
}

template <int GELU>
__global__ __launch_bounds__(256) void dp_reduce(const float* __restrict__ P,
                                                 const float* __restrict__ bias,
                                                 float* __restrict__ O, int N) {
  int b = blockIdx.y;
  int j = blockIdx.x * 256 + threadIdx.x;
  float s = bias[j];
#pragma unroll 8
  for (int kt = 0; kt < 32; ++kt) s += P[((size_t)kt * 8 + b) * N + j];
  if constexpr (GELU) s = 0.5f * s * (1.f + erff(s * 0.70710678118654752440f));
  O[(size_t)b * N + j] = s;
}

extern "C" void kernel_launch(void* const* d_in, const int* in_sizes, int n_in,
                              void* d_out, int out_size, void* d_ws, size_t ws_size,
                              hipStream_t stream) {
  const float* text = (const float*)d_in[0];
  const float* node = (const float*)d_in[1];
  const float* Wq = (const float*)d_in[2];
  const float* bq = (const float*)d_in[3];
  const float* Wk = (const float*)d_in[4];
  const float* bk = (const float*)d_in[5];
  const float* Wv = (const float*)d_in[6];
  const float* bv = (const float*)d_in[7];
  const float* Wo = (const float*)d_in[8];
  const float* bo = (const float*)d_in[9];
  const float* lng = (const float*)d_in[10];
  const float* lnb = (const float*)d_in[11];
  const float* aqW = (const float*)d_in[12];
  const float* aqb = (const float*)d_in[13];
  const float* akW = (const float*)d_in[14];
  const float* akb = (const float*)d_in[15];
  const float* attv = (const float*)d_in[16];
  const float* attb = (const float*)d_in[17];
  const float* dp1W = (const float*)d_in[18];
  const float* dp1b = (const float*)d_in[19];
  const float* dp2W = (const float*)d_in[20];
  const float* dp2b = (const float*)d_in[21];
  const int* gmask = (const int*)d_in[22];
  const int* lmask = (const int*)d_in[23];
  (void)in_sizes; (void)n_in; (void)out_size; (void)ws_size;

  char* base = (char*)d_ws;
#define MB(x) (((size_t)(x)) << 20)
  // ws = 256 MiB (confirmed by harness poison fills). Non-aliased layout, ~88 MB.
  ushort* TwtQKV = (ushort*)(base);                 // 0..24 MB
  ushort* TwtWo = (ushort*)(base + MB(24));         // 24..32
  ushort* TwtAQ = (ushort*)(base + MB(32));         // 32..36 (aq 2MB + ak 2MB contiguous)
  ushort* node_bf = (ushort*)(base + MB(36));       // 36..37
  ushort* text_bf = (ushort*)(base + MB(37));       // 37..41
  ushort* Qb = (ushort*)(base + MB(41));            // 41..45
  ushort* Kb = (ushort*)(base + MB(45));            // 45..49
  ushort* Vb = (ushort*)(base + MB(49));            // 49..53
  ushort* AO = (ushort*)(base + MB(53));            // 53..57
  float* Sp = (float*)(base + MB(57));              // 57..61
  float* P_Wo = (float*)(base + MB(61));            // 61..69
  ushort* H2 = (ushort*)(base + MB(69));            // 69..70
  float* QBu = (float*)(base + MB(70));             // 70..72
  float* KAB = (float*)(base + MB(72));             // 72..80
  float* E8 = (float*)(base + MB(80));              // 80..84
  float* Wvb = (float*)(base + MB(84));             // 84..84.5
  float* H4 = (float*)(base + MB(84) + (512 << 10));   // 32KB
  float* G = (float*)(base + MB(84) + (512 << 10) + 32768);  // 32KB
  float* P1 = (float*)(base + MB(85));              // 85..86
  float* P2 = (float*)(base + MB(86));              // 86..88
  float* Z = (float*)d_out;
#undef MB

  const int M1 = NB * LNN;  // 512
  dim3 blk(256);

  // one launch: activations cvt + all 6 weight transposes
  prep<<<dim3(5888), blk, 0, stream>>>(node, node_bf, text, text_bf,
                                       Wq, Wk, Wv, Wo, aqW, akW,
                                       TwtQKV, TwtWo, TwtAQ);

  // QKV projections (one launch, grid.z = 3)
  gemm_qkv3<<<dim3(HDD / 128, M1 / 64, 3), blk, 0, stream>>>(node_bf, TwtQKV, bq, bk, bv, Qb, Kb, Vb, M1, HDD, DD);

  // self-attention: QK^T split-K then softmax+PV
  attn_qk<<<dim3(NB * NH, 8), blk, 0, stream>>>(Qb, Kb, Sp);
  attn_pv<<<dim3(NB * NH * 8), blk, 0, stream>>>(Sp, Vb, gmask, AO);

  // output proj: split-K 4-way partials, then fused reduce+residual+LayerNorm
  gemm_wo_split<<<dim3(DD / 128, M1 / 64, 4), blk, 0, stream>>>(AO, TwtWo, P_Wo, M1, DD, HDD);
  wo_ln<<<dim3(M1), blk, 0, stream>>>(P_Wo, bo, node, lng, lnb, H2);

  // aq + ak (M-concat), outputs pre-scaled by C_TANH
  gemm_aqak<<<dim3(DD / 128, 40), blk, 0, stream>>>(H2, text_bf, TwtAQ, aqb, akb, attb, QBu, KAB, DD, DD);

  // additive attention: partial-e (8-q reuse, 8 d-slices) -> softmax -> pooled context
  addatt_e<<<dim3(8, 8, NB), blk, 0, stream>>>(QBu, KAB, attv, E8);
  addatt_sm<<<dim3(M1), blk, 0, stream>>>(E8, lmask, Wvb);
  addatt_pool<<<dim3(4, NB), blk, 0, stream>>>(Wvb, text, gmask, H4);

  // MLP via split-K GEMV (weight-read-bound)
  dp_split<<<dim3(DHN / 64, 32), blk, 0, stream>>>(H4, dp1W, P1, DD, DHN);
  dp_reduce<1><<<dim3(DHN / 256, NB), blk, 0, stream>>>(P1, dp1b, G, DHN);
  dp_split<<<dim3(DINN / 64, 32), blk, 0, stream>>>(G, dp2W, P2, DHN, DINN);
  dp_reduce<0><<<dim3(DINN / 256, NB), blk, 0, stream>>>(P2, dp2b, Z, DINN);
}